// Round 6
// baseline (772.306 us; speedup 1.0000x reference)
//
#include <hip/hip_runtime.h>
#include <hip/hip_fp16.h>
#include <cmath>

#define NN 50000
#define NE 1600000
#define NG 64
#define CAP 96    // slots per row; deg ~ Poisson(32), P(deg>=96) ~ e^-41 -> safe
// Build: two-pass bucketed, NO per-edge global atomics (r15 verified: -31us,
// build kernels out of top-5). Ledger: r9 +1.6M atomics=+74us; r12 padding=nil
// (per-op serializer ~21G ops/s, ~43B write-through/op); r13 co-residency=nil.
// LESSON: never per-element device-scope atomics on gfx950 — bucket + LDS-rank.
#define BSH 7
#define NBUCK ((NN + (1 << BSH) - 1) >> BSH)   // 391 buckets of 128 rows
#define MAXBUCK 6144                            // mean 4096, sigma ~64 -> safe
// r16: L5 props are the top tier (2x59.5us, FETCH 156MB = structural 8-XCD
// duplication of the random 256B-row gather; rate 2.9TB/s = issue-limited,
// VALU 35%). k_prop8: 8 feats/lane (us8 16B dwordx4) halves load instructions
// at same bytes — applied to L4/L5 props only.
// r11 LESSON (kept): workspace layout is perf-relevant state — all pre-existing
// buffer addresses are byte-identical to the 764us r15 run.

typedef __attribute__((ext_vector_type(8))) short short8_t;
typedef __attribute__((ext_vector_type(4))) float floatx4;
typedef __attribute__((ext_vector_type(4))) unsigned short us4;
typedef __attribute__((ext_vector_type(8))) unsigned short us8;

static __device__ __forceinline__ float softplusf(float x) {
    return fmaxf(x, 0.0f) + log1pf(expf(-fabsf(x)));
}

static __device__ __forceinline__ float bf2f(unsigned short u) {
    return __uint_as_float(((unsigned)u) << 16);
}
static __device__ __forceinline__ unsigned short f2bf(float x) {
    unsigned u = __float_as_uint(x);
    unsigned t = (u >> 16) & 1u;
    return (unsigned short)((u + 0x7FFFu + t) >> 16);  // RNE
}
static __device__ __forceinline__ float h2f(unsigned u) {
    __half_raw r; r.x = (unsigned short)(u & 0xFFFFu);
    return __half2float(__half(r));
}
static __device__ __forceinline__ unsigned short f2h(float x) {
    __half h = __float2half_rn(x);
    return static_cast<__half_raw>(h).x;
}

// exact split x = hi + lo (bf16 each, ~2^-16 relative residual)
static __device__ __forceinline__ void split_bf16(float x, unsigned short& hi, unsigned short& lo) {
    unsigned u = __float_as_uint(x);
    unsigned hb = u & 0xFFFF0000u;
    hi = (unsigned short)(hb >> 16);
    float r = x - __uint_as_float(hb);   // exact
    lo = f2bf(r);
}

static __device__ __forceinline__ int lower_bound_dev(const int* __restrict__ b, int val) {
    int lo = 0, hi = NN;
    while (lo < hi) {
        int mid = (lo + hi) >> 1;
        if (b[mid] < val) lo = mid + 1; else hi = mid;
    }
    return lo;
}

// ---- One-shot prep: all weight splits (layer-1 wcat computed on the fly,
// bit-identical to the old k_wcat1->k_wsplit path) + graph bounds.
__global__ __launch_bounds__(256) void k_prep(
    const float* __restrict__ W1, const float* __restrict__ W3,
    const float* __restrict__ W4, const float* __restrict__ W5,
    const int* __restrict__ batch,
    unsigned short* __restrict__ bt1h, unsigned short* __restrict__ bt1l,
    unsigned short* __restrict__ bt3h, unsigned short* __restrict__ bt3l,
    unsigned short* __restrict__ bt4h, unsigned short* __restrict__ bt4l,
    unsigned short* __restrict__ bt5h, unsigned short* __restrict__ bt5l,
    int* __restrict__ gb)
{
    const int bx = blockIdx.x;
    const int tid = threadIdx.x;
    if (bx < 24) {                       // layer 1: K=128, N=48, wcat on the fly
        int idx = bx * 256 + tid;
        if (idx < 128 * 48) {
            int k = idx / 48, j = idx - k * 48;
            float v;
            if (j < 16)      v = W1[k * 16 + j] - W1[2 * 2048 + k * 16 + j];
            else if (j < 32) v = W1[2048 + k * 16 + (j - 16)];
            else             v = W1[2 * 2048 + k * 16 + (j - 32)];
            unsigned short h, l;
            split_bf16(v, h, l);
            bt1h[(size_t)j * 128 + k] = h;
            bt1l[(size_t)j * 128 + k] = l;
        }
    } else if (bx < 48) {                // layer 3: K=96, N=64
        int idx = (bx - 24) * 256 + tid;
        if (idx < 96 * 64) {
            int k = idx / 64, n = idx - k * 64;
            unsigned short h, l;
            split_bf16(W3[idx], h, l);
            bt3h[(size_t)n * 96 + k] = h;
            bt3l[(size_t)n * 96 + k] = l;
        }
    } else if (bx < 144) {               // layer 4: K=192, N=128
        int idx = (bx - 48) * 256 + tid;
        if (idx < 192 * 128) {
            int k = idx / 128, n = idx - k * 128;
            unsigned short h, l;
            split_bf16(W4[idx], h, l);
            bt4h[(size_t)n * 192 + k] = h;
            bt4l[(size_t)n * 192 + k] = l;
        }
    } else if (bx < 528) {               // layer 5: K=384, N=256
        int idx = (bx - 144) * 256 + tid;
        if (idx < 384 * 256) {
            int k = idx / 256, n = idx - k * 256;
            unsigned short h, l;
            split_bf16(W5[idx], h, l);
            bt5h[(size_t)n * 384 + k] = h;
            bt5l[(size_t)n * 384 + k] = l;
        }
    } else {                             // graph bounds
        int g = tid;
        if (g <= NG) gb[g] = (g == NG) ? NN : lower_bound_dev(batch, g);
    }
}

// ---- Build pass 1: bin edges into NBUCK row-buckets. Per-block LDS
// histogram; ONE global atomic per (block,touched bucket) ~ 100K total.
// ebuf[b*MAXBUCK + i] = (row<<32) | (col<<16) | fp16(w).
__global__ __launch_bounds__(256) void k_bin(const int* __restrict__ row,
                                             const int* __restrict__ col,
                                             const float* __restrict__ w,
                                             int* __restrict__ bbase,
                                             unsigned long long* __restrict__ ebuf) {
    __shared__ int hist[NBUCK];
    __shared__ int base[NBUCK];
    const int t = threadIdx.x;
    const int per = (NE + gridDim.x - 1) / gridDim.x;
    const int e0 = blockIdx.x * per;
    const int e1 = min(e0 + per, NE);
    for (int i = t; i < NBUCK; i += 256) hist[i] = 0;
    __syncthreads();
    for (int e = e0 + t; e < e1; e += 256) atomicAdd(&hist[row[e] >> BSH], 1);
    __syncthreads();
    for (int i = t; i < NBUCK; i += 256) {
        int h = hist[i];
        base[i] = h ? atomicAdd(&bbase[i], h) : 0;
    }
    __syncthreads();
    for (int i = t; i < NBUCK; i += 256) hist[i] = 0;
    __syncthreads();
    for (int e = e0 + t; e < e1; e += 256) {
        int r = row[e];
        int b = r >> BSH;
        int k = atomicAdd(&hist[b], 1);        // LDS: local rank
        int idx = base[b] + k;
        if (idx < MAXBUCK) {                   // defensive (impossible stat.)
            unsigned pay = ((unsigned)col[e] << 16) | (unsigned)f2h(w[e]);
            ebuf[(size_t)b * MAXBUCK + idx] =
                ((unsigned long long)(unsigned)r << 32) | pay;
        }
    }
}

// ---- Build pass 2: one block per bucket; slot ranks via LDS atomics only.
// pslot writes for a bucket land in a 48KB region -> L2-merged full lines.
// Also writes cnt (no global memset needed).
__global__ __launch_bounds__(256) void k_place(const int* __restrict__ bbase,
                                               const unsigned long long* __restrict__ ebuf,
                                               int* __restrict__ cnt,
                                               unsigned* __restrict__ pslots) {
    __shared__ int cl[1 << BSH];
    const int t = threadIdx.x;
    const int b = blockIdx.x;
    if (t < (1 << BSH)) cl[t] = 0;
    __syncthreads();
    const int n = min(bbase[b], MAXBUCK);
    const unsigned long long* eb = ebuf + (size_t)b * MAXBUCK;
    for (int i = t; i < n; i += 256) {
        unsigned long long pk = eb[i];
        int r = (int)(pk >> 32);
        int k = atomicAdd(&cl[r & ((1 << BSH) - 1)], 1);
        k = min(k, CAP - 1);                   // defensive
        pslots[(size_t)r * CAP + k] = (unsigned)pk;
    }
    __syncthreads();
    int r = (b << BSH) + t;
    if (t < (1 << BSH) && r < NN) cnt[r] = min(cl[t], CAP);
}

#define ASTR 40  // padded LDS row stride in ushorts (32 + 8)

// ---------------- MFMA GEMM, fp32 A (3-term split), bf16 C. Layer 1 only.
__global__ __launch_bounds__(256, 2) void k_gemm_mfma_f32A(
    const float* __restrict__ A, int lda,
    const unsigned short* __restrict__ BhiT,
    const unsigned short* __restrict__ BloT,
    unsigned short* __restrict__ C, int ldc,
    int M, int K, int Ncol)
{
    __shared__ unsigned short Ah[128 * ASTR];
    __shared__ unsigned short Al[128 * ASTR];
    __shared__ unsigned short Bh[128 * ASTR];
    __shared__ unsigned short Bl[128 * ASTR];

    const int tid = threadIdx.x;
    const int lane = tid & 63;
    const int wave = tid >> 6;
    const int wm = wave >> 1, wn = wave & 1;
    const int quad = lane >> 4, l16 = lane & 15;
    const int bm = blockIdx.y * 128, bn = blockIdx.x * 128;
    const int srow = tid >> 1;
    const int skq  = (tid & 1) * 16;

    floatx4 acc[4][4];
#pragma unroll
    for (int i = 0; i < 4; ++i)
#pragma unroll
        for (int j = 0; j < 4; ++j) acc[i][j] = (floatx4){0.f, 0.f, 0.f, 0.f};

    for (int k0 = 0; k0 < K; k0 += 32) {
        float4 a0 = make_float4(0, 0, 0, 0), a1 = a0, a2 = a0, a3 = a0;
        const int ga = bm + srow;
        if (ga < M) {
            const float* Ap = A + (size_t)ga * lda + k0 + skq;
            a0 = *(const float4*)(Ap + 0);
            a1 = *(const float4*)(Ap + 4);
            a2 = *(const float4*)(Ap + 8);
            a3 = *(const float4*)(Ap + 12);
        }
        uint4 bh0 = make_uint4(0, 0, 0, 0), bh1 = bh0, bl0 = bh0, bl1 = bh0;
        const int gb2 = bn + srow;
        if (gb2 < Ncol) {
            const unsigned short* ph = BhiT + (size_t)gb2 * K + k0 + skq;
            const unsigned short* pl = BloT + (size_t)gb2 * K + k0 + skq;
            bh0 = *(const uint4*)(ph);
            bh1 = *(const uint4*)(ph + 8);
            bl0 = *(const uint4*)(pl);
            bl1 = *(const uint4*)(pl + 8);
        }
        __attribute__((aligned(16))) unsigned short ah[16], al[16];
        const float av[16] = {a0.x, a0.y, a0.z, a0.w, a1.x, a1.y, a1.z, a1.w,
                              a2.x, a2.y, a2.z, a2.w, a3.x, a3.y, a3.z, a3.w};
#pragma unroll
        for (int i = 0; i < 16; ++i) split_bf16(av[i], ah[i], al[i]);

        __syncthreads();
        *(uint4*)&Ah[srow * ASTR + skq]     = *(const uint4*)&ah[0];
        *(uint4*)&Ah[srow * ASTR + skq + 8] = *(const uint4*)&ah[8];
        *(uint4*)&Al[srow * ASTR + skq]     = *(const uint4*)&al[0];
        *(uint4*)&Al[srow * ASTR + skq + 8] = *(const uint4*)&al[8];
        *(uint4*)&Bh[srow * ASTR + skq]     = bh0;
        *(uint4*)&Bh[srow * ASTR + skq + 8] = bh1;
        *(uint4*)&Bl[srow * ASTR + skq]     = bl0;
        *(uint4*)&Bl[srow * ASTR + skq + 8] = bl1;
        __syncthreads();

        short8_t afh[4], afl[4], bfh[4], bfl[4];
#pragma unroll
        for (int t = 0; t < 4; ++t) {
            const int m = wm * 64 + t * 16 + l16;
            afh[t] = *(const short8_t*)&Ah[m * ASTR + quad * 8];
            afl[t] = *(const short8_t*)&Al[m * ASTR + quad * 8];
            const int n = wn * 64 + t * 16 + l16;
            bfh[t] = *(const short8_t*)&Bh[n * ASTR + quad * 8];
            bfl[t] = *(const short8_t*)&Bl[n * ASTR + quad * 8];
        }
#pragma unroll
        for (int i = 0; i < 4; ++i)
#pragma unroll
            for (int j = 0; j < 4; ++j) {
                acc[i][j] = __builtin_amdgcn_mfma_f32_16x16x32_bf16(afh[i], bfh[j], acc[i][j], 0, 0, 0);
                acc[i][j] = __builtin_amdgcn_mfma_f32_16x16x32_bf16(afh[i], bfl[j], acc[i][j], 0, 0, 0);
                acc[i][j] = __builtin_amdgcn_mfma_f32_16x16x32_bf16(afl[i], bfh[j], acc[i][j], 0, 0, 0);
            }
    }

#pragma unroll
    for (int j = 0; j < 4; ++j) {
        const int colc = bn + wn * 64 + j * 16 + l16;
        if (colc >= Ncol) continue;
#pragma unroll
        for (int i = 0; i < 4; ++i) {
#pragma unroll
            for (int r = 0; r < 4; ++r) {
                const int rowc = bm + wm * 64 + i * 16 + quad * 4 + r;
                if (rowc >= M) continue;
                C[(size_t)rowc * ldc + colc] = f2bf(acc[i][j][r]);
            }
        }
    }
}

// dinv[r] = rsqrt(sum of raw w over row r), 0 if deg<=0 (atomic-free)
__global__ __launch_bounds__(256) void k_degsum(const int* __restrict__ cnt,
                                                const unsigned* __restrict__ pslots,
                                                float* __restrict__ dinv) {
    int tid = threadIdx.x;
    int lane = tid & 15;
    int node = blockIdx.x * 16 + (tid >> 4);
    if (node >= NN) return;
    int e = cnt[node];
    const unsigned* base = pslots + (size_t)node * CAP;
    float s = 0.0f;
    for (int k = lane; k < e; k += 16) s += h2f(base[k]);
#pragma unroll
    for (int m = 8; m >= 1; m >>= 1) s += __shfl_xor(s, m);
    if (lane == 0) dinv[node] = (s > 0.0f) ? rsqrtf(s) : 0.0f;
}

// In-place: weight half of pslot <- fp16(-w * dinv[r] * dinv[col])
__global__ __launch_bounds__(256) void k_repack(const int* __restrict__ cnt,
                                                unsigned* __restrict__ pslots,
                                                const float* __restrict__ dinv) {
    int tid = threadIdx.x;
    int lane = tid & 15;
    int node = blockIdx.x * 16 + (tid >> 4);
    if (node >= NN) return;
    int e = cnt[node];
    float dr = dinv[node];
    unsigned* pb = pslots + (size_t)node * CAP;
    for (int k = lane; k < e; k += 16) {
        unsigned s = pb[k];
        float wv = -h2f(s) * dr * dinv[s >> 16];
        pb[k] = (s & 0xFFFF0000u) | (unsigned)f2h(wv);
    }
}

// ---------------- MFMA GEMM, bf16 A direct (2-term W split). Layers 3/4/5.
__global__ __launch_bounds__(256, 2) void k_gemm_mfma_bf(
    const unsigned short* __restrict__ A, int lda,
    const unsigned short* __restrict__ BhiT,
    const unsigned short* __restrict__ BloT,
    unsigned short* __restrict__ C, int ldc,
    int M, int K, int Ncol,
    const float* __restrict__ bias, int act)
{
    __shared__ unsigned short Ah[128 * ASTR];
    __shared__ unsigned short Bh[128 * ASTR];
    __shared__ unsigned short Bl[128 * ASTR];

    const int tid = threadIdx.x;
    const int lane = tid & 63;
    const int wave = tid >> 6;
    const int wm = wave >> 1, wn = wave & 1;
    const int quad = lane >> 4, l16 = lane & 15;
    const int bm = blockIdx.y * 128, bn = blockIdx.x * 128;
    const int srow = tid >> 1;
    const int skq  = (tid & 1) * 16;

    floatx4 acc[4][4];
#pragma unroll
    for (int i = 0; i < 4; ++i)
#pragma unroll
        for (int j = 0; j < 4; ++j) acc[i][j] = (floatx4){0.f, 0.f, 0.f, 0.f};

    for (int k0 = 0; k0 < K; k0 += 32) {
        uint4 a0 = make_uint4(0, 0, 0, 0), a1 = a0;
        const int ga = bm + srow;
        if (ga < M) {
            const unsigned short* Ap = A + (size_t)ga * lda + k0 + skq;
            a0 = *(const uint4*)(Ap);
            a1 = *(const uint4*)(Ap + 8);
        }
        uint4 bh0 = make_uint4(0, 0, 0, 0), bh1 = bh0, bl0 = bh0, bl1 = bh0;
        const int gb = bn + srow;
        if (gb < Ncol) {
            const unsigned short* ph = BhiT + (size_t)gb * K + k0 + skq;
            const unsigned short* pl = BloT + (size_t)gb * K + k0 + skq;
            bh0 = *(const uint4*)(ph);
            bh1 = *(const uint4*)(ph + 8);
            bl0 = *(const uint4*)(pl);
            bl1 = *(const uint4*)(pl + 8);
        }
        __syncthreads();
        *(uint4*)&Ah[srow * ASTR + skq]     = a0;
        *(uint4*)&Ah[srow * ASTR + skq + 8] = a1;
        *(uint4*)&Bh[srow * ASTR + skq]     = bh0;
        *(uint4*)&Bh[srow * ASTR + skq + 8] = bh1;
        *(uint4*)&Bl[srow * ASTR + skq]     = bl0;
        *(uint4*)&Bl[srow * ASTR + skq + 8] = bl1;
        __syncthreads();

        short8_t afh[4], bfh[4], bfl[4];
#pragma unroll
        for (int t = 0; t < 4; ++t) {
            const int m = wm * 64 + t * 16 + l16;
            afh[t] = *(const short8_t*)&Ah[m * ASTR + quad * 8];
            const int n = wn * 64 + t * 16 + l16;
            bfh[t] = *(const short8_t*)&Bh[n * ASTR + quad * 8];
            bfl[t] = *(const short8_t*)&Bl[n * ASTR + quad * 8];
        }
#pragma unroll
        for (int i = 0; i < 4; ++i)
#pragma unroll
            for (int j = 0; j < 4; ++j) {
                acc[i][j] = __builtin_amdgcn_mfma_f32_16x16x32_bf16(afh[i], bfh[j], acc[i][j], 0, 0, 0);
                acc[i][j] = __builtin_amdgcn_mfma_f32_16x16x32_bf16(afh[i], bfl[j], acc[i][j], 0, 0, 0);
            }
    }

#pragma unroll
    for (int j = 0; j < 4; ++j) {
        const int col = bn + wn * 64 + j * 16 + l16;
        if (col >= Ncol) continue;
        const float bv = bias ? bias[col] : 0.0f;
#pragma unroll
        for (int i = 0; i < 4; ++i) {
#pragma unroll
            for (int r = 0; r < 4; ++r) {
                const int row = bm + wm * 64 + i * 16 + quad * 4 + r;
                if (row >= M) continue;
                float v = acc[i][j][r] + bv;
                if (act) v = softplusf(v);
                C[(size_t)row * ldc + col] = f2bf(v);
            }
        }
    }
}

// fp32-weight vector GEMM with bf16 A and bf16 C (layer 2 only, K=48)
__global__ __launch_bounds__(256) void k_gemm(
    const unsigned short* __restrict__ A, int lda,
    const float* __restrict__ B, int ldb,
    unsigned short* __restrict__ C, int ldc,
    int M, int K, int Ncol,
    const float* __restrict__ bias, int act)
{
    __shared__ float As[16][128];
    __shared__ float Bs[16][128];
    const int tid = threadIdx.x;
    const int tx = tid & 15;
    const int ty = tid >> 4;
    const int bm = blockIdx.y * 128;
    const int bn = blockIdx.x * 128;
    const int arow = tid >> 1;
    const int akq = (tid & 1) * 8;
    const int bkr = tid >> 4;
    const int bcq = (tid & 15) * 8;

    float acc[8][8];
#pragma unroll
    for (int i = 0; i < 8; ++i)
#pragma unroll
        for (int j = 0; j < 8; ++j) acc[i][j] = 0.0f;

    for (int k0 = 0; k0 < K; k0 += 16) {
        uint4 ald = make_uint4(0, 0, 0, 0);
        int gr = bm + arow;
        if (gr < M) ald = *(const uint4*)(A + (size_t)gr * lda + k0 + akq);
        float4 b0 = make_float4(0, 0, 0, 0), b1 = make_float4(0, 0, 0, 0);
        int cb = bn + bcq;
        const float* Bp = B + (k0 + bkr) * ldb;
        if (cb < Ncol)     b0 = *(const float4*)(Bp + cb);
        if (cb + 4 < Ncol) b1 = *(const float4*)(Bp + cb + 4);
        __syncthreads();
        const unsigned short* au = (const unsigned short*)&ald;
#pragma unroll
        for (int i = 0; i < 8; ++i) As[akq + i][arow] = bf2f(au[i]);
        *(float4*)&Bs[bkr][bcq] = b0;
        *(float4*)&Bs[bkr][bcq + 4] = b1;
        __syncthreads();
#pragma unroll
        for (int kk = 0; kk < 16; ++kk) {
            float a[8], b[8];
            float4 t;
            t = *(const float4*)&As[kk][ty * 4];      a[0] = t.x; a[1] = t.y; a[2] = t.z; a[3] = t.w;
            t = *(const float4*)&As[kk][64 + ty * 4]; a[4] = t.x; a[5] = t.y; a[6] = t.z; a[7] = t.w;
            t = *(const float4*)&Bs[kk][tx * 4];      b[0] = t.x; b[1] = t.y; b[2] = t.z; b[3] = t.w;
            t = *(const float4*)&Bs[kk][64 + tx * 4]; b[4] = t.x; b[5] = t.y; b[6] = t.z; b[7] = t.w;
#pragma unroll
            for (int i = 0; i < 8; ++i)
#pragma unroll
                for (int j = 0; j < 8; ++j)
                    acc[i][j] = fmaf(a[i], b[j], acc[i][j]);
        }
    }
#pragma unroll
    for (int i = 0; i < 8; ++i) {
        int r = bm + ((i < 4) ? (ty * 4 + i) : (64 + ty * 4 + i - 4));
        if (r >= M) continue;
#pragma unroll
        for (int j = 0; j < 8; ++j) {
            int cl = bn + ((j < 4) ? (tx * 4 + j) : (64 + tx * 4 + j - 4));
            if (cl >= Ncol) continue;
            float v = acc[i][j];
            if (bias) v += bias[cl];
            if (act) v = softplusf(v);
            C[(size_t)r * ldc + cl] = f2bf(v);
        }
    }
}

// Slotted propagation, 4 bf16 feats/lane (us4 8B gathers). Layers 1-3.
__global__ __launch_bounds__(256) void k_prop(
    const int* __restrict__ cnt, const unsigned* __restrict__ pslots,
    const unsigned short* __restrict__ z, int zld, int zoff,
    unsigned short* __restrict__ out, int outld, int ooff,
    int ltw, float alpha,
    const unsigned short* __restrict__ add1, int a1ld, int a1off, float c1,
    const unsigned short* __restrict__ add2, int a2ld, int a2off,
    const float* __restrict__ bias, int act)
{
    const int T = 1 << ltw;
    const int lane = threadIdx.x & (T - 1);
    const int node = blockIdx.x * (256 >> ltw) + (threadIdx.x >> ltw);
    if (node >= NN) return;
    const int f4 = lane * 4;
    const int e = cnt[node];
    const unsigned* base = pslots + (size_t)node * CAP;
    float accA[4] = {0, 0, 0, 0};
    float accB[4] = {0, 0, 0, 0};
    const unsigned short* zp = z + zoff + f4;
    int p = 0;
    for (; p + 8 <= e; p += 8) {
        unsigned s0 = base[p + 0], s1 = base[p + 1], s2 = base[p + 2], s3 = base[p + 3];
        unsigned s4 = base[p + 4], s5 = base[p + 5], s6 = base[p + 6], s7 = base[p + 7];
        const us4 z0 = *(const us4*)(zp + (size_t)(s0 >> 16) * zld);
        const us4 z1 = *(const us4*)(zp + (size_t)(s1 >> 16) * zld);
        const us4 z2 = *(const us4*)(zp + (size_t)(s2 >> 16) * zld);
        const us4 z3 = *(const us4*)(zp + (size_t)(s3 >> 16) * zld);
        const us4 z4 = *(const us4*)(zp + (size_t)(s4 >> 16) * zld);
        const us4 z5 = *(const us4*)(zp + (size_t)(s5 >> 16) * zld);
        const us4 z6 = *(const us4*)(zp + (size_t)(s6 >> 16) * zld);
        const us4 z7 = *(const us4*)(zp + (size_t)(s7 >> 16) * zld);
        float w0 = h2f(s0), w1 = h2f(s1), w2 = h2f(s2), w3 = h2f(s3);
        float w4 = h2f(s4), w5 = h2f(s5), w6 = h2f(s6), w7 = h2f(s7);
#pragma unroll
        for (int i = 0; i < 4; ++i) {
            accA[i] = fmaf(w0, bf2f(z0[i]), accA[i]);
            accB[i] = fmaf(w1, bf2f(z1[i]), accB[i]);
            accA[i] = fmaf(w2, bf2f(z2[i]), accA[i]);
            accB[i] = fmaf(w3, bf2f(z3[i]), accB[i]);
            accA[i] = fmaf(w4, bf2f(z4[i]), accA[i]);
            accB[i] = fmaf(w5, bf2f(z5[i]), accB[i]);
            accA[i] = fmaf(w6, bf2f(z6[i]), accA[i]);
            accB[i] = fmaf(w7, bf2f(z7[i]), accB[i]);
        }
    }
    for (; p + 4 <= e; p += 4) {
        unsigned s0 = base[p + 0], s1 = base[p + 1], s2 = base[p + 2], s3 = base[p + 3];
        const us4 z0 = *(const us4*)(zp + (size_t)(s0 >> 16) * zld);
        const us4 z1 = *(const us4*)(zp + (size_t)(s1 >> 16) * zld);
        const us4 z2 = *(const us4*)(zp + (size_t)(s2 >> 16) * zld);
        const us4 z3 = *(const us4*)(zp + (size_t)(s3 >> 16) * zld);
        float w0 = h2f(s0), w1 = h2f(s1), w2 = h2f(s2), w3 = h2f(s3);
#pragma unroll
        for (int i = 0; i < 4; ++i) {
            accA[i] = fmaf(w0, bf2f(z0[i]), accA[i]);
            accB[i] = fmaf(w1, bf2f(z1[i]), accB[i]);
            accA[i] = fmaf(w2, bf2f(z2[i]), accA[i]);
            accB[i] = fmaf(w3, bf2f(z3[i]), accB[i]);
        }
    }
    for (; p < e; ++p) {
        unsigned s = base[p];
        float wv = h2f(s);
        const us4 zv = *(const us4*)(zp + (size_t)(s >> 16) * zld);
#pragma unroll
        for (int i = 0; i < 4; ++i) accA[i] = fmaf(wv, bf2f(zv[i]), accA[i]);
    }
#pragma unroll
    for (int i = 0; i < 4; ++i) accA[i] = alpha * (accA[i] + accB[i]);
    if (add1) {
        const us4 t = *(const us4*)(add1 + (size_t)node * a1ld + a1off + f4);
#pragma unroll
        for (int i = 0; i < 4; ++i) accA[i] = fmaf(c1, bf2f(t[i]), accA[i]);
    }
    if (add2) {
        const us4 t = *(const us4*)(add2 + (size_t)node * a2ld + a2off + f4);
#pragma unroll
        for (int i = 0; i < 4; ++i) accA[i] += bf2f(t[i]);
    }
    if (bias) {
        const float4 t = *(const float4*)(bias + f4);
        accA[0] += t.x; accA[1] += t.y; accA[2] += t.z; accA[3] += t.w;
    }
    if (act) {
#pragma unroll
        for (int i = 0; i < 4; ++i) accA[i] = softplusf(accA[i]);
    }
    us4 o;
#pragma unroll
    for (int i = 0; i < 4; ++i) o[i] = f2bf(accA[i]);
    *(us4*)(out + (size_t)node * outld + ooff + f4) = o;
}

// r16: 8 bf16 feats/lane (us8 16B dwordx4 gathers) — half the load
// instructions at the same bytes/edge vs k_prop. ltw = log2(feats/8).
// x4 edge unroll keeps ~50 VGPRs; launch_bounds(256,8) pins 8 waves/SIMD.
// Layers 4/5 only (add2 path unused there).
__global__ __launch_bounds__(256, 8) void k_prop8(
    const int* __restrict__ cnt, const unsigned* __restrict__ pslots,
    const unsigned short* __restrict__ z, int zld, int zoff,
    unsigned short* __restrict__ out, int outld, int ooff,
    int ltw, float alpha,
    const unsigned short* __restrict__ add1, int a1ld, int a1off, float c1)
{
    const int T = 1 << ltw;
    const int lane = threadIdx.x & (T - 1);
    const int node = blockIdx.x * (256 >> ltw) + (threadIdx.x >> ltw);
    if (node >= NN) return;
    const int f8 = lane * 8;
    const int e = cnt[node];
    const unsigned* base = pslots + (size_t)node * CAP;
    float accA[8] = {0, 0, 0, 0, 0, 0, 0, 0};
    float accB[8] = {0, 0, 0, 0, 0, 0, 0, 0};
    const unsigned short* zp = z + zoff + f8;
    int p = 0;
    for (; p + 4 <= e; p += 4) {
        unsigned s0 = base[p + 0], s1 = base[p + 1], s2 = base[p + 2], s3 = base[p + 3];
        const us8 z0 = *(const us8*)(zp + (size_t)(s0 >> 16) * zld);
        const us8 z1 = *(const us8*)(zp + (size_t)(s1 >> 16) * zld);
        const us8 z2 = *(const us8*)(zp + (size_t)(s2 >> 16) * zld);
        const us8 z3 = *(const us8*)(zp + (size_t)(s3 >> 16) * zld);
        float w0 = h2f(s0), w1 = h2f(s1), w2 = h2f(s2), w3 = h2f(s3);
#pragma unroll
        for (int i = 0; i < 8; ++i) {
            accA[i] = fmaf(w0, bf2f(z0[i]), accA[i]);
            accB[i] = fmaf(w1, bf2f(z1[i]), accB[i]);
            accA[i] = fmaf(w2, bf2f(z2[i]), accA[i]);
            accB[i] = fmaf(w3, bf2f(z3[i]), accB[i]);
        }
    }
    for (; p + 2 <= e; p += 2) {
        unsigned s0 = base[p + 0], s1 = base[p + 1];
        const us8 z0 = *(const us8*)(zp + (size_t)(s0 >> 16) * zld);
        const us8 z1 = *(const us8*)(zp + (size_t)(s1 >> 16) * zld);
        float w0 = h2f(s0), w1 = h2f(s1);
#pragma unroll
        for (int i = 0; i < 8; ++i) {
            accA[i] = fmaf(w0, bf2f(z0[i]), accA[i]);
            accB[i] = fmaf(w1, bf2f(z1[i]), accB[i]);
        }
    }
    if (p < e) {
        unsigned s = base[p];
        const us8 zv = *(const us8*)(zp + (size_t)(s >> 16) * zld);
        float wv = h2f(s);
#pragma unroll
        for (int i = 0; i < 8; ++i) accA[i] = fmaf(wv, bf2f(zv[i]), accA[i]);
    }
#pragma unroll
    for (int i = 0; i < 8; ++i) accA[i] = alpha * (accA[i] + accB[i]);
    if (add1) {
        const us8 t = *(const us8*)(add1 + (size_t)node * a1ld + a1off + f8);
#pragma unroll
        for (int i = 0; i < 8; ++i) accA[i] = fmaf(c1, bf2f(t[i]), accA[i]);
    }
    us8 o;
#pragma unroll
    for (int i = 0; i < 8; ++i) o[i] = f2bf(accA[i]);
    *(us8*)(out + (size_t)node * outld + ooff + f8) = o;
}

__global__ __launch_bounds__(256) void k_bnstats(const unsigned short* __restrict__ h, int ld, int lc,
                                                 float* __restrict__ stats) {
    const int C = 1 << lc;
    const int tid = threadIdx.x;
    const int c = tid & (C - 1);
    const int rpb = 256 >> lc;
    int r = blockIdx.x * rpb + (tid >> lc);
    const int stride = gridDim.x * rpb;
    float s = 0.0f, q = 0.0f;
    for (; r < NN; r += stride) {
        float v = bf2f(h[(size_t)r * ld + c]);
        s += v;
        q = fmaf(v, v, q);
    }
    __shared__ float shs[256], shq[256];
    shs[tid] = s; shq[tid] = q;
    __syncthreads();
    for (int o = 128; o >= C; o >>= 1) {
        if (tid < o) { shs[tid] += shs[tid + o]; shq[tid] += shq[tid + o]; }
        __syncthreads();
    }
    if (tid < C) {
        atomicAdd(&stats[c], shs[tid]);
        atomicAdd(&stats[128 + c], shq[tid]);
    }
}

// Vectorized BN apply: 8 elems/thread.
__global__ void k_bnapply(unsigned short* __restrict__ h, int ld, int lc,
                          const float* __restrict__ stats,
                          const float* __restrict__ g, const float* __restrict__ be) {
    int idx = blockIdx.x * 256 + threadIdx.x;        // in units of 8 elems
    const int C8 = 1 << (lc - 3);
    if (idx >= NN * C8) return;
    int r = idx >> (lc - 3);
    int c0 = (idx & (C8 - 1)) << 3;
    const float invN = 1.0f / (float)NN;
    unsigned short* hp = h + (size_t)r * ld + c0;
    us8 v = *(const us8*)hp;
    us8 o;
#pragma unroll
    for (int i = 0; i < 8; ++i) {
        int c = c0 + i;
        float m = stats[c] * invN;
        float var = fmaf(stats[128 + c], invN, -m * m);
        var = fmaxf(var, 0.0f);
        float inv = rsqrtf(var + 1e-5f);
        o[i] = f2bf(fmaf(g[c] * inv, bf2f(v[i]) - m, be[c]));
    }
    *(us8*)hp = o;
}

// Pool stage 1 over bf16 h5.
__global__ __launch_bounds__(256) void k_pool1(const unsigned short* __restrict__ h,
                                               const int* __restrict__ gb,
                                               float* __restrict__ partial) {
    int g = blockIdx.y;
    int j = blockIdx.x;
    int start = gb[g], end = gb[g + 1];
    int len = end - start;
    int chunk = (len + 15) >> 4;
    int s = start + j * chunk;
    int e = min(s + chunk, end);
    int c = threadIdx.x;
    float mx = -INFINITY, sum = 0.0f;
    for (int r = s; r < e; ++r) {
        float v = bf2f(h[(size_t)r * 256 + c]);
        mx = fmaxf(mx, v);
        sum += v;
    }
    size_t base = ((size_t)(g * 16 + j)) * 512;
    partial[base + c] = mx;
    partial[base + 256 + c] = sum;
}

// Fused pool stage 2 + dense + log_softmax: 64 blocks.
__global__ __launch_bounds__(256) void k_pool2d(const float* __restrict__ partial,
                                                const int* __restrict__ gb,
                                                const float* __restrict__ Wd,
                                                const float* __restrict__ bd,
                                                float* __restrict__ out) {
    __shared__ float pl[512];
    __shared__ float red[4][256];
    int g = blockIdx.x;
    int c = threadIdx.x;
    float mx = -INFINITY, sum = 0.0f;
#pragma unroll
    for (int j = 0; j < 16; ++j) {
        size_t base = ((size_t)(g * 16 + j)) * 512;
        mx = fmaxf(mx, partial[base + c]);
        sum += partial[base + 256 + c];
    }
    int len = gb[g + 1] - gb[g];
    pl[c] = (len > 0) ? mx : 0.0f;
    pl[256 + c] = sum / fmaxf((float)len, 1.0f);
    __syncthreads();
    float p[4] = {0, 0, 0, 0};
    for (int k = c; k < 512; k += 256) {
        float pv = pl[k];
#pragma unroll
        for (int cc = 0; cc < 4; ++cc) p[cc] = fmaf(pv, Wd[k * 4 + cc], p[cc]);
    }
#pragma unroll
    for (int cc = 0; cc < 4; ++cc) red[cc][c] = p[cc];
    __syncthreads();
    for (int o = 128; o >= 1; o >>= 1) {
        if (c < o) {
#pragma unroll
            for (int cc = 0; cc < 4; ++cc) red[cc][c] += red[cc][c + o];
        }
        __syncthreads();
    }
    if (c == 0) {
        float l0 = red[0][0] + bd[0], l1 = red[1][0] + bd[1];
        float l2 = red[2][0] + bd[2], l3 = red[3][0] + bd[3];
        float m = fmaxf(fmaxf(l0, l1), fmaxf(l2, l3));
        float ls = m + logf(expf(l0 - m) + expf(l1 - m) + expf(l2 - m) + expf(l3 - m));
        out[g * 4 + 0] = l0 - ls;
        out[g * 4 + 1] = l1 - ls;
        out[g * 4 + 2] = l2 - ls;
        out[g * 4 + 3] = l3 - ls;
    }
}

extern "C" void kernel_launch(void* const* d_in, const int* in_sizes, int n_in,
                              void* d_out, int out_size, void* d_ws, size_t ws_size,
                              hipStream_t stream)
{
    const float* x    = (const float*)d_in[0];
    const float* ew   = (const float*)d_in[1];
    const int*   row  = (const int*)d_in[2];
    const int*   colp = row + NE;
    const int*   batch = (const int*)d_in[3];
    const float* W1 = (const float*)d_in[4];
    const float* b1 = (const float*)d_in[5];
    const float* g1 = (const float*)d_in[6];
    const float* be1 = (const float*)d_in[7];
    const float* W2 = (const float*)d_in[8];
    const float* b2 = (const float*)d_in[9];
    const float* g2 = (const float*)d_in[10];
    const float* be2 = (const float*)d_in[11];
    const float* W3 = (const float*)d_in[12];
    const float* b3 = (const float*)d_in[13];
    const float* g3 = (const float*)d_in[14];
    const float* be3 = (const float*)d_in[15];
    const float* W4 = (const float*)d_in[16];
    const float* b4 = (const float*)d_in[17];
    const float* g4 = (const float*)d_in[18];
    const float* be4 = (const float*)d_in[19];
    const float* W5 = (const float*)d_in[20];
    const float* b5 = (const float*)d_in[21];
    const float* Wd = (const float*)d_in[22];
    const float* bd = (const float*)d_in[23];
    float* outp = (float*)d_out;
    (void)in_sizes; (void)n_in; (void)out_size; (void)ws_size; (void)ew;

    char* wsb = (char*)d_ws;
    size_t off = 0;
    auto take = [&](size_t bytes) -> void* {
        void* p = wsb + off;
        off = (off + bytes + 255) & ~(size_t)255;
        return p;
    };
    // Layout byte-identical to the 764us r15 run (r11 lesson).
    int*   cnt    = (int*)take((size_t)NN * sizeof(int));
    float* dinv   = (float*)take((size_t)NN * sizeof(float));
    int*   gb     = (int*)take((NG + 1) * sizeof(int));
    unsigned* pslots = (unsigned*)take((size_t)NN * CAP * sizeof(unsigned));
    float* statsA = (float*)take(4 * 256 * sizeof(float));
    float* wcat   = (float*)take(6144 * sizeof(float));  // placeholder, unused
    unsigned short* bt1h = (unsigned short*)take(48 * 128 * 2);
    unsigned short* bt1l = (unsigned short*)take(48 * 128 * 2);
    unsigned short* bt3h = (unsigned short*)take(64 * 96 * 2);
    unsigned short* bt3l = (unsigned short*)take(64 * 96 * 2);
    unsigned short* bt4h = (unsigned short*)take(128 * 192 * 2);
    unsigned short* bt4l = (unsigned short*)take(128 * 192 * 2);
    unsigned short* bt5h = (unsigned short*)take(256 * 384 * 2);
    unsigned short* bt5l = (unsigned short*)take(256 * 384 * 2);
    float* partial= (float*)take((size_t)NG * 16 * 512 * sizeof(float));
    unsigned short* P   = (unsigned short*)take((size_t)NN * 48 * 2);
    unsigned short* uv  = (unsigned short*)take((size_t)NN * 32 * 2);
    unsigned short* Hc2 = (unsigned short*)take((size_t)NN * 48 * 2);
    unsigned short* Hc3 = (unsigned short*)take((size_t)NN * 96 * 2);
    unsigned short* Hc4 = (unsigned short*)take((size_t)NN * 192 * 2);
    unsigned short* Hc5 = (unsigned short*)take((size_t)NN * 384 * 2);
    unsigned short* h5  = (unsigned short*)take((size_t)NN * 256 * 2);
    int*   bbase  = (int*)take(NBUCK * sizeof(int));
    (void)wcat;
    // ebuf aliases Hc5: needs NBUCK*MAXBUCK*8 = 19.2MB < Hc5's 38.4MB; dead
    // before k_gemm_mfma_bf(layer 4) first writes Hc5.
    unsigned long long* ebuf = (unsigned long long*)Hc5;

    float* stats1 = statsA;
    float* stats2 = statsA + 256;
    float* stats3 = statsA + 512;
    float* stats4 = statsA + 768;

    hipMemsetAsync(bbase, 0, NBUCK * sizeof(int), stream);
    hipMemsetAsync(statsA, 0, 4 * 256 * sizeof(float), stream);

    // ---- weight prep + graph bounds (single launch)
    k_prep<<<529, 256, 0, stream>>>(W1, W3, W4, W5, batch,
                                    bt1h, bt1l, bt3h, bt3l, bt4h, bt4l,
                                    bt5h, bt5l, gb);

    // ---- adjacency build: bucket-bin (pass 1) + LDS-ranked place (pass 2)
    k_bin<<<256, 256, 0, stream>>>(row, colp, ew, bbase, ebuf);
    k_place<<<NBUCK, 256, 0, stream>>>(bbase, ebuf, cnt, pslots);

    // ---- Layer 1 GEMM (128->48): P = x @ [W0-W2 | W1 | W2]
    k_gemm_mfma_f32A<<<dim3(1, 391), 256, 0, stream>>>(x, 128, bt1h, bt1l, P, 48, NN, 128, 48);

    k_degsum<<<3125, 256, 0, stream>>>(cnt, pslots, dinv);
    k_repack<<<3125, 256, 0, stream>>>(cnt, pslots, dinv);

    // ---- Layer 1 (128->16): h1 = P0 + prop(P1) + 2*prop(prop(P2)) + b
    k_prop<<<1563, 256, 0, stream>>>(cnt, pslots, P, 48, 16, uv, 32, 0, 3, 1.0f,
                                     nullptr, 0, 0, 0.0f, nullptr, 0, 0, nullptr, 0);
    k_prop<<<782, 256, 0, stream>>>(cnt, pslots, uv, 32, 16, Hc2, 48, 0, 2, 2.0f,
                                    P, 48, 0, 1.0f, uv, 32, 0, b1, 1);
    k_bnstats<<<256, 256, 0, stream>>>(Hc2, 48, 4, stats1);
    k_bnapply<<<391, 256, 0, stream>>>(Hc2, 48, 4, stats1, g1, be1);

    // ---- Layer 2 (16->32)
    k_prop<<<782, 256, 0, stream>>>(cnt, pslots, Hc2, 48, 0, Hc2, 48, 16, 2, 1.0f,
                                    nullptr, 0, 0, 0.0f, nullptr, 0, 0, nullptr, 0);
    k_prop<<<782, 256, 0, stream>>>(cnt, pslots, Hc2, 48, 16, Hc2, 48, 32, 2, 2.0f,
                                    Hc2, 48, 0, -1.0f, nullptr, 0, 0, nullptr, 0);
    k_gemm<<<dim3(1, 391), 256, 0, stream>>>(Hc2, 48, W2, 32, Hc3, 96, NN, 48, 32, b2, 1);
    k_bnstats<<<256, 256, 0, stream>>>(Hc3, 96, 5, stats2);
    k_bnapply<<<782, 256, 0, stream>>>(Hc3, 96, 5, stats2, g2, be2);

    // ---- Layer 3 (32->64)
    k_prop<<<1563, 256, 0, stream>>>(cnt, pslots, Hc3, 96, 0, Hc3, 96, 32, 3, 1.0f,
                                     nullptr, 0, 0, 0.0f, nullptr, 0, 0, nullptr, 0);
    k_prop<<<1563, 256, 0, stream>>>(cnt, pslots, Hc3, 96, 32, Hc3, 96, 64, 3, 2.0f,
                                     Hc3, 96, 0, -1.0f, nullptr, 0, 0, nullptr, 0);
    k_gemm_mfma_bf<<<dim3(1, 391), 256, 0, stream>>>(Hc3, 96, bt3h, bt3l, Hc4, 192, NN, 96, 64, b3, 1);
    k_bnstats<<<256, 256, 0, stream>>>(Hc4, 192, 6, stats3);
    k_bnapply<<<1563, 256, 0, stream>>>(Hc4, 192, 6, stats3, g3, be3);

    // ---- Layer 4 (64->128): props on k_prop8 (8 feats/lane, T=8)
    k_prop8<<<1563, 256, 0, stream>>>(cnt, pslots, Hc4, 192, 0, Hc4, 192, 64, 3, 1.0f,
                                      nullptr, 0, 0, 0.0f);
    k_prop8<<<1563, 256, 0, stream>>>(cnt, pslots, Hc4, 192, 64, Hc4, 192, 128, 3, 2.0f,
                                      Hc4, 192, 0, -1.0f);
    k_gemm_mfma_bf<<<dim3(1, 391), 256, 0, stream>>>(Hc4, 192, bt4h, bt4l, Hc5, 384, NN, 192, 128, b4, 1);
    k_bnstats<<<256, 256, 0, stream>>>(Hc5, 384, 7, stats4);
    k_bnapply<<<3125, 256, 0, stream>>>(Hc5, 384, 7, stats4, g4, be4);

    // ---- Layer 5 (128->256): props on k_prop8 (8 feats/lane, T=16)
    k_prop8<<<3125, 256, 0, stream>>>(cnt, pslots, Hc5, 384, 0, Hc5, 384, 128, 4, 1.0f,
                                      nullptr, 0, 0, 0.0f);
    k_prop8<<<3125, 256, 0, stream>>>(cnt, pslots, Hc5, 384, 128, Hc5, 384, 256, 4, 2.0f,
                                      Hc5, 384, 0, -1.0f);
    k_gemm_mfma_bf<<<dim3(2, 391), 256, 0, stream>>>(Hc5, 384, bt5h, bt5l, h5, 256, NN, 384, 256, b5, 0);

    // ---- Pool + dense + log_softmax
    k_pool1<<<dim3(16, 64), 256, 0, stream>>>(h5, gb, partial);
    k_pool2d<<<64, 256, 0, stream>>>(partial, gb, Wd, bd, outp);
}

// Round 7
// 766.876 us; speedup vs baseline: 1.0071x; 1.0071x over previous
//
#include <hip/hip_runtime.h>
#include <hip/hip_fp16.h>
#include <cmath>

#define NN 50000
#define NE 1600000
#define NG 64
#define CAP 96    // slots per row; deg ~ Poisson(32), P(deg>=96) ~ e^-41 -> safe
// Build: two-pass bucketed, NO per-edge global atomics (r15 verified: -31us).
// Ledger: r9 +1.6M atomics=+74us; r12 line-padding=nil (per-op serializer
// ~21G ops/s, ~43B write-through/op); r13 co-residency=nil.
// LESSON: never per-element device-scope atomics on gfx950 — bucket + LDS-rank.
#define BSH 7
#define NBUCK ((NN + (1 << BSH) - 1) >> BSH)   // 391 buckets of 128 rows
#define MAXBUCK 6144                            // mean 4096, sigma ~64 -> safe
// r16 FALSIFIED: us8 16B gathers (4 outstanding misses/wave) made L5 props
// 59.5->67us. LESSON: random-gather kernels are MLP-bound — more smaller
// loads in flight beat fewer wider loads. r17: revert to us4, and push MLP
// the other way: k_prop16 holds 16 slot loads + 16 us4 gathers in flight
// (L4/L5 call sites only; L1-3 keep k_prop byte-identical).
// r11 LESSON (kept): workspace layout is perf-relevant state — all buffer
// addresses byte-identical to the 764us r15 run.

typedef __attribute__((ext_vector_type(8))) short short8_t;
typedef __attribute__((ext_vector_type(4))) float floatx4;
typedef __attribute__((ext_vector_type(4))) unsigned short us4;
typedef __attribute__((ext_vector_type(8))) unsigned short us8;

static __device__ __forceinline__ float softplusf(float x) {
    return fmaxf(x, 0.0f) + log1pf(expf(-fabsf(x)));
}

static __device__ __forceinline__ float bf2f(unsigned short u) {
    return __uint_as_float(((unsigned)u) << 16);
}
static __device__ __forceinline__ unsigned short f2bf(float x) {
    unsigned u = __float_as_uint(x);
    unsigned t = (u >> 16) & 1u;
    return (unsigned short)((u + 0x7FFFu + t) >> 16);  // RNE
}
static __device__ __forceinline__ float h2f(unsigned u) {
    __half_raw r; r.x = (unsigned short)(u & 0xFFFFu);
    return __half2float(__half(r));
}
static __device__ __forceinline__ unsigned short f2h(float x) {
    __half h = __float2half_rn(x);
    return static_cast<__half_raw>(h).x;
}

// exact split x = hi + lo (bf16 each, ~2^-16 relative residual)
static __device__ __forceinline__ void split_bf16(float x, unsigned short& hi, unsigned short& lo) {
    unsigned u = __float_as_uint(x);
    unsigned hb = u & 0xFFFF0000u;
    hi = (unsigned short)(hb >> 16);
    float r = x - __uint_as_float(hb);   // exact
    lo = f2bf(r);
}

static __device__ __forceinline__ int lower_bound_dev(const int* __restrict__ b, int val) {
    int lo = 0, hi = NN;
    while (lo < hi) {
        int mid = (lo + hi) >> 1;
        if (b[mid] < val) lo = mid + 1; else hi = mid;
    }
    return lo;
}

// ---- One-shot prep: all weight splits (layer-1 wcat computed on the fly,
// bit-identical to the old k_wcat1->k_wsplit path) + graph bounds.
__global__ __launch_bounds__(256) void k_prep(
    const float* __restrict__ W1, const float* __restrict__ W3,
    const float* __restrict__ W4, const float* __restrict__ W5,
    const int* __restrict__ batch,
    unsigned short* __restrict__ bt1h, unsigned short* __restrict__ bt1l,
    unsigned short* __restrict__ bt3h, unsigned short* __restrict__ bt3l,
    unsigned short* __restrict__ bt4h, unsigned short* __restrict__ bt4l,
    unsigned short* __restrict__ bt5h, unsigned short* __restrict__ bt5l,
    int* __restrict__ gb)
{
    const int bx = blockIdx.x;
    const int tid = threadIdx.x;
    if (bx < 24) {                       // layer 1: K=128, N=48, wcat on the fly
        int idx = bx * 256 + tid;
        if (idx < 128 * 48) {
            int k = idx / 48, j = idx - k * 48;
            float v;
            if (j < 16)      v = W1[k * 16 + j] - W1[2 * 2048 + k * 16 + j];
            else if (j < 32) v = W1[2048 + k * 16 + (j - 16)];
            else             v = W1[2 * 2048 + k * 16 + (j - 32)];
            unsigned short h, l;
            split_bf16(v, h, l);
            bt1h[(size_t)j * 128 + k] = h;
            bt1l[(size_t)j * 128 + k] = l;
        }
    } else if (bx < 48) {                // layer 3: K=96, N=64
        int idx = (bx - 24) * 256 + tid;
        if (idx < 96 * 64) {
            int k = idx / 64, n = idx - k * 64;
            unsigned short h, l;
            split_bf16(W3[idx], h, l);
            bt3h[(size_t)n * 96 + k] = h;
            bt3l[(size_t)n * 96 + k] = l;
        }
    } else if (bx < 144) {               // layer 4: K=192, N=128
        int idx = (bx - 48) * 256 + tid;
        if (idx < 192 * 128) {
            int k = idx / 128, n = idx - k * 128;
            unsigned short h, l;
            split_bf16(W4[idx], h, l);
            bt4h[(size_t)n * 192 + k] = h;
            bt4l[(size_t)n * 192 + k] = l;
        }
    } else if (bx < 528) {               // layer 5: K=384, N=256
        int idx = (bx - 144) * 256 + tid;
        if (idx < 384 * 256) {
            int k = idx / 256, n = idx - k * 256;
            unsigned short h, l;
            split_bf16(W5[idx], h, l);
            bt5h[(size_t)n * 384 + k] = h;
            bt5l[(size_t)n * 384 + k] = l;
        }
    } else {                             // graph bounds
        int g = tid;
        if (g <= NG) gb[g] = (g == NG) ? NN : lower_bound_dev(batch, g);
    }
}

// ---- Build pass 1: bin edges into NBUCK row-buckets. Per-block LDS
// histogram; ONE global atomic per (block,touched bucket) ~ 100K total.
// ebuf[b*MAXBUCK + i] = (row<<32) | (col<<16) | fp16(w).
__global__ __launch_bounds__(256) void k_bin(const int* __restrict__ row,
                                             const int* __restrict__ col,
                                             const float* __restrict__ w,
                                             int* __restrict__ bbase,
                                             unsigned long long* __restrict__ ebuf) {
    __shared__ int hist[NBUCK];
    __shared__ int base[NBUCK];
    const int t = threadIdx.x;
    const int per = (NE + gridDim.x - 1) / gridDim.x;
    const int e0 = blockIdx.x * per;
    const int e1 = min(e0 + per, NE);
    for (int i = t; i < NBUCK; i += 256) hist[i] = 0;
    __syncthreads();
    for (int e = e0 + t; e < e1; e += 256) atomicAdd(&hist[row[e] >> BSH], 1);
    __syncthreads();
    for (int i = t; i < NBUCK; i += 256) {
        int h = hist[i];
        base[i] = h ? atomicAdd(&bbase[i], h) : 0;
    }
    __syncthreads();
    for (int i = t; i < NBUCK; i += 256) hist[i] = 0;
    __syncthreads();
    for (int e = e0 + t; e < e1; e += 256) {
        int r = row[e];
        int b = r >> BSH;
        int k = atomicAdd(&hist[b], 1);        // LDS: local rank
        int idx = base[b] + k;
        if (idx < MAXBUCK) {                   // defensive (impossible stat.)
            unsigned pay = ((unsigned)col[e] << 16) | (unsigned)f2h(w[e]);
            ebuf[(size_t)b * MAXBUCK + idx] =
                ((unsigned long long)(unsigned)r << 32) | pay;
        }
    }
}

// ---- Build pass 2: one block per bucket; slot ranks via LDS atomics only.
// pslot writes for a bucket land in a 48KB region -> L2-merged full lines.
// Also writes cnt (no global memset needed).
__global__ __launch_bounds__(256) void k_place(const int* __restrict__ bbase,
                                               const unsigned long long* __restrict__ ebuf,
                                               int* __restrict__ cnt,
                                               unsigned* __restrict__ pslots) {
    __shared__ int cl[1 << BSH];
    const int t = threadIdx.x;
    const int b = blockIdx.x;
    if (t < (1 << BSH)) cl[t] = 0;
    __syncthreads();
    const int n = min(bbase[b], MAXBUCK);
    const unsigned long long* eb = ebuf + (size_t)b * MAXBUCK;
    for (int i = t; i < n; i += 256) {
        unsigned long long pk = eb[i];
        int r = (int)(pk >> 32);
        int k = atomicAdd(&cl[r & ((1 << BSH) - 1)], 1);
        k = min(k, CAP - 1);                   // defensive
        pslots[(size_t)r * CAP + k] = (unsigned)pk;
    }
    __syncthreads();
    int r = (b << BSH) + t;
    if (t < (1 << BSH) && r < NN) cnt[r] = min(cl[t], CAP);
}

#define ASTR 40  // padded LDS row stride in ushorts (32 + 8)

// ---------------- MFMA GEMM, fp32 A (3-term split), bf16 C. Layer 1 only.
__global__ __launch_bounds__(256, 2) void k_gemm_mfma_f32A(
    const float* __restrict__ A, int lda,
    const unsigned short* __restrict__ BhiT,
    const unsigned short* __restrict__ BloT,
    unsigned short* __restrict__ C, int ldc,
    int M, int K, int Ncol)
{
    __shared__ unsigned short Ah[128 * ASTR];
    __shared__ unsigned short Al[128 * ASTR];
    __shared__ unsigned short Bh[128 * ASTR];
    __shared__ unsigned short Bl[128 * ASTR];

    const int tid = threadIdx.x;
    const int lane = tid & 63;
    const int wave = tid >> 6;
    const int wm = wave >> 1, wn = wave & 1;
    const int quad = lane >> 4, l16 = lane & 15;
    const int bm = blockIdx.y * 128, bn = blockIdx.x * 128;
    const int srow = tid >> 1;
    const int skq  = (tid & 1) * 16;

    floatx4 acc[4][4];
#pragma unroll
    for (int i = 0; i < 4; ++i)
#pragma unroll
        for (int j = 0; j < 4; ++j) acc[i][j] = (floatx4){0.f, 0.f, 0.f, 0.f};

    for (int k0 = 0; k0 < K; k0 += 32) {
        float4 a0 = make_float4(0, 0, 0, 0), a1 = a0, a2 = a0, a3 = a0;
        const int ga = bm + srow;
        if (ga < M) {
            const float* Ap = A + (size_t)ga * lda + k0 + skq;
            a0 = *(const float4*)(Ap + 0);
            a1 = *(const float4*)(Ap + 4);
            a2 = *(const float4*)(Ap + 8);
            a3 = *(const float4*)(Ap + 12);
        }
        uint4 bh0 = make_uint4(0, 0, 0, 0), bh1 = bh0, bl0 = bh0, bl1 = bh0;
        const int gb2 = bn + srow;
        if (gb2 < Ncol) {
            const unsigned short* ph = BhiT + (size_t)gb2 * K + k0 + skq;
            const unsigned short* pl = BloT + (size_t)gb2 * K + k0 + skq;
            bh0 = *(const uint4*)(ph);
            bh1 = *(const uint4*)(ph + 8);
            bl0 = *(const uint4*)(pl);
            bl1 = *(const uint4*)(pl + 8);
        }
        __attribute__((aligned(16))) unsigned short ah[16], al[16];
        const float av[16] = {a0.x, a0.y, a0.z, a0.w, a1.x, a1.y, a1.z, a1.w,
                              a2.x, a2.y, a2.z, a2.w, a3.x, a3.y, a3.z, a3.w};
#pragma unroll
        for (int i = 0; i < 16; ++i) split_bf16(av[i], ah[i], al[i]);

        __syncthreads();
        *(uint4*)&Ah[srow * ASTR + skq]     = *(const uint4*)&ah[0];
        *(uint4*)&Ah[srow * ASTR + skq + 8] = *(const uint4*)&ah[8];
        *(uint4*)&Al[srow * ASTR + skq]     = *(const uint4*)&al[0];
        *(uint4*)&Al[srow * ASTR + skq + 8] = *(const uint4*)&al[8];
        *(uint4*)&Bh[srow * ASTR + skq]     = bh0;
        *(uint4*)&Bh[srow * ASTR + skq + 8] = bh1;
        *(uint4*)&Bl[srow * ASTR + skq]     = bl0;
        *(uint4*)&Bl[srow * ASTR + skq + 8] = bl1;
        __syncthreads();

        short8_t afh[4], afl[4], bfh[4], bfl[4];
#pragma unroll
        for (int t = 0; t < 4; ++t) {
            const int m = wm * 64 + t * 16 + l16;
            afh[t] = *(const short8_t*)&Ah[m * ASTR + quad * 8];
            afl[t] = *(const short8_t*)&Al[m * ASTR + quad * 8];
            const int n = wn * 64 + t * 16 + l16;
            bfh[t] = *(const short8_t*)&Bh[n * ASTR + quad * 8];
            bfl[t] = *(const short8_t*)&Bl[n * ASTR + quad * 8];
        }
#pragma unroll
        for (int i = 0; i < 4; ++i)
#pragma unroll
            for (int j = 0; j < 4; ++j) {
                acc[i][j] = __builtin_amdgcn_mfma_f32_16x16x32_bf16(afh[i], bfh[j], acc[i][j], 0, 0, 0);
                acc[i][j] = __builtin_amdgcn_mfma_f32_16x16x32_bf16(afh[i], bfl[j], acc[i][j], 0, 0, 0);
                acc[i][j] = __builtin_amdgcn_mfma_f32_16x16x32_bf16(afl[i], bfh[j], acc[i][j], 0, 0, 0);
            }
    }

#pragma unroll
    for (int j = 0; j < 4; ++j) {
        const int colc = bn + wn * 64 + j * 16 + l16;
        if (colc >= Ncol) continue;
#pragma unroll
        for (int i = 0; i < 4; ++i) {
#pragma unroll
            for (int r = 0; r < 4; ++r) {
                const int rowc = bm + wm * 64 + i * 16 + quad * 4 + r;
                if (rowc >= M) continue;
                C[(size_t)rowc * ldc + colc] = f2bf(acc[i][j][r]);
            }
        }
    }
}

// dinv[r] = rsqrt(sum of raw w over row r), 0 if deg<=0 (atomic-free)
__global__ __launch_bounds__(256) void k_degsum(const int* __restrict__ cnt,
                                                const unsigned* __restrict__ pslots,
                                                float* __restrict__ dinv) {
    int tid = threadIdx.x;
    int lane = tid & 15;
    int node = blockIdx.x * 16 + (tid >> 4);
    if (node >= NN) return;
    int e = cnt[node];
    const unsigned* base = pslots + (size_t)node * CAP;
    float s = 0.0f;
    for (int k = lane; k < e; k += 16) s += h2f(base[k]);
#pragma unroll
    for (int m = 8; m >= 1; m >>= 1) s += __shfl_xor(s, m);
    if (lane == 0) dinv[node] = (s > 0.0f) ? rsqrtf(s) : 0.0f;
}

// In-place: weight half of pslot <- fp16(-w * dinv[r] * dinv[col])
__global__ __launch_bounds__(256) void k_repack(const int* __restrict__ cnt,
                                                unsigned* __restrict__ pslots,
                                                const float* __restrict__ dinv) {
    int tid = threadIdx.x;
    int lane = tid & 15;
    int node = blockIdx.x * 16 + (tid >> 4);
    if (node >= NN) return;
    int e = cnt[node];
    float dr = dinv[node];
    unsigned* pb = pslots + (size_t)node * CAP;
    for (int k = lane; k < e; k += 16) {
        unsigned s = pb[k];
        float wv = -h2f(s) * dr * dinv[s >> 16];
        pb[k] = (s & 0xFFFF0000u) | (unsigned)f2h(wv);
    }
}

// ---------------- MFMA GEMM, bf16 A direct (2-term W split). Layers 3/4/5.
__global__ __launch_bounds__(256, 2) void k_gemm_mfma_bf(
    const unsigned short* __restrict__ A, int lda,
    const unsigned short* __restrict__ BhiT,
    const unsigned short* __restrict__ BloT,
    unsigned short* __restrict__ C, int ldc,
    int M, int K, int Ncol,
    const float* __restrict__ bias, int act)
{
    __shared__ unsigned short Ah[128 * ASTR];
    __shared__ unsigned short Bh[128 * ASTR];
    __shared__ unsigned short Bl[128 * ASTR];

    const int tid = threadIdx.x;
    const int lane = tid & 63;
    const int wave = tid >> 6;
    const int wm = wave >> 1, wn = wave & 1;
    const int quad = lane >> 4, l16 = lane & 15;
    const int bm = blockIdx.y * 128, bn = blockIdx.x * 128;
    const int srow = tid >> 1;
    const int skq  = (tid & 1) * 16;

    floatx4 acc[4][4];
#pragma unroll
    for (int i = 0; i < 4; ++i)
#pragma unroll
        for (int j = 0; j < 4; ++j) acc[i][j] = (floatx4){0.f, 0.f, 0.f, 0.f};

    for (int k0 = 0; k0 < K; k0 += 32) {
        uint4 a0 = make_uint4(0, 0, 0, 0), a1 = a0;
        const int ga = bm + srow;
        if (ga < M) {
            const unsigned short* Ap = A + (size_t)ga * lda + k0 + skq;
            a0 = *(const uint4*)(Ap);
            a1 = *(const uint4*)(Ap + 8);
        }
        uint4 bh0 = make_uint4(0, 0, 0, 0), bh1 = bh0, bl0 = bh0, bl1 = bh0;
        const int gb = bn + srow;
        if (gb < Ncol) {
            const unsigned short* ph = BhiT + (size_t)gb * K + k0 + skq;
            const unsigned short* pl = BloT + (size_t)gb * K + k0 + skq;
            bh0 = *(const uint4*)(ph);
            bh1 = *(const uint4*)(ph + 8);
            bl0 = *(const uint4*)(pl);
            bl1 = *(const uint4*)(pl + 8);
        }
        __syncthreads();
        *(uint4*)&Ah[srow * ASTR + skq]     = a0;
        *(uint4*)&Ah[srow * ASTR + skq + 8] = a1;
        *(uint4*)&Bh[srow * ASTR + skq]     = bh0;
        *(uint4*)&Bh[srow * ASTR + skq + 8] = bh1;
        *(uint4*)&Bl[srow * ASTR + skq]     = bl0;
        *(uint4*)&Bl[srow * ASTR + skq + 8] = bl1;
        __syncthreads();

        short8_t afh[4], bfh[4], bfl[4];
#pragma unroll
        for (int t = 0; t < 4; ++t) {
            const int m = wm * 64 + t * 16 + l16;
            afh[t] = *(const short8_t*)&Ah[m * ASTR + quad * 8];
            const int n = wn * 64 + t * 16 + l16;
            bfh[t] = *(const short8_t*)&Bh[n * ASTR + quad * 8];
            bfl[t] = *(const short8_t*)&Bl[n * ASTR + quad * 8];
        }
#pragma unroll
        for (int i = 0; i < 4; ++i)
#pragma unroll
            for (int j = 0; j < 4; ++j) {
                acc[i][j] = __builtin_amdgcn_mfma_f32_16x16x32_bf16(afh[i], bfh[j], acc[i][j], 0, 0, 0);
                acc[i][j] = __builtin_amdgcn_mfma_f32_16x16x32_bf16(afh[i], bfl[j], acc[i][j], 0, 0, 0);
            }
    }

#pragma unroll
    for (int j = 0; j < 4; ++j) {
        const int col = bn + wn * 64 + j * 16 + l16;
        if (col >= Ncol) continue;
        const float bv = bias ? bias[col] : 0.0f;
#pragma unroll
        for (int i = 0; i < 4; ++i) {
#pragma unroll
            for (int r = 0; r < 4; ++r) {
                const int row = bm + wm * 64 + i * 16 + quad * 4 + r;
                if (row >= M) continue;
                float v = acc[i][j][r] + bv;
                if (act) v = softplusf(v);
                C[(size_t)row * ldc + col] = f2bf(v);
            }
        }
    }
}

// fp32-weight vector GEMM with bf16 A and bf16 C (layer 2 only, K=48)
__global__ __launch_bounds__(256) void k_gemm(
    const unsigned short* __restrict__ A, int lda,
    const float* __restrict__ B, int ldb,
    unsigned short* __restrict__ C, int ldc,
    int M, int K, int Ncol,
    const float* __restrict__ bias, int act)
{
    __shared__ float As[16][128];
    __shared__ float Bs[16][128];
    const int tid = threadIdx.x;
    const int tx = tid & 15;
    const int ty = tid >> 4;
    const int bm = blockIdx.y * 128;
    const int bn = blockIdx.x * 128;
    const int arow = tid >> 1;
    const int akq = (tid & 1) * 8;
    const int bkr = tid >> 4;
    const int bcq = (tid & 15) * 8;

    float acc[8][8];
#pragma unroll
    for (int i = 0; i < 8; ++i)
#pragma unroll
        for (int j = 0; j < 8; ++j) acc[i][j] = 0.0f;

    for (int k0 = 0; k0 < K; k0 += 16) {
        uint4 ald = make_uint4(0, 0, 0, 0);
        int gr = bm + arow;
        if (gr < M) ald = *(const uint4*)(A + (size_t)gr * lda + k0 + akq);
        float4 b0 = make_float4(0, 0, 0, 0), b1 = make_float4(0, 0, 0, 0);
        int cb = bn + bcq;
        const float* Bp = B + (k0 + bkr) * ldb;
        if (cb < Ncol)     b0 = *(const float4*)(Bp + cb);
        if (cb + 4 < Ncol) b1 = *(const float4*)(Bp + cb + 4);
        __syncthreads();
        const unsigned short* au = (const unsigned short*)&ald;
#pragma unroll
        for (int i = 0; i < 8; ++i) As[akq + i][arow] = bf2f(au[i]);
        *(float4*)&Bs[bkr][bcq] = b0;
        *(float4*)&Bs[bkr][bcq + 4] = b1;
        __syncthreads();
#pragma unroll
        for (int kk = 0; kk < 16; ++kk) {
            float a[8], b[8];
            float4 t;
            t = *(const float4*)&As[kk][ty * 4];      a[0] = t.x; a[1] = t.y; a[2] = t.z; a[3] = t.w;
            t = *(const float4*)&As[kk][64 + ty * 4]; a[4] = t.x; a[5] = t.y; a[6] = t.z; a[7] = t.w;
            t = *(const float4*)&Bs[kk][tx * 4];      b[0] = t.x; b[1] = t.y; b[2] = t.z; b[3] = t.w;
            t = *(const float4*)&Bs[kk][64 + tx * 4]; b[4] = t.x; b[5] = t.y; b[6] = t.z; b[7] = t.w;
#pragma unroll
            for (int i = 0; i < 8; ++i)
#pragma unroll
                for (int j = 0; j < 8; ++j)
                    acc[i][j] = fmaf(a[i], b[j], acc[i][j]);
        }
    }
#pragma unroll
    for (int i = 0; i < 8; ++i) {
        int r = bm + ((i < 4) ? (ty * 4 + i) : (64 + ty * 4 + i - 4));
        if (r >= M) continue;
#pragma unroll
        for (int j = 0; j < 8; ++j) {
            int cl = bn + ((j < 4) ? (tx * 4 + j) : (64 + tx * 4 + j - 4));
            if (cl >= Ncol) continue;
            float v = acc[i][j];
            if (bias) v += bias[cl];
            if (act) v = softplusf(v);
            C[(size_t)r * ldc + cl] = f2bf(v);
        }
    }
}

// Slotted propagation, 4 bf16 feats/lane (us4 8B gathers), 8 edges in flight.
// Layers 1-3 (proven r8 structure).
__global__ __launch_bounds__(256) void k_prop(
    const int* __restrict__ cnt, const unsigned* __restrict__ pslots,
    const unsigned short* __restrict__ z, int zld, int zoff,
    unsigned short* __restrict__ out, int outld, int ooff,
    int ltw, float alpha,
    const unsigned short* __restrict__ add1, int a1ld, int a1off, float c1,
    const unsigned short* __restrict__ add2, int a2ld, int a2off,
    const float* __restrict__ bias, int act)
{
    const int T = 1 << ltw;
    const int lane = threadIdx.x & (T - 1);
    const int node = blockIdx.x * (256 >> ltw) + (threadIdx.x >> ltw);
    if (node >= NN) return;
    const int f4 = lane * 4;
    const int e = cnt[node];
    const unsigned* base = pslots + (size_t)node * CAP;
    float accA[4] = {0, 0, 0, 0};
    float accB[4] = {0, 0, 0, 0};
    const unsigned short* zp = z + zoff + f4;
    int p = 0;
    for (; p + 8 <= e; p += 8) {
        unsigned s0 = base[p + 0], s1 = base[p + 1], s2 = base[p + 2], s3 = base[p + 3];
        unsigned s4 = base[p + 4], s5 = base[p + 5], s6 = base[p + 6], s7 = base[p + 7];
        const us4 z0 = *(const us4*)(zp + (size_t)(s0 >> 16) * zld);
        const us4 z1 = *(const us4*)(zp + (size_t)(s1 >> 16) * zld);
        const us4 z2 = *(const us4*)(zp + (size_t)(s2 >> 16) * zld);
        const us4 z3 = *(const us4*)(zp + (size_t)(s3 >> 16) * zld);
        const us4 z4 = *(const us4*)(zp + (size_t)(s4 >> 16) * zld);
        const us4 z5 = *(const us4*)(zp + (size_t)(s5 >> 16) * zld);
        const us4 z6 = *(const us4*)(zp + (size_t)(s6 >> 16) * zld);
        const us4 z7 = *(const us4*)(zp + (size_t)(s7 >> 16) * zld);
        float w0 = h2f(s0), w1 = h2f(s1), w2 = h2f(s2), w3 = h2f(s3);
        float w4 = h2f(s4), w5 = h2f(s5), w6 = h2f(s6), w7 = h2f(s7);
#pragma unroll
        for (int i = 0; i < 4; ++i) {
            accA[i] = fmaf(w0, bf2f(z0[i]), accA[i]);
            accB[i] = fmaf(w1, bf2f(z1[i]), accB[i]);
            accA[i] = fmaf(w2, bf2f(z2[i]), accA[i]);
            accB[i] = fmaf(w3, bf2f(z3[i]), accB[i]);
            accA[i] = fmaf(w4, bf2f(z4[i]), accA[i]);
            accB[i] = fmaf(w5, bf2f(z5[i]), accB[i]);
            accA[i] = fmaf(w6, bf2f(z6[i]), accA[i]);
            accB[i] = fmaf(w7, bf2f(z7[i]), accB[i]);
        }
    }
    for (; p + 4 <= e; p += 4) {
        unsigned s0 = base[p + 0], s1 = base[p + 1], s2 = base[p + 2], s3 = base[p + 3];
        const us4 z0 = *(const us4*)(zp + (size_t)(s0 >> 16) * zld);
        const us4 z1 = *(const us4*)(zp + (size_t)(s1 >> 16) * zld);
        const us4 z2 = *(const us4*)(zp + (size_t)(s2 >> 16) * zld);
        const us4 z3 = *(const us4*)(zp + (size_t)(s3 >> 16) * zld);
        float w0 = h2f(s0), w1 = h2f(s1), w2 = h2f(s2), w3 = h2f(s3);
#pragma unroll
        for (int i = 0; i < 4; ++i) {
            accA[i] = fmaf(w0, bf2f(z0[i]), accA[i]);
            accB[i] = fmaf(w1, bf2f(z1[i]), accB[i]);
            accA[i] = fmaf(w2, bf2f(z2[i]), accA[i]);
            accB[i] = fmaf(w3, bf2f(z3[i]), accB[i]);
        }
    }
    for (; p < e; ++p) {
        unsigned s = base[p];
        float wv = h2f(s);
        const us4 zv = *(const us4*)(zp + (size_t)(s >> 16) * zld);
#pragma unroll
        for (int i = 0; i < 4; ++i) accA[i] = fmaf(wv, bf2f(zv[i]), accA[i]);
    }
#pragma unroll
    for (int i = 0; i < 4; ++i) accA[i] = alpha * (accA[i] + accB[i]);
    if (add1) {
        const us4 t = *(const us4*)(add1 + (size_t)node * a1ld + a1off + f4);
#pragma unroll
        for (int i = 0; i < 4; ++i) accA[i] = fmaf(c1, bf2f(t[i]), accA[i]);
    }
    if (add2) {
        const us4 t = *(const us4*)(add2 + (size_t)node * a2ld + a2off + f4);
#pragma unroll
        for (int i = 0; i < 4; ++i) accA[i] += bf2f(t[i]);
    }
    if (bias) {
        const float4 t = *(const float4*)(bias + f4);
        accA[0] += t.x; accA[1] += t.y; accA[2] += t.z; accA[3] += t.w;
    }
    if (act) {
#pragma unroll
        for (int i = 0; i < 4; ++i) accA[i] = softplusf(accA[i]);
    }
    us4 o;
#pragma unroll
    for (int i = 0; i < 4; ++i) o[i] = f2bf(accA[i]);
    *(us4*)(out + (size_t)node * outld + ooff + f4) = o;
}

// r17: same math/layout as k_prop but 16 edges in flight (16 slot loads +
// 16 us4 gathers) — MLP experiment (r16 showed gather throughput tracks
// outstanding misses). Fully unrolled, compile-time indices only (no scratch).
// L4/L5 call sites only.
__global__ __launch_bounds__(256) void k_prop16(
    const int* __restrict__ cnt, const unsigned* __restrict__ pslots,
    const unsigned short* __restrict__ z, int zld, int zoff,
    unsigned short* __restrict__ out, int outld, int ooff,
    int ltw, float alpha,
    const unsigned short* __restrict__ add1, int a1ld, int a1off, float c1)
{
    const int T = 1 << ltw;
    const int lane = threadIdx.x & (T - 1);
    const int node = blockIdx.x * (256 >> ltw) + (threadIdx.x >> ltw);
    if (node >= NN) return;
    const int f4 = lane * 4;
    const int e = cnt[node];
    const unsigned* base = pslots + (size_t)node * CAP;
    float accA[4] = {0, 0, 0, 0};
    float accB[4] = {0, 0, 0, 0};
    const unsigned short* zp = z + zoff + f4;
    int p = 0;
    for (; p + 16 <= e; p += 16) {
        unsigned s[16];
#pragma unroll
        for (int q = 0; q < 16; ++q) s[q] = base[p + q];
        us4 zv[16];
#pragma unroll
        for (int q = 0; q < 16; ++q)
            zv[q] = *(const us4*)(zp + (size_t)(s[q] >> 16) * zld);
#pragma unroll
        for (int q = 0; q < 16; q += 2) {
            float wa = h2f(s[q]), wb = h2f(s[q + 1]);
#pragma unroll
            for (int i = 0; i < 4; ++i) {
                accA[i] = fmaf(wa, bf2f(zv[q][i]), accA[i]);
                accB[i] = fmaf(wb, bf2f(zv[q + 1][i]), accB[i]);
            }
        }
    }
    for (; p + 8 <= e; p += 8) {
        unsigned s0 = base[p + 0], s1 = base[p + 1], s2 = base[p + 2], s3 = base[p + 3];
        unsigned s4 = base[p + 4], s5 = base[p + 5], s6 = base[p + 6], s7 = base[p + 7];
        const us4 z0 = *(const us4*)(zp + (size_t)(s0 >> 16) * zld);
        const us4 z1 = *(const us4*)(zp + (size_t)(s1 >> 16) * zld);
        const us4 z2 = *(const us4*)(zp + (size_t)(s2 >> 16) * zld);
        const us4 z3 = *(const us4*)(zp + (size_t)(s3 >> 16) * zld);
        const us4 z4 = *(const us4*)(zp + (size_t)(s4 >> 16) * zld);
        const us4 z5 = *(const us4*)(zp + (size_t)(s5 >> 16) * zld);
        const us4 z6 = *(const us4*)(zp + (size_t)(s6 >> 16) * zld);
        const us4 z7 = *(const us4*)(zp + (size_t)(s7 >> 16) * zld);
        float w0 = h2f(s0), w1 = h2f(s1), w2 = h2f(s2), w3 = h2f(s3);
        float w4 = h2f(s4), w5 = h2f(s5), w6 = h2f(s6), w7 = h2f(s7);
#pragma unroll
        for (int i = 0; i < 4; ++i) {
            accA[i] = fmaf(w0, bf2f(z0[i]), accA[i]);
            accB[i] = fmaf(w1, bf2f(z1[i]), accB[i]);
            accA[i] = fmaf(w2, bf2f(z2[i]), accA[i]);
            accB[i] = fmaf(w3, bf2f(z3[i]), accB[i]);
            accA[i] = fmaf(w4, bf2f(z4[i]), accA[i]);
            accB[i] = fmaf(w5, bf2f(z5[i]), accB[i]);
            accA[i] = fmaf(w6, bf2f(z6[i]), accA[i]);
            accB[i] = fmaf(w7, bf2f(z7[i]), accB[i]);
        }
    }
    for (; p + 4 <= e; p += 4) {
        unsigned s0 = base[p + 0], s1 = base[p + 1], s2 = base[p + 2], s3 = base[p + 3];
        const us4 z0 = *(const us4*)(zp + (size_t)(s0 >> 16) * zld);
        const us4 z1 = *(const us4*)(zp + (size_t)(s1 >> 16) * zld);
        const us4 z2 = *(const us4*)(zp + (size_t)(s2 >> 16) * zld);
        const us4 z3 = *(const us4*)(zp + (size_t)(s3 >> 16) * zld);
        float w0 = h2f(s0), w1 = h2f(s1), w2 = h2f(s2), w3 = h2f(s3);
#pragma unroll
        for (int i = 0; i < 4; ++i) {
            accA[i] = fmaf(w0, bf2f(z0[i]), accA[i]);
            accB[i] = fmaf(w1, bf2f(z1[i]), accB[i]);
            accA[i] = fmaf(w2, bf2f(z2[i]), accA[i]);
            accB[i] = fmaf(w3, bf2f(z3[i]), accB[i]);
        }
    }
    for (; p < e; ++p) {
        unsigned s = base[p];
        float wv = h2f(s);
        const us4 zv = *(const us4*)(zp + (size_t)(s >> 16) * zld);
#pragma unroll
        for (int i = 0; i < 4; ++i) accA[i] = fmaf(wv, bf2f(zv[i]), accA[i]);
    }
#pragma unroll
    for (int i = 0; i < 4; ++i) accA[i] = alpha * (accA[i] + accB[i]);
    if (add1) {
        const us4 t = *(const us4*)(add1 + (size_t)node * a1ld + a1off + f4);
#pragma unroll
        for (int i = 0; i < 4; ++i) accA[i] = fmaf(c1, bf2f(t[i]), accA[i]);
    }
    us4 o;
#pragma unroll
    for (int i = 0; i < 4; ++i) o[i] = f2bf(accA[i]);
    *(us4*)(out + (size_t)node * outld + ooff + f4) = o;
}

__global__ __launch_bounds__(256) void k_bnstats(const unsigned short* __restrict__ h, int ld, int lc,
                                                 float* __restrict__ stats) {
    const int C = 1 << lc;
    const int tid = threadIdx.x;
    const int c = tid & (C - 1);
    const int rpb = 256 >> lc;
    int r = blockIdx.x * rpb + (tid >> lc);
    const int stride = gridDim.x * rpb;
    float s = 0.0f, q = 0.0f;
    for (; r < NN; r += stride) {
        float v = bf2f(h[(size_t)r * ld + c]);
        s += v;
        q = fmaf(v, v, q);
    }
    __shared__ float shs[256], shq[256];
    shs[tid] = s; shq[tid] = q;
    __syncthreads();
    for (int o = 128; o >= C; o >>= 1) {
        if (tid < o) { shs[tid] += shs[tid + o]; shq[tid] += shq[tid + o]; }
        __syncthreads();
    }
    if (tid < C) {
        atomicAdd(&stats[c], shs[tid]);
        atomicAdd(&stats[128 + c], shq[tid]);
    }
}

// Vectorized BN apply: 8 elems/thread.
__global__ void k_bnapply(unsigned short* __restrict__ h, int ld, int lc,
                          const float* __restrict__ stats,
                          const float* __restrict__ g, const float* __restrict__ be) {
    int idx = blockIdx.x * 256 + threadIdx.x;        // in units of 8 elems
    const int C8 = 1 << (lc - 3);
    if (idx >= NN * C8) return;
    int r = idx >> (lc - 3);
    int c0 = (idx & (C8 - 1)) << 3;
    const float invN = 1.0f / (float)NN;
    unsigned short* hp = h + (size_t)r * ld + c0;
    us8 v = *(const us8*)hp;
    us8 o;
#pragma unroll
    for (int i = 0; i < 8; ++i) {
        int c = c0 + i;
        float m = stats[c] * invN;
        float var = fmaf(stats[128 + c], invN, -m * m);
        var = fmaxf(var, 0.0f);
        float inv = rsqrtf(var + 1e-5f);
        o[i] = f2bf(fmaf(g[c] * inv, bf2f(v[i]) - m, be[c]));
    }
    *(us8*)hp = o;
}

// Pool stage 1 over bf16 h5.
__global__ __launch_bounds__(256) void k_pool1(const unsigned short* __restrict__ h,
                                               const int* __restrict__ gb,
                                               float* __restrict__ partial) {
    int g = blockIdx.y;
    int j = blockIdx.x;
    int start = gb[g], end = gb[g + 1];
    int len = end - start;
    int chunk = (len + 15) >> 4;
    int s = start + j * chunk;
    int e = min(s + chunk, end);
    int c = threadIdx.x;
    float mx = -INFINITY, sum = 0.0f;
    for (int r = s; r < e; ++r) {
        float v = bf2f(h[(size_t)r * 256 + c]);
        mx = fmaxf(mx, v);
        sum += v;
    }
    size_t base = ((size_t)(g * 16 + j)) * 512;
    partial[base + c] = mx;
    partial[base + 256 + c] = sum;
}

// Fused pool stage 2 + dense + log_softmax: 64 blocks.
__global__ __launch_bounds__(256) void k_pool2d(const float* __restrict__ partial,
                                                const int* __restrict__ gb,
                                                const float* __restrict__ Wd,
                                                const float* __restrict__ bd,
                                                float* __restrict__ out) {
    __shared__ float pl[512];
    __shared__ float red[4][256];
    int g = blockIdx.x;
    int c = threadIdx.x;
    float mx = -INFINITY, sum = 0.0f;
#pragma unroll
    for (int j = 0; j < 16; ++j) {
        size_t base = ((size_t)(g * 16 + j)) * 512;
        mx = fmaxf(mx, partial[base + c]);
        sum += partial[base + 256 + c];
    }
    int len = gb[g + 1] - gb[g];
    pl[c] = (len > 0) ? mx : 0.0f;
    pl[256 + c] = sum / fmaxf((float)len, 1.0f);
    __syncthreads();
    float p[4] = {0, 0, 0, 0};
    for (int k = c; k < 512; k += 256) {
        float pv = pl[k];
#pragma unroll
        for (int cc = 0; cc < 4; ++cc) p[cc] = fmaf(pv, Wd[k * 4 + cc], p[cc]);
    }
#pragma unroll
    for (int cc = 0; cc < 4; ++cc) red[cc][c] = p[cc];
    __syncthreads();
    for (int o = 128; o >= 1; o >>= 1) {
        if (c < o) {
#pragma unroll
            for (int cc = 0; cc < 4; ++cc) red[cc][c] += red[cc][c + o];
        }
        __syncthreads();
    }
    if (c == 0) {
        float l0 = red[0][0] + bd[0], l1 = red[1][0] + bd[1];
        float l2 = red[2][0] + bd[2], l3 = red[3][0] + bd[3];
        float m = fmaxf(fmaxf(l0, l1), fmaxf(l2, l3));
        float ls = m + logf(expf(l0 - m) + expf(l1 - m) + expf(l2 - m) + expf(l3 - m));
        out[g * 4 + 0] = l0 - ls;
        out[g * 4 + 1] = l1 - ls;
        out[g * 4 + 2] = l2 - ls;
        out[g * 4 + 3] = l3 - ls;
    }
}

extern "C" void kernel_launch(void* const* d_in, const int* in_sizes, int n_in,
                              void* d_out, int out_size, void* d_ws, size_t ws_size,
                              hipStream_t stream)
{
    const float* x    = (const float*)d_in[0];
    const float* ew   = (const float*)d_in[1];
    const int*   row  = (const int*)d_in[2];
    const int*   colp = row + NE;
    const int*   batch = (const int*)d_in[3];
    const float* W1 = (const float*)d_in[4];
    const float* b1 = (const float*)d_in[5];
    const float* g1 = (const float*)d_in[6];
    const float* be1 = (const float*)d_in[7];
    const float* W2 = (const float*)d_in[8];
    const float* b2 = (const float*)d_in[9];
    const float* g2 = (const float*)d_in[10];
    const float* be2 = (const float*)d_in[11];
    const float* W3 = (const float*)d_in[12];
    const float* b3 = (const float*)d_in[13];
    const float* g3 = (const float*)d_in[14];
    const float* be3 = (const float*)d_in[15];
    const float* W4 = (const float*)d_in[16];
    const float* b4 = (const float*)d_in[17];
    const float* g4 = (const float*)d_in[18];
    const float* be4 = (const float*)d_in[19];
    const float* W5 = (const float*)d_in[20];
    const float* b5 = (const float*)d_in[21];
    const float* Wd = (const float*)d_in[22];
    const float* bd = (const float*)d_in[23];
    float* outp = (float*)d_out;
    (void)in_sizes; (void)n_in; (void)out_size; (void)ws_size; (void)ew;

    char* wsb = (char*)d_ws;
    size_t off = 0;
    auto take = [&](size_t bytes) -> void* {
        void* p = wsb + off;
        off = (off + bytes + 255) & ~(size_t)255;
        return p;
    };
    // Layout byte-identical to the 764us r15 run (r11 lesson).
    int*   cnt    = (int*)take((size_t)NN * sizeof(int));
    float* dinv   = (float*)take((size_t)NN * sizeof(float));
    int*   gb     = (int*)take((NG + 1) * sizeof(int));
    unsigned* pslots = (unsigned*)take((size_t)NN * CAP * sizeof(unsigned));
    float* statsA = (float*)take(4 * 256 * sizeof(float));
    float* wcat   = (float*)take(6144 * sizeof(float));  // placeholder, unused
    unsigned short* bt1h = (unsigned short*)take(48 * 128 * 2);
    unsigned short* bt1l = (unsigned short*)take(48 * 128 * 2);
    unsigned short* bt3h = (unsigned short*)take(64 * 96 * 2);
    unsigned short* bt3l = (unsigned short*)take(64 * 96 * 2);
    unsigned short* bt4h = (unsigned short*)take(128 * 192 * 2);
    unsigned short* bt4l = (unsigned short*)take(128 * 192 * 2);
    unsigned short* bt5h = (unsigned short*)take(256 * 384 * 2);
    unsigned short* bt5l = (unsigned short*)take(256 * 384 * 2);
    float* partial= (float*)take((size_t)NG * 16 * 512 * sizeof(float));
    unsigned short* P   = (unsigned short*)take((size_t)NN * 48 * 2);
    unsigned short* uv  = (unsigned short*)take((size_t)NN * 32 * 2);
    unsigned short* Hc2 = (unsigned short*)take((size_t)NN * 48 * 2);
    unsigned short* Hc3 = (unsigned short*)take((size_t)NN * 96 * 2);
    unsigned short* Hc4 = (unsigned short*)take((size_t)NN * 192 * 2);
    unsigned short* Hc5 = (unsigned short*)take((size_t)NN * 384 * 2);
    unsigned short* h5  = (unsigned short*)take((size_t)NN * 256 * 2);
    int*   bbase  = (int*)take(NBUCK * sizeof(int));
    (void)wcat;
    // ebuf aliases Hc5: needs NBUCK*MAXBUCK*8 = 19.2MB < Hc5's 38.4MB; dead
    // before k_gemm_mfma_bf(layer 4) first writes Hc5.
    unsigned long long* ebuf = (unsigned long long*)Hc5;

    float* stats1 = statsA;
    float* stats2 = statsA + 256;
    float* stats3 = statsA + 512;
    float* stats4 = statsA + 768;

    hipMemsetAsync(bbase, 0, NBUCK * sizeof(int), stream);
    hipMemsetAsync(statsA, 0, 4 * 256 * sizeof(float), stream);

    // ---- weight prep + graph bounds (single launch)
    k_prep<<<529, 256, 0, stream>>>(W1, W3, W4, W5, batch,
                                    bt1h, bt1l, bt3h, bt3l, bt4h, bt4l,
                                    bt5h, bt5l, gb);

    // ---- adjacency build: bucket-bin (pass 1) + LDS-ranked place (pass 2)
    k_bin<<<256, 256, 0, stream>>>(row, colp, ew, bbase, ebuf);
    k_place<<<NBUCK, 256, 0, stream>>>(bbase, ebuf, cnt, pslots);

    // ---- Layer 1 GEMM (128->48): P = x @ [W0-W2 | W1 | W2]
    k_gemm_mfma_f32A<<<dim3(1, 391), 256, 0, stream>>>(x, 128, bt1h, bt1l, P, 48, NN, 128, 48);

    k_degsum<<<3125, 256, 0, stream>>>(cnt, pslots, dinv);
    k_repack<<<3125, 256, 0, stream>>>(cnt, pslots, dinv);

    // ---- Layer 1 (128->16): h1 = P0 + prop(P1) + 2*prop(prop(P2)) + b
    k_prop<<<1563, 256, 0, stream>>>(cnt, pslots, P, 48, 16, uv, 32, 0, 3, 1.0f,
                                     nullptr, 0, 0, 0.0f, nullptr, 0, 0, nullptr, 0);
    k_prop<<<782, 256, 0, stream>>>(cnt, pslots, uv, 32, 16, Hc2, 48, 0, 2, 2.0f,
                                    P, 48, 0, 1.0f, uv, 32, 0, b1, 1);
    k_bnstats<<<256, 256, 0, stream>>>(Hc2, 48, 4, stats1);
    k_bnapply<<<391, 256, 0, stream>>>(Hc2, 48, 4, stats1, g1, be1);

    // ---- Layer 2 (16->32)
    k_prop<<<782, 256, 0, stream>>>(cnt, pslots, Hc2, 48, 0, Hc2, 48, 16, 2, 1.0f,
                                    nullptr, 0, 0, 0.0f, nullptr, 0, 0, nullptr, 0);
    k_prop<<<782, 256, 0, stream>>>(cnt, pslots, Hc2, 48, 16, Hc2, 48, 32, 2, 2.0f,
                                    Hc2, 48, 0, -1.0f, nullptr, 0, 0, nullptr, 0);
    k_gemm<<<dim3(1, 391), 256, 0, stream>>>(Hc2, 48, W2, 32, Hc3, 96, NN, 48, 32, b2, 1);
    k_bnstats<<<256, 256, 0, stream>>>(Hc3, 96, 5, stats2);
    k_bnapply<<<782, 256, 0, stream>>>(Hc3, 96, 5, stats2, g2, be2);

    // ---- Layer 3 (32->64)
    k_prop<<<1563, 256, 0, stream>>>(cnt, pslots, Hc3, 96, 0, Hc3, 96, 32, 3, 1.0f,
                                     nullptr, 0, 0, 0.0f, nullptr, 0, 0, nullptr, 0);
    k_prop<<<1563, 256, 0, stream>>>(cnt, pslots, Hc3, 96, 32, Hc3, 96, 64, 3, 2.0f,
                                     Hc3, 96, 0, -1.0f, nullptr, 0, 0, nullptr, 0);
    k_gemm_mfma_bf<<<dim3(1, 391), 256, 0, stream>>>(Hc3, 96, bt3h, bt3l, Hc4, 192, NN, 96, 64, b3, 1);
    k_bnstats<<<256, 256, 0, stream>>>(Hc4, 192, 6, stats3);
    k_bnapply<<<1563, 256, 0, stream>>>(Hc4, 192, 6, stats3, g3, be3);

    // ---- Layer 4 (64->128): props on k_prop16 (us4, 16 edges in flight)
    k_prop16<<<3125, 256, 0, stream>>>(cnt, pslots, Hc4, 192, 0, Hc4, 192, 64, 4, 1.0f,
                                       nullptr, 0, 0, 0.0f);
    k_prop16<<<3125, 256, 0, stream>>>(cnt, pslots, Hc4, 192, 64, Hc4, 192, 128, 4, 2.0f,
                                       Hc4, 192, 0, -1.0f);
    k_gemm_mfma_bf<<<dim3(1, 391), 256, 0, stream>>>(Hc4, 192, bt4h, bt4l, Hc5, 384, NN, 192, 128, b4, 1);
    k_bnstats<<<256, 256, 0, stream>>>(Hc5, 384, 7, stats4);
    k_bnapply<<<3125, 256, 0, stream>>>(Hc5, 384, 7, stats4, g4, be4);

    // ---- Layer 5 (128->256): props on k_prop16 (us4, 16 edges in flight)
    k_prop16<<<6250, 256, 0, stream>>>(cnt, pslots, Hc5, 384, 0, Hc5, 384, 128, 5, 1.0f,
                                       nullptr, 0, 0, 0.0f);
    k_prop16<<<6250, 256, 0, stream>>>(cnt, pslots, Hc5, 384, 128, Hc5, 384, 256, 5, 2.0f,
                                       Hc5, 384, 0, -1.0f);
    k_gemm_mfma_bf<<<dim3(2, 391), 256, 0, stream>>>(Hc5, 384, bt5h, bt5l, h5, 256, NN, 384, 256, b5, 0);

    // ---- Pool + dense + log_softmax
    k_pool1<<<dim3(16, 64), 256, 0, stream>>>(h5, gb, partial);
    k_pool2d<<<64, 256, 0, stream>>>(partial, gb, Wd, bd, outp);
}

// Round 8
// 764.735 us; speedup vs baseline: 1.0099x; 1.0028x over previous
//
#include <hip/hip_runtime.h>
#include <hip/hip_fp16.h>
#include <cmath>

#define NN 50000
#define NE 1600000
#define NG 64
#define CAP 96    // slots per row; deg ~ Poisson(32), P(deg>=96) ~ e^-41 -> safe
// Build: two-pass bucketed, NO per-edge global atomics (r15 verified: -31us).
// Ledger: r9 +1.6M atomics=+74us; r12 line-padding=nil (per-op serializer
// ~21G ops/s, ~43B write-through/op); r13 co-residency=nil.
// LESSON: never per-element device-scope atomics on gfx950 — bucket + LDS-rank.
#define BSH 7
#define NBUCK ((NN + (1 << BSH) - 1) >> BSH)   // 391 buckets of 128 rows
#define MAXBUCK 6144                            // mean 4096, sigma ~64 -> safe
// Prop ladder: r16 us8 (4-deep) = WORSE (59.5->67us); r17 16-deep = flat.
// LESSON: random gather saturates at <=8 outstanding misses/wave; limiter is
// miss-rate x latency. Per-XCD hit rate is at its compulsory ceiling (reuse
// ~4x, hit 68% vs 75% ceiling) under full-width gather.
// r18: L5 2-way feature-slice with XCD-aware mapping (blockIdx%8 = XCD):
// XCDs 0-3 own feats[0:64), 4-7 own [64:128) -> per-XCD WS 12.8->6.4MB,
// reuse 4->8. Cost: pslots read 2x, VALU +~11%. L4 excluded (64B sub-slices
// share cache lines -> slicing inflates line accesses).
// r11 LESSON (kept): workspace layout is perf-relevant state — all buffer
// addresses byte-identical to the 764us r15 run.

typedef __attribute__((ext_vector_type(8))) short short8_t;
typedef __attribute__((ext_vector_type(4))) float floatx4;
typedef __attribute__((ext_vector_type(4))) unsigned short us4;
typedef __attribute__((ext_vector_type(8))) unsigned short us8;

static __device__ __forceinline__ float softplusf(float x) {
    return fmaxf(x, 0.0f) + log1pf(expf(-fabsf(x)));
}

static __device__ __forceinline__ float bf2f(unsigned short u) {
    return __uint_as_float(((unsigned)u) << 16);
}
static __device__ __forceinline__ unsigned short f2bf(float x) {
    unsigned u = __float_as_uint(x);
    unsigned t = (u >> 16) & 1u;
    return (unsigned short)((u + 0x7FFFu + t) >> 16);  // RNE
}
static __device__ __forceinline__ float h2f(unsigned u) {
    __half_raw r; r.x = (unsigned short)(u & 0xFFFFu);
    return __half2float(__half(r));
}
static __device__ __forceinline__ unsigned short f2h(float x) {
    __half h = __float2half_rn(x);
    return static_cast<__half_raw>(h).x;
}

// exact split x = hi + lo (bf16 each, ~2^-16 relative residual)
static __device__ __forceinline__ void split_bf16(float x, unsigned short& hi, unsigned short& lo) {
    unsigned u = __float_as_uint(x);
    unsigned hb = u & 0xFFFF0000u;
    hi = (unsigned short)(hb >> 16);
    float r = x - __uint_as_float(hb);   // exact
    lo = f2bf(r);
}

static __device__ __forceinline__ int lower_bound_dev(const int* __restrict__ b, int val) {
    int lo = 0, hi = NN;
    while (lo < hi) {
        int mid = (lo + hi) >> 1;
        if (b[mid] < val) lo = mid + 1; else hi = mid;
    }
    return lo;
}

// ---- One-shot prep: all weight splits (layer-1 wcat computed on the fly,
// bit-identical to the old k_wcat1->k_wsplit path) + graph bounds.
__global__ __launch_bounds__(256) void k_prep(
    const float* __restrict__ W1, const float* __restrict__ W3,
    const float* __restrict__ W4, const float* __restrict__ W5,
    const int* __restrict__ batch,
    unsigned short* __restrict__ bt1h, unsigned short* __restrict__ bt1l,
    unsigned short* __restrict__ bt3h, unsigned short* __restrict__ bt3l,
    unsigned short* __restrict__ bt4h, unsigned short* __restrict__ bt4l,
    unsigned short* __restrict__ bt5h, unsigned short* __restrict__ bt5l,
    int* __restrict__ gb)
{
    const int bx = blockIdx.x;
    const int tid = threadIdx.x;
    if (bx < 24) {                       // layer 1: K=128, N=48, wcat on the fly
        int idx = bx * 256 + tid;
        if (idx < 128 * 48) {
            int k = idx / 48, j = idx - k * 48;
            float v;
            if (j < 16)      v = W1[k * 16 + j] - W1[2 * 2048 + k * 16 + j];
            else if (j < 32) v = W1[2048 + k * 16 + (j - 16)];
            else             v = W1[2 * 2048 + k * 16 + (j - 32)];
            unsigned short h, l;
            split_bf16(v, h, l);
            bt1h[(size_t)j * 128 + k] = h;
            bt1l[(size_t)j * 128 + k] = l;
        }
    } else if (bx < 48) {                // layer 3: K=96, N=64
        int idx = (bx - 24) * 256 + tid;
        if (idx < 96 * 64) {
            int k = idx / 64, n = idx - k * 64;
            unsigned short h, l;
            split_bf16(W3[idx], h, l);
            bt3h[(size_t)n * 96 + k] = h;
            bt3l[(size_t)n * 96 + k] = l;
        }
    } else if (bx < 144) {               // layer 4: K=192, N=128
        int idx = (bx - 48) * 256 + tid;
        if (idx < 192 * 128) {
            int k = idx / 128, n = idx - k * 128;
            unsigned short h, l;
            split_bf16(W4[idx], h, l);
            bt4h[(size_t)n * 192 + k] = h;
            bt4l[(size_t)n * 192 + k] = l;
        }
    } else if (bx < 528) {               // layer 5: K=384, N=256
        int idx = (bx - 144) * 256 + tid;
        if (idx < 384 * 256) {
            int k = idx / 256, n = idx - k * 256;
            unsigned short h, l;
            split_bf16(W5[idx], h, l);
            bt5h[(size_t)n * 384 + k] = h;
            bt5l[(size_t)n * 384 + k] = l;
        }
    } else {                             // graph bounds
        int g = tid;
        if (g <= NG) gb[g] = (g == NG) ? NN : lower_bound_dev(batch, g);
    }
}

// ---- Build pass 1: bin edges into NBUCK row-buckets. Per-block LDS
// histogram; ONE global atomic per (block,touched bucket) ~ 100K total.
// ebuf[b*MAXBUCK + i] = (row<<32) | (col<<16) | fp16(w).
__global__ __launch_bounds__(256) void k_bin(const int* __restrict__ row,
                                             const int* __restrict__ col,
                                             const float* __restrict__ w,
                                             int* __restrict__ bbase,
                                             unsigned long long* __restrict__ ebuf) {
    __shared__ int hist[NBUCK];
    __shared__ int base[NBUCK];
    const int t = threadIdx.x;
    const int per = (NE + gridDim.x - 1) / gridDim.x;
    const int e0 = blockIdx.x * per;
    const int e1 = min(e0 + per, NE);
    for (int i = t; i < NBUCK; i += 256) hist[i] = 0;
    __syncthreads();
    for (int e = e0 + t; e < e1; e += 256) atomicAdd(&hist[row[e] >> BSH], 1);
    __syncthreads();
    for (int i = t; i < NBUCK; i += 256) {
        int h = hist[i];
        base[i] = h ? atomicAdd(&bbase[i], h) : 0;
    }
    __syncthreads();
    for (int i = t; i < NBUCK; i += 256) hist[i] = 0;
    __syncthreads();
    for (int e = e0 + t; e < e1; e += 256) {
        int r = row[e];
        int b = r >> BSH;
        int k = atomicAdd(&hist[b], 1);        // LDS: local rank
        int idx = base[b] + k;
        if (idx < MAXBUCK) {                   // defensive (impossible stat.)
            unsigned pay = ((unsigned)col[e] << 16) | (unsigned)f2h(w[e]);
            ebuf[(size_t)b * MAXBUCK + idx] =
                ((unsigned long long)(unsigned)r << 32) | pay;
        }
    }
}

// ---- Build pass 2: one block per bucket; slot ranks via LDS atomics only.
// pslot writes for a bucket land in a 48KB region -> L2-merged full lines.
// Also writes cnt (no global memset needed).
__global__ __launch_bounds__(256) void k_place(const int* __restrict__ bbase,
                                               const unsigned long long* __restrict__ ebuf,
                                               int* __restrict__ cnt,
                                               unsigned* __restrict__ pslots) {
    __shared__ int cl[1 << BSH];
    const int t = threadIdx.x;
    const int b = blockIdx.x;
    if (t < (1 << BSH)) cl[t] = 0;
    __syncthreads();
    const int n = min(bbase[b], MAXBUCK);
    const unsigned long long* eb = ebuf + (size_t)b * MAXBUCK;
    for (int i = t; i < n; i += 256) {
        unsigned long long pk = eb[i];
        int r = (int)(pk >> 32);
        int k = atomicAdd(&cl[r & ((1 << BSH) - 1)], 1);
        k = min(k, CAP - 1);                   // defensive
        pslots[(size_t)r * CAP + k] = (unsigned)pk;
    }
    __syncthreads();
    int r = (b << BSH) + t;
    if (t < (1 << BSH) && r < NN) cnt[r] = min(cl[t], CAP);
}

#define ASTR 40  // padded LDS row stride in ushorts (32 + 8)

// ---------------- MFMA GEMM, fp32 A (3-term split), bf16 C. Layer 1 only.
__global__ __launch_bounds__(256, 2) void k_gemm_mfma_f32A(
    const float* __restrict__ A, int lda,
    const unsigned short* __restrict__ BhiT,
    const unsigned short* __restrict__ BloT,
    unsigned short* __restrict__ C, int ldc,
    int M, int K, int Ncol)
{
    __shared__ unsigned short Ah[128 * ASTR];
    __shared__ unsigned short Al[128 * ASTR];
    __shared__ unsigned short Bh[128 * ASTR];
    __shared__ unsigned short Bl[128 * ASTR];

    const int tid = threadIdx.x;
    const int lane = tid & 63;
    const int wave = tid >> 6;
    const int wm = wave >> 1, wn = wave & 1;
    const int quad = lane >> 4, l16 = lane & 15;
    const int bm = blockIdx.y * 128, bn = blockIdx.x * 128;
    const int srow = tid >> 1;
    const int skq  = (tid & 1) * 16;

    floatx4 acc[4][4];
#pragma unroll
    for (int i = 0; i < 4; ++i)
#pragma unroll
        for (int j = 0; j < 4; ++j) acc[i][j] = (floatx4){0.f, 0.f, 0.f, 0.f};

    for (int k0 = 0; k0 < K; k0 += 32) {
        float4 a0 = make_float4(0, 0, 0, 0), a1 = a0, a2 = a0, a3 = a0;
        const int ga = bm + srow;
        if (ga < M) {
            const float* Ap = A + (size_t)ga * lda + k0 + skq;
            a0 = *(const float4*)(Ap + 0);
            a1 = *(const float4*)(Ap + 4);
            a2 = *(const float4*)(Ap + 8);
            a3 = *(const float4*)(Ap + 12);
        }
        uint4 bh0 = make_uint4(0, 0, 0, 0), bh1 = bh0, bl0 = bh0, bl1 = bh0;
        const int gb2 = bn + srow;
        if (gb2 < Ncol) {
            const unsigned short* ph = BhiT + (size_t)gb2 * K + k0 + skq;
            const unsigned short* pl = BloT + (size_t)gb2 * K + k0 + skq;
            bh0 = *(const uint4*)(ph);
            bh1 = *(const uint4*)(ph + 8);
            bl0 = *(const uint4*)(pl);
            bl1 = *(const uint4*)(pl + 8);
        }
        __attribute__((aligned(16))) unsigned short ah[16], al[16];
        const float av[16] = {a0.x, a0.y, a0.z, a0.w, a1.x, a1.y, a1.z, a1.w,
                              a2.x, a2.y, a2.z, a2.w, a3.x, a3.y, a3.z, a3.w};
#pragma unroll
        for (int i = 0; i < 16; ++i) split_bf16(av[i], ah[i], al[i]);

        __syncthreads();
        *(uint4*)&Ah[srow * ASTR + skq]     = *(const uint4*)&ah[0];
        *(uint4*)&Ah[srow * ASTR + skq + 8] = *(const uint4*)&ah[8];
        *(uint4*)&Al[srow * ASTR + skq]     = *(const uint4*)&al[0];
        *(uint4*)&Al[srow * ASTR + skq + 8] = *(const uint4*)&al[8];
        *(uint4*)&Bh[srow * ASTR + skq]     = bh0;
        *(uint4*)&Bh[srow * ASTR + skq + 8] = bh1;
        *(uint4*)&Bl[srow * ASTR + skq]     = bl0;
        *(uint4*)&Bl[srow * ASTR + skq + 8] = bl1;
        __syncthreads();

        short8_t afh[4], afl[4], bfh[4], bfl[4];
#pragma unroll
        for (int t = 0; t < 4; ++t) {
            const int m = wm * 64 + t * 16 + l16;
            afh[t] = *(const short8_t*)&Ah[m * ASTR + quad * 8];
            afl[t] = *(const short8_t*)&Al[m * ASTR + quad * 8];
            const int n = wn * 64 + t * 16 + l16;
            bfh[t] = *(const short8_t*)&Bh[n * ASTR + quad * 8];
            bfl[t] = *(const short8_t*)&Bl[n * ASTR + quad * 8];
        }
#pragma unroll
        for (int i = 0; i < 4; ++i)
#pragma unroll
            for (int j = 0; j < 4; ++j) {
                acc[i][j] = __builtin_amdgcn_mfma_f32_16x16x32_bf16(afh[i], bfh[j], acc[i][j], 0, 0, 0);
                acc[i][j] = __builtin_amdgcn_mfma_f32_16x16x32_bf16(afh[i], bfl[j], acc[i][j], 0, 0, 0);
                acc[i][j] = __builtin_amdgcn_mfma_f32_16x16x32_bf16(afl[i], bfh[j], acc[i][j], 0, 0, 0);
            }
    }

#pragma unroll
    for (int j = 0; j < 4; ++j) {
        const int colc = bn + wn * 64 + j * 16 + l16;
        if (colc >= Ncol) continue;
#pragma unroll
        for (int i = 0; i < 4; ++i) {
#pragma unroll
            for (int r = 0; r < 4; ++r) {
                const int rowc = bm + wm * 64 + i * 16 + quad * 4 + r;
                if (rowc >= M) continue;
                C[(size_t)rowc * ldc + colc] = f2bf(acc[i][j][r]);
            }
        }
    }
}

// dinv[r] = rsqrt(sum of raw w over row r), 0 if deg<=0 (atomic-free)
__global__ __launch_bounds__(256) void k_degsum(const int* __restrict__ cnt,
                                                const unsigned* __restrict__ pslots,
                                                float* __restrict__ dinv) {
    int tid = threadIdx.x;
    int lane = tid & 15;
    int node = blockIdx.x * 16 + (tid >> 4);
    if (node >= NN) return;
    int e = cnt[node];
    const unsigned* base = pslots + (size_t)node * CAP;
    float s = 0.0f;
    for (int k = lane; k < e; k += 16) s += h2f(base[k]);
#pragma unroll
    for (int m = 8; m >= 1; m >>= 1) s += __shfl_xor(s, m);
    if (lane == 0) dinv[node] = (s > 0.0f) ? rsqrtf(s) : 0.0f;
}

// In-place: weight half of pslot <- fp16(-w * dinv[r] * dinv[col])
__global__ __launch_bounds__(256) void k_repack(const int* __restrict__ cnt,
                                                unsigned* __restrict__ pslots,
                                                const float* __restrict__ dinv) {
    int tid = threadIdx.x;
    int lane = tid & 15;
    int node = blockIdx.x * 16 + (tid >> 4);
    if (node >= NN) return;
    int e = cnt[node];
    float dr = dinv[node];
    unsigned* pb = pslots + (size_t)node * CAP;
    for (int k = lane; k < e; k += 16) {
        unsigned s = pb[k];
        float wv = -h2f(s) * dr * dinv[s >> 16];
        pb[k] = (s & 0xFFFF0000u) | (unsigned)f2h(wv);
    }
}

// ---------------- MFMA GEMM, bf16 A direct (2-term W split). Layers 3/4/5.
__global__ __launch_bounds__(256, 2) void k_gemm_mfma_bf(
    const unsigned short* __restrict__ A, int lda,
    const unsigned short* __restrict__ BhiT,
    const unsigned short* __restrict__ BloT,
    unsigned short* __restrict__ C, int ldc,
    int M, int K, int Ncol,
    const float* __restrict__ bias, int act)
{
    __shared__ unsigned short Ah[128 * ASTR];
    __shared__ unsigned short Bh[128 * ASTR];
    __shared__ unsigned short Bl[128 * ASTR];

    const int tid = threadIdx.x;
    const int lane = tid & 63;
    const int wave = tid >> 6;
    const int wm = wave >> 1, wn = wave & 1;
    const int quad = lane >> 4, l16 = lane & 15;
    const int bm = blockIdx.y * 128, bn = blockIdx.x * 128;
    const int srow = tid >> 1;
    const int skq  = (tid & 1) * 16;

    floatx4 acc[4][4];
#pragma unroll
    for (int i = 0; i < 4; ++i)
#pragma unroll
        for (int j = 0; j < 4; ++j) acc[i][j] = (floatx4){0.f, 0.f, 0.f, 0.f};

    for (int k0 = 0; k0 < K; k0 += 32) {
        uint4 a0 = make_uint4(0, 0, 0, 0), a1 = a0;
        const int ga = bm + srow;
        if (ga < M) {
            const unsigned short* Ap = A + (size_t)ga * lda + k0 + skq;
            a0 = *(const uint4*)(Ap);
            a1 = *(const uint4*)(Ap + 8);
        }
        uint4 bh0 = make_uint4(0, 0, 0, 0), bh1 = bh0, bl0 = bh0, bl1 = bh0;
        const int gb = bn + srow;
        if (gb < Ncol) {
            const unsigned short* ph = BhiT + (size_t)gb * K + k0 + skq;
            const unsigned short* pl = BloT + (size_t)gb * K + k0 + skq;
            bh0 = *(const uint4*)(ph);
            bh1 = *(const uint4*)(ph + 8);
            bl0 = *(const uint4*)(pl);
            bl1 = *(const uint4*)(pl + 8);
        }
        __syncthreads();
        *(uint4*)&Ah[srow * ASTR + skq]     = a0;
        *(uint4*)&Ah[srow * ASTR + skq + 8] = a1;
        *(uint4*)&Bh[srow * ASTR + skq]     = bh0;
        *(uint4*)&Bh[srow * ASTR + skq + 8] = bh1;
        *(uint4*)&Bl[srow * ASTR + skq]     = bl0;
        *(uint4*)&Bl[srow * ASTR + skq + 8] = bl1;
        __syncthreads();

        short8_t afh[4], bfh[4], bfl[4];
#pragma unroll
        for (int t = 0; t < 4; ++t) {
            const int m = wm * 64 + t * 16 + l16;
            afh[t] = *(const short8_t*)&Ah[m * ASTR + quad * 8];
            const int n = wn * 64 + t * 16 + l16;
            bfh[t] = *(const short8_t*)&Bh[n * ASTR + quad * 8];
            bfl[t] = *(const short8_t*)&Bl[n * ASTR + quad * 8];
        }
#pragma unroll
        for (int i = 0; i < 4; ++i)
#pragma unroll
            for (int j = 0; j < 4; ++j) {
                acc[i][j] = __builtin_amdgcn_mfma_f32_16x16x32_bf16(afh[i], bfh[j], acc[i][j], 0, 0, 0);
                acc[i][j] = __builtin_amdgcn_mfma_f32_16x16x32_bf16(afh[i], bfl[j], acc[i][j], 0, 0, 0);
            }
    }

#pragma unroll
    for (int j = 0; j < 4; ++j) {
        const int col = bn + wn * 64 + j * 16 + l16;
        if (col >= Ncol) continue;
        const float bv = bias ? bias[col] : 0.0f;
#pragma unroll
        for (int i = 0; i < 4; ++i) {
#pragma unroll
            for (int r = 0; r < 4; ++r) {
                const int row = bm + wm * 64 + i * 16 + quad * 4 + r;
                if (row >= M) continue;
                float v = acc[i][j][r] + bv;
                if (act) v = softplusf(v);
                C[(size_t)row * ldc + col] = f2bf(v);
            }
        }
    }
}

// fp32-weight vector GEMM with bf16 A and bf16 C (layer 2 only, K=48)
__global__ __launch_bounds__(256) void k_gemm(
    const unsigned short* __restrict__ A, int lda,
    const float* __restrict__ B, int ldb,
    unsigned short* __restrict__ C, int ldc,
    int M, int K, int Ncol,
    const float* __restrict__ bias, int act)
{
    __shared__ float As[16][128];
    __shared__ float Bs[16][128];
    const int tid = threadIdx.x;
    const int tx = tid & 15;
    const int ty = tid >> 4;
    const int bm = blockIdx.y * 128;
    const int bn = blockIdx.x * 128;
    const int arow = tid >> 1;
    const int akq = (tid & 1) * 8;
    const int bkr = tid >> 4;
    const int bcq = (tid & 15) * 8;

    float acc[8][8];
#pragma unroll
    for (int i = 0; i < 8; ++i)
#pragma unroll
        for (int j = 0; j < 8; ++j) acc[i][j] = 0.0f;

    for (int k0 = 0; k0 < K; k0 += 16) {
        uint4 ald = make_uint4(0, 0, 0, 0);
        int gr = bm + arow;
        if (gr < M) ald = *(const uint4*)(A + (size_t)gr * lda + k0 + akq);
        float4 b0 = make_float4(0, 0, 0, 0), b1 = make_float4(0, 0, 0, 0);
        int cb = bn + bcq;
        const float* Bp = B + (k0 + bkr) * ldb;
        if (cb < Ncol)     b0 = *(const float4*)(Bp + cb);
        if (cb + 4 < Ncol) b1 = *(const float4*)(Bp + cb + 4);
        __syncthreads();
        const unsigned short* au = (const unsigned short*)&ald;
#pragma unroll
        for (int i = 0; i < 8; ++i) As[akq + i][arow] = bf2f(au[i]);
        *(float4*)&Bs[bkr][bcq] = b0;
        *(float4*)&Bs[bkr][bcq + 4] = b1;
        __syncthreads();
#pragma unroll
        for (int kk = 0; kk < 16; ++kk) {
            float a[8], b[8];
            float4 t;
            t = *(const float4*)&As[kk][ty * 4];      a[0] = t.x; a[1] = t.y; a[2] = t.z; a[3] = t.w;
            t = *(const float4*)&As[kk][64 + ty * 4]; a[4] = t.x; a[5] = t.y; a[6] = t.z; a[7] = t.w;
            t = *(const float4*)&Bs[kk][tx * 4];      b[0] = t.x; b[1] = t.y; b[2] = t.z; b[3] = t.w;
            t = *(const float4*)&Bs[kk][64 + tx * 4]; b[4] = t.x; b[5] = t.y; b[6] = t.z; b[7] = t.w;
#pragma unroll
            for (int i = 0; i < 8; ++i)
#pragma unroll
                for (int j = 0; j < 8; ++j)
                    acc[i][j] = fmaf(a[i], b[j], acc[i][j]);
        }
    }
#pragma unroll
    for (int i = 0; i < 8; ++i) {
        int r = bm + ((i < 4) ? (ty * 4 + i) : (64 + ty * 4 + i - 4));
        if (r >= M) continue;
#pragma unroll
        for (int j = 0; j < 8; ++j) {
            int cl = bn + ((j < 4) ? (tx * 4 + j) : (64 + tx * 4 + j - 4));
            if (cl >= Ncol) continue;
            float v = acc[i][j];
            if (bias) v += bias[cl];
            if (act) v = softplusf(v);
            C[(size_t)r * ldc + cl] = f2bf(v);
        }
    }
}

// Slotted propagation, 4 bf16 feats/lane (us4 8B gathers), 8 edges in flight.
// Layers 1-3 (proven r8 structure).
__global__ __launch_bounds__(256) void k_prop(
    const int* __restrict__ cnt, const unsigned* __restrict__ pslots,
    const unsigned short* __restrict__ z, int zld, int zoff,
    unsigned short* __restrict__ out, int outld, int ooff,
    int ltw, float alpha,
    const unsigned short* __restrict__ add1, int a1ld, int a1off, float c1,
    const unsigned short* __restrict__ add2, int a2ld, int a2off,
    const float* __restrict__ bias, int act)
{
    const int T = 1 << ltw;
    const int lane = threadIdx.x & (T - 1);
    const int node = blockIdx.x * (256 >> ltw) + (threadIdx.x >> ltw);
    if (node >= NN) return;
    const int f4 = lane * 4;
    const int e = cnt[node];
    const unsigned* base = pslots + (size_t)node * CAP;
    float accA[4] = {0, 0, 0, 0};
    float accB[4] = {0, 0, 0, 0};
    const unsigned short* zp = z + zoff + f4;
    int p = 0;
    for (; p + 8 <= e; p += 8) {
        unsigned s0 = base[p + 0], s1 = base[p + 1], s2 = base[p + 2], s3 = base[p + 3];
        unsigned s4 = base[p + 4], s5 = base[p + 5], s6 = base[p + 6], s7 = base[p + 7];
        const us4 z0 = *(const us4*)(zp + (size_t)(s0 >> 16) * zld);
        const us4 z1 = *(const us4*)(zp + (size_t)(s1 >> 16) * zld);
        const us4 z2 = *(const us4*)(zp + (size_t)(s2 >> 16) * zld);
        const us4 z3 = *(const us4*)(zp + (size_t)(s3 >> 16) * zld);
        const us4 z4 = *(const us4*)(zp + (size_t)(s4 >> 16) * zld);
        const us4 z5 = *(const us4*)(zp + (size_t)(s5 >> 16) * zld);
        const us4 z6 = *(const us4*)(zp + (size_t)(s6 >> 16) * zld);
        const us4 z7 = *(const us4*)(zp + (size_t)(s7 >> 16) * zld);
        float w0 = h2f(s0), w1 = h2f(s1), w2 = h2f(s2), w3 = h2f(s3);
        float w4 = h2f(s4), w5 = h2f(s5), w6 = h2f(s6), w7 = h2f(s7);
#pragma unroll
        for (int i = 0; i < 4; ++i) {
            accA[i] = fmaf(w0, bf2f(z0[i]), accA[i]);
            accB[i] = fmaf(w1, bf2f(z1[i]), accB[i]);
            accA[i] = fmaf(w2, bf2f(z2[i]), accA[i]);
            accB[i] = fmaf(w3, bf2f(z3[i]), accB[i]);
            accA[i] = fmaf(w4, bf2f(z4[i]), accA[i]);
            accB[i] = fmaf(w5, bf2f(z5[i]), accB[i]);
            accA[i] = fmaf(w6, bf2f(z6[i]), accA[i]);
            accB[i] = fmaf(w7, bf2f(z7[i]), accB[i]);
        }
    }
    for (; p + 4 <= e; p += 4) {
        unsigned s0 = base[p + 0], s1 = base[p + 1], s2 = base[p + 2], s3 = base[p + 3];
        const us4 z0 = *(const us4*)(zp + (size_t)(s0 >> 16) * zld);
        const us4 z1 = *(const us4*)(zp + (size_t)(s1 >> 16) * zld);
        const us4 z2 = *(const us4*)(zp + (size_t)(s2 >> 16) * zld);
        const us4 z3 = *(const us4*)(zp + (size_t)(s3 >> 16) * zld);
        float w0 = h2f(s0), w1 = h2f(s1), w2 = h2f(s2), w3 = h2f(s3);
#pragma unroll
        for (int i = 0; i < 4; ++i) {
            accA[i] = fmaf(w0, bf2f(z0[i]), accA[i]);
            accB[i] = fmaf(w1, bf2f(z1[i]), accB[i]);
            accA[i] = fmaf(w2, bf2f(z2[i]), accA[i]);
            accB[i] = fmaf(w3, bf2f(z3[i]), accB[i]);
        }
    }
    for (; p < e; ++p) {
        unsigned s = base[p];
        float wv = h2f(s);
        const us4 zv = *(const us4*)(zp + (size_t)(s >> 16) * zld);
#pragma unroll
        for (int i = 0; i < 4; ++i) accA[i] = fmaf(wv, bf2f(zv[i]), accA[i]);
    }
#pragma unroll
    for (int i = 0; i < 4; ++i) accA[i] = alpha * (accA[i] + accB[i]);
    if (add1) {
        const us4 t = *(const us4*)(add1 + (size_t)node * a1ld + a1off + f4);
#pragma unroll
        for (int i = 0; i < 4; ++i) accA[i] = fmaf(c1, bf2f(t[i]), accA[i]);
    }
    if (add2) {
        const us4 t = *(const us4*)(add2 + (size_t)node * a2ld + a2off + f4);
#pragma unroll
        for (int i = 0; i < 4; ++i) accA[i] += bf2f(t[i]);
    }
    if (bias) {
        const float4 t = *(const float4*)(bias + f4);
        accA[0] += t.x; accA[1] += t.y; accA[2] += t.z; accA[3] += t.w;
    }
    if (act) {
#pragma unroll
        for (int i = 0; i < 4; ++i) accA[i] = softplusf(accA[i]);
    }
    us4 o;
#pragma unroll
    for (int i = 0; i < 4; ++i) o[i] = f2bf(accA[i]);
    *(us4*)(out + (size_t)node * outld + ooff + f4) = o;
}

// r17 structure, 16 edges in flight (fully unrolled, compile-time indices).
// Layer 4 call sites.
__global__ __launch_bounds__(256) void k_prop16(
    const int* __restrict__ cnt, const unsigned* __restrict__ pslots,
    const unsigned short* __restrict__ z, int zld, int zoff,
    unsigned short* __restrict__ out, int outld, int ooff,
    int ltw, float alpha,
    const unsigned short* __restrict__ add1, int a1ld, int a1off, float c1)
{
    const int T = 1 << ltw;
    const int lane = threadIdx.x & (T - 1);
    const int node = blockIdx.x * (256 >> ltw) + (threadIdx.x >> ltw);
    if (node >= NN) return;
    const int f4 = lane * 4;
    const int e = cnt[node];
    const unsigned* base = pslots + (size_t)node * CAP;
    float accA[4] = {0, 0, 0, 0};
    float accB[4] = {0, 0, 0, 0};
    const unsigned short* zp = z + zoff + f4;
    int p = 0;
    for (; p + 16 <= e; p += 16) {
        unsigned s[16];
#pragma unroll
        for (int q = 0; q < 16; ++q) s[q] = base[p + q];
        us4 zv[16];
#pragma unroll
        for (int q = 0; q < 16; ++q)
            zv[q] = *(const us4*)(zp + (size_t)(s[q] >> 16) * zld);
#pragma unroll
        for (int q = 0; q < 16; q += 2) {
            float wa = h2f(s[q]), wb = h2f(s[q + 1]);
#pragma unroll
            for (int i = 0; i < 4; ++i) {
                accA[i] = fmaf(wa, bf2f(zv[q][i]), accA[i]);
                accB[i] = fmaf(wb, bf2f(zv[q + 1][i]), accB[i]);
            }
        }
    }
    for (; p + 8 <= e; p += 8) {
        unsigned s0 = base[p + 0], s1 = base[p + 1], s2 = base[p + 2], s3 = base[p + 3];
        unsigned s4 = base[p + 4], s5 = base[p + 5], s6 = base[p + 6], s7 = base[p + 7];
        const us4 z0 = *(const us4*)(zp + (size_t)(s0 >> 16) * zld);
        const us4 z1 = *(const us4*)(zp + (size_t)(s1 >> 16) * zld);
        const us4 z2 = *(const us4*)(zp + (size_t)(s2 >> 16) * zld);
        const us4 z3 = *(const us4*)(zp + (size_t)(s3 >> 16) * zld);
        const us4 z4 = *(const us4*)(zp + (size_t)(s4 >> 16) * zld);
        const us4 z5 = *(const us4*)(zp + (size_t)(s5 >> 16) * zld);
        const us4 z6 = *(const us4*)(zp + (size_t)(s6 >> 16) * zld);
        const us4 z7 = *(const us4*)(zp + (size_t)(s7 >> 16) * zld);
        float w0 = h2f(s0), w1 = h2f(s1), w2 = h2f(s2), w3 = h2f(s3);
        float w4 = h2f(s4), w5 = h2f(s5), w6 = h2f(s6), w7 = h2f(s7);
#pragma unroll
        for (int i = 0; i < 4; ++i) {
            accA[i] = fmaf(w0, bf2f(z0[i]), accA[i]);
            accB[i] = fmaf(w1, bf2f(z1[i]), accB[i]);
            accA[i] = fmaf(w2, bf2f(z2[i]), accA[i]);
            accB[i] = fmaf(w3, bf2f(z3[i]), accB[i]);
            accA[i] = fmaf(w4, bf2f(z4[i]), accA[i]);
            accB[i] = fmaf(w5, bf2f(z5[i]), accB[i]);
            accA[i] = fmaf(w6, bf2f(z6[i]), accA[i]);
            accB[i] = fmaf(w7, bf2f(z7[i]), accB[i]);
        }
    }
    for (; p + 4 <= e; p += 4) {
        unsigned s0 = base[p + 0], s1 = base[p + 1], s2 = base[p + 2], s3 = base[p + 3];
        const us4 z0 = *(const us4*)(zp + (size_t)(s0 >> 16) * zld);
        const us4 z1 = *(const us4*)(zp + (size_t)(s1 >> 16) * zld);
        const us4 z2 = *(const us4*)(zp + (size_t)(s2 >> 16) * zld);
        const us4 z3 = *(const us4*)(zp + (size_t)(s3 >> 16) * zld);
        float w0 = h2f(s0), w1 = h2f(s1), w2 = h2f(s2), w3 = h2f(s3);
#pragma unroll
        for (int i = 0; i < 4; ++i) {
            accA[i] = fmaf(w0, bf2f(z0[i]), accA[i]);
            accB[i] = fmaf(w1, bf2f(z1[i]), accB[i]);
            accA[i] = fmaf(w2, bf2f(z2[i]), accA[i]);
            accB[i] = fmaf(w3, bf2f(z3[i]), accB[i]);
        }
    }
    for (; p < e; ++p) {
        unsigned s = base[p];
        float wv = h2f(s);
        const us4 zv = *(const us4*)(zp + (size_t)(s >> 16) * zld);
#pragma unroll
        for (int i = 0; i < 4; ++i) accA[i] = fmaf(wv, bf2f(zv[i]), accA[i]);
    }
#pragma unroll
    for (int i = 0; i < 4; ++i) accA[i] = alpha * (accA[i] + accB[i]);
    if (add1) {
        const us4 t = *(const us4*)(add1 + (size_t)node * a1ld + a1off + f4);
#pragma unroll
        for (int i = 0; i < 4; ++i) accA[i] = fmaf(c1, bf2f(t[i]), accA[i]);
    }
    us4 o;
#pragma unroll
    for (int i = 0; i < 4; ++i) o[i] = f2bf(accA[i]);
    *(us4*)(out + (size_t)node * outld + ooff + f4) = o;
}

// r18: L5-only 2-way feature-sliced prop with XCD-aware block mapping.
// blockIdx%8 selects the XCD (round-robin dispatch); XCDs 0-3 own feature
// slice 0 ([0,64) feats = first 128B line of the slice), XCDs 4-7 own slice 1.
// Per-XCD gather working set halves (12.8->6.4MB), per-line reuse doubles
// (4->8, hit ceiling 75%->87.5%). T=16 lanes per node-slice; 16 node-slices
// per block; grid 782*8=6256 (nb<3125 guard). Costs: pslots read per slice
// (2x), wave iterations +~11% (max of 4 Poissons vs 2).
__global__ __launch_bounds__(256) void k_prop16s(
    const int* __restrict__ cnt, const unsigned* __restrict__ pslots,
    const unsigned short* __restrict__ z, int zld, int zoff,
    unsigned short* __restrict__ out, int outld, int ooff,
    float alpha,
    const unsigned short* __restrict__ add1, int a1ld, int a1off, float c1)
{
    const int o8 = blockIdx.x & 7;
    const int g8 = blockIdx.x >> 3;
    const int slice = o8 >> 2;                  // 0 for XCDs 0-3, 1 for 4-7
    const int nb = g8 * 4 + (o8 & 3);           // node-block within slice
    if (nb >= 3125) return;
    const int lane = threadIdx.x & 15;
    const int node = nb * 16 + (threadIdx.x >> 4);
    const int f4 = slice * 64 + lane * 4;       // feature offset (ushorts)
    const int e = cnt[node];
    const unsigned* base = pslots + (size_t)node * CAP;
    float accA[4] = {0, 0, 0, 0};
    float accB[4] = {0, 0, 0, 0};
    const unsigned short* zp = z + zoff + f4;
    int p = 0;
    for (; p + 16 <= e; p += 16) {
        unsigned s[16];
#pragma unroll
        for (int q = 0; q < 16; ++q) s[q] = base[p + q];
        us4 zv[16];
#pragma unroll
        for (int q = 0; q < 16; ++q)
            zv[q] = *(const us4*)(zp + (size_t)(s[q] >> 16) * zld);
#pragma unroll
        for (int q = 0; q < 16; q += 2) {
            float wa = h2f(s[q]), wb = h2f(s[q + 1]);
#pragma unroll
            for (int i = 0; i < 4; ++i) {
                accA[i] = fmaf(wa, bf2f(zv[q][i]), accA[i]);
                accB[i] = fmaf(wb, bf2f(zv[q + 1][i]), accB[i]);
            }
        }
    }
    for (; p + 8 <= e; p += 8) {
        unsigned s0 = base[p + 0], s1 = base[p + 1], s2 = base[p + 2], s3 = base[p + 3];
        unsigned s4 = base[p + 4], s5 = base[p + 5], s6 = base[p + 6], s7 = base[p + 7];
        const us4 z0 = *(const us4*)(zp + (size_t)(s0 >> 16) * zld);
        const us4 z1 = *(const us4*)(zp + (size_t)(s1 >> 16) * zld);
        const us4 z2 = *(const us4*)(zp + (size_t)(s2 >> 16) * zld);
        const us4 z3 = *(const us4*)(zp + (size_t)(s3 >> 16) * zld);
        const us4 z4 = *(const us4*)(zp + (size_t)(s4 >> 16) * zld);
        const us4 z5 = *(const us4*)(zp + (size_t)(s5 >> 16) * zld);
        const us4 z6 = *(const us4*)(zp + (size_t)(s6 >> 16) * zld);
        const us4 z7 = *(const us4*)(zp + (size_t)(s7 >> 16) * zld);
        float w0 = h2f(s0), w1 = h2f(s1), w2 = h2f(s2), w3 = h2f(s3);
        float w4 = h2f(s4), w5 = h2f(s5), w6 = h2f(s6), w7 = h2f(s7);
#pragma unroll
        for (int i = 0; i < 4; ++i) {
            accA[i] = fmaf(w0, bf2f(z0[i]), accA[i]);
            accB[i] = fmaf(w1, bf2f(z1[i]), accB[i]);
            accA[i] = fmaf(w2, bf2f(z2[i]), accA[i]);
            accB[i] = fmaf(w3, bf2f(z3[i]), accB[i]);
            accA[i] = fmaf(w4, bf2f(z4[i]), accA[i]);
            accB[i] = fmaf(w5, bf2f(z5[i]), accB[i]);
            accA[i] = fmaf(w6, bf2f(z6[i]), accA[i]);
            accB[i] = fmaf(w7, bf2f(z7[i]), accB[i]);
        }
    }
    for (; p + 4 <= e; p += 4) {
        unsigned s0 = base[p + 0], s1 = base[p + 1], s2 = base[p + 2], s3 = base[p + 3];
        const us4 z0 = *(const us4*)(zp + (size_t)(s0 >> 16) * zld);
        const us4 z1 = *(const us4*)(zp + (size_t)(s1 >> 16) * zld);
        const us4 z2 = *(const us4*)(zp + (size_t)(s2 >> 16) * zld);
        const us4 z3 = *(const us4*)(zp + (size_t)(s3 >> 16) * zld);
        float w0 = h2f(s0), w1 = h2f(s1), w2 = h2f(s2), w3 = h2f(s3);
#pragma unroll
        for (int i = 0; i < 4; ++i) {
            accA[i] = fmaf(w0, bf2f(z0[i]), accA[i]);
            accB[i] = fmaf(w1, bf2f(z1[i]), accB[i]);
            accA[i] = fmaf(w2, bf2f(z2[i]), accA[i]);
            accB[i] = fmaf(w3, bf2f(z3[i]), accB[i]);
        }
    }
    for (; p < e; ++p) {
        unsigned s = base[p];
        float wv = h2f(s);
        const us4 zv = *(const us4*)(zp + (size_t)(s >> 16) * zld);
#pragma unroll
        for (int i = 0; i < 4; ++i) accA[i] = fmaf(wv, bf2f(zv[i]), accA[i]);
    }
#pragma unroll
    for (int i = 0; i < 4; ++i) accA[i] = alpha * (accA[i] + accB[i]);
    if (add1) {
        const us4 t = *(const us4*)(add1 + (size_t)node * a1ld + a1off + f4);
#pragma unroll
        for (int i = 0; i < 4; ++i) accA[i] = fmaf(c1, bf2f(t[i]), accA[i]);
    }
    us4 o;
#pragma unroll
    for (int i = 0; i < 4; ++i) o[i] = f2bf(accA[i]);
    *(us4*)(out + (size_t)node * outld + ooff + f4) = o;
}

__global__ __launch_bounds__(256) void k_bnstats(const unsigned short* __restrict__ h, int ld, int lc,
                                                 float* __restrict__ stats) {
    const int C = 1 << lc;
    const int tid = threadIdx.x;
    const int c = tid & (C - 1);
    const int rpb = 256 >> lc;
    int r = blockIdx.x * rpb + (tid >> lc);
    const int stride = gridDim.x * rpb;
    float s = 0.0f, q = 0.0f;
    for (; r < NN; r += stride) {
        float v = bf2f(h[(size_t)r * ld + c]);
        s += v;
        q = fmaf(v, v, q);
    }
    __shared__ float shs[256], shq[256];
    shs[tid] = s; shq[tid] = q;
    __syncthreads();
    for (int o = 128; o >= C; o >>= 1) {
        if (tid < o) { shs[tid] += shs[tid + o]; shq[tid] += shq[tid + o]; }
        __syncthreads();
    }
    if (tid < C) {
        atomicAdd(&stats[c], shs[tid]);
        atomicAdd(&stats[128 + c], shq[tid]);
    }
}

// Vectorized BN apply: 8 elems/thread.
__global__ void k_bnapply(unsigned short* __restrict__ h, int ld, int lc,
                          const float* __restrict__ stats,
                          const float* __restrict__ g, const float* __restrict__ be) {
    int idx = blockIdx.x * 256 + threadIdx.x;        // in units of 8 elems
    const int C8 = 1 << (lc - 3);
    if (idx >= NN * C8) return;
    int r = idx >> (lc - 3);
    int c0 = (idx & (C8 - 1)) << 3;
    const float invN = 1.0f / (float)NN;
    unsigned short* hp = h + (size_t)r * ld + c0;
    us8 v = *(const us8*)hp;
    us8 o;
#pragma unroll
    for (int i = 0; i < 8; ++i) {
        int c = c0 + i;
        float m = stats[c] * invN;
        float var = fmaf(stats[128 + c], invN, -m * m);
        var = fmaxf(var, 0.0f);
        float inv = rsqrtf(var + 1e-5f);
        o[i] = f2bf(fmaf(g[c] * inv, bf2f(v[i]) - m, be[c]));
    }
    *(us8*)hp = o;
}

// Pool stage 1 over bf16 h5.
__global__ __launch_bounds__(256) void k_pool1(const unsigned short* __restrict__ h,
                                               const int* __restrict__ gb,
                                               float* __restrict__ partial) {
    int g = blockIdx.y;
    int j = blockIdx.x;
    int start = gb[g], end = gb[g + 1];
    int len = end - start;
    int chunk = (len + 15) >> 4;
    int s = start + j * chunk;
    int e = min(s + chunk, end);
    int c = threadIdx.x;
    float mx = -INFINITY, sum = 0.0f;
    for (int r = s; r < e; ++r) {
        float v = bf2f(h[(size_t)r * 256 + c]);
        mx = fmaxf(mx, v);
        sum += v;
    }
    size_t base = ((size_t)(g * 16 + j)) * 512;
    partial[base + c] = mx;
    partial[base + 256 + c] = sum;
}

// Fused pool stage 2 + dense + log_softmax: 64 blocks.
__global__ __launch_bounds__(256) void k_pool2d(const float* __restrict__ partial,
                                                const int* __restrict__ gb,
                                                const float* __restrict__ Wd,
                                                const float* __restrict__ bd,
                                                float* __restrict__ out) {
    __shared__ float pl[512];
    __shared__ float red[4][256];
    int g = blockIdx.x;
    int c = threadIdx.x;
    float mx = -INFINITY, sum = 0.0f;
#pragma unroll
    for (int j = 0; j < 16; ++j) {
        size_t base = ((size_t)(g * 16 + j)) * 512;
        mx = fmaxf(mx, partial[base + c]);
        sum += partial[base + 256 + c];
    }
    int len = gb[g + 1] - gb[g];
    pl[c] = (len > 0) ? mx : 0.0f;
    pl[256 + c] = sum / fmaxf((float)len, 1.0f);
    __syncthreads();
    float p[4] = {0, 0, 0, 0};
    for (int k = c; k < 512; k += 256) {
        float pv = pl[k];
#pragma unroll
        for (int cc = 0; cc < 4; ++cc) p[cc] = fmaf(pv, Wd[k * 4 + cc], p[cc]);
    }
#pragma unroll
    for (int cc = 0; cc < 4; ++cc) red[cc][c] = p[cc];
    __syncthreads();
    for (int o = 128; o >= 1; o >>= 1) {
        if (c < o) {
#pragma unroll
            for (int cc = 0; cc < 4; ++cc) red[cc][c] += red[cc][c + o];
        }
        __syncthreads();
    }
    if (c == 0) {
        float l0 = red[0][0] + bd[0], l1 = red[1][0] + bd[1];
        float l2 = red[2][0] + bd[2], l3 = red[3][0] + bd[3];
        float m = fmaxf(fmaxf(l0, l1), fmaxf(l2, l3));
        float ls = m + logf(expf(l0 - m) + expf(l1 - m) + expf(l2 - m) + expf(l3 - m));
        out[g * 4 + 0] = l0 - ls;
        out[g * 4 + 1] = l1 - ls;
        out[g * 4 + 2] = l2 - ls;
        out[g * 4 + 3] = l3 - ls;
    }
}

extern "C" void kernel_launch(void* const* d_in, const int* in_sizes, int n_in,
                              void* d_out, int out_size, void* d_ws, size_t ws_size,
                              hipStream_t stream)
{
    const float* x    = (const float*)d_in[0];
    const float* ew   = (const float*)d_in[1];
    const int*   row  = (const int*)d_in[2];
    const int*   colp = row + NE;
    const int*   batch = (const int*)d_in[3];
    const float* W1 = (const float*)d_in[4];
    const float* b1 = (const float*)d_in[5];
    const float* g1 = (const float*)d_in[6];
    const float* be1 = (const float*)d_in[7];
    const float* W2 = (const float*)d_in[8];
    const float* b2 = (const float*)d_in[9];
    const float* g2 = (const float*)d_in[10];
    const float* be2 = (const float*)d_in[11];
    const float* W3 = (const float*)d_in[12];
    const float* b3 = (const float*)d_in[13];
    const float* g3 = (const float*)d_in[14];
    const float* be3 = (const float*)d_in[15];
    const float* W4 = (const float*)d_in[16];
    const float* b4 = (const float*)d_in[17];
    const float* g4 = (const float*)d_in[18];
    const float* be4 = (const float*)d_in[19];
    const float* W5 = (const float*)d_in[20];
    const float* b5 = (const float*)d_in[21];
    const float* Wd = (const float*)d_in[22];
    const float* bd = (const float*)d_in[23];
    float* outp = (float*)d_out;
    (void)in_sizes; (void)n_in; (void)out_size; (void)ws_size; (void)ew;

    char* wsb = (char*)d_ws;
    size_t off = 0;
    auto take = [&](size_t bytes) -> void* {
        void* p = wsb + off;
        off = (off + bytes + 255) & ~(size_t)255;
        return p;
    };
    // Layout byte-identical to the 764us r15 run (r11 lesson).
    int*   cnt    = (int*)take((size_t)NN * sizeof(int));
    float* dinv   = (float*)take((size_t)NN * sizeof(float));
    int*   gb     = (int*)take((NG + 1) * sizeof(int));
    unsigned* pslots = (unsigned*)take((size_t)NN * CAP * sizeof(unsigned));
    float* statsA = (float*)take(4 * 256 * sizeof(float));
    float* wcat   = (float*)take(6144 * sizeof(float));  // placeholder, unused
    unsigned short* bt1h = (unsigned short*)take(48 * 128 * 2);
    unsigned short* bt1l = (unsigned short*)take(48 * 128 * 2);
    unsigned short* bt3h = (unsigned short*)take(64 * 96 * 2);
    unsigned short* bt3l = (unsigned short*)take(64 * 96 * 2);
    unsigned short* bt4h = (unsigned short*)take(128 * 192 * 2);
    unsigned short* bt4l = (unsigned short*)take(128 * 192 * 2);
    unsigned short* bt5h = (unsigned short*)take(256 * 384 * 2);
    unsigned short* bt5l = (unsigned short*)take(256 * 384 * 2);
    float* partial= (float*)take((size_t)NG * 16 * 512 * sizeof(float));
    unsigned short* P   = (unsigned short*)take((size_t)NN * 48 * 2);
    unsigned short* uv  = (unsigned short*)take((size_t)NN * 32 * 2);
    unsigned short* Hc2 = (unsigned short*)take((size_t)NN * 48 * 2);
    unsigned short* Hc3 = (unsigned short*)take((size_t)NN * 96 * 2);
    unsigned short* Hc4 = (unsigned short*)take((size_t)NN * 192 * 2);
    unsigned short* Hc5 = (unsigned short*)take((size_t)NN * 384 * 2);
    unsigned short* h5  = (unsigned short*)take((size_t)NN * 256 * 2);
    int*   bbase  = (int*)take(NBUCK * sizeof(int));
    (void)wcat;
    // ebuf aliases Hc5: needs NBUCK*MAXBUCK*8 = 19.2MB < Hc5's 38.4MB; dead
    // before k_gemm_mfma_bf(layer 4) first writes Hc5.
    unsigned long long* ebuf = (unsigned long long*)Hc5;

    float* stats1 = statsA;
    float* stats2 = statsA + 256;
    float* stats3 = statsA + 512;
    float* stats4 = statsA + 768;

    hipMemsetAsync(bbase, 0, NBUCK * sizeof(int), stream);
    hipMemsetAsync(statsA, 0, 4 * 256 * sizeof(float), stream);

    // ---- weight prep + graph bounds (single launch)
    k_prep<<<529, 256, 0, stream>>>(W1, W3, W4, W5, batch,
                                    bt1h, bt1l, bt3h, bt3l, bt4h, bt4l,
                                    bt5h, bt5l, gb);

    // ---- adjacency build: bucket-bin (pass 1) + LDS-ranked place (pass 2)
    k_bin<<<256, 256, 0, stream>>>(row, colp, ew, bbase, ebuf);
    k_place<<<NBUCK, 256, 0, stream>>>(bbase, ebuf, cnt, pslots);

    // ---- Layer 1 GEMM (128->48): P = x @ [W0-W2 | W1 | W2]
    k_gemm_mfma_f32A<<<dim3(1, 391), 256, 0, stream>>>(x, 128, bt1h, bt1l, P, 48, NN, 128, 48);

    k_degsum<<<3125, 256, 0, stream>>>(cnt, pslots, dinv);
    k_repack<<<3125, 256, 0, stream>>>(cnt, pslots, dinv);

    // ---- Layer 1 (128->16): h1 = P0 + prop(P1) + 2*prop(prop(P2)) + b
    k_prop<<<1563, 256, 0, stream>>>(cnt, pslots, P, 48, 16, uv, 32, 0, 3, 1.0f,
                                     nullptr, 0, 0, 0.0f, nullptr, 0, 0, nullptr, 0);
    k_prop<<<782, 256, 0, stream>>>(cnt, pslots, uv, 32, 16, Hc2, 48, 0, 2, 2.0f,
                                    P, 48, 0, 1.0f, uv, 32, 0, b1, 1);
    k_bnstats<<<256, 256, 0, stream>>>(Hc2, 48, 4, stats1);
    k_bnapply<<<391, 256, 0, stream>>>(Hc2, 48, 4, stats1, g1, be1);

    // ---- Layer 2 (16->32)
    k_prop<<<782, 256, 0, stream>>>(cnt, pslots, Hc2, 48, 0, Hc2, 48, 16, 2, 1.0f,
                                    nullptr, 0, 0, 0.0f, nullptr, 0, 0, nullptr, 0);
    k_prop<<<782, 256, 0, stream>>>(cnt, pslots, Hc2, 48, 16, Hc2, 48, 32, 2, 2.0f,
                                    Hc2, 48, 0, -1.0f, nullptr, 0, 0, nullptr, 0);
    k_gemm<<<dim3(1, 391), 256, 0, stream>>>(Hc2, 48, W2, 32, Hc3, 96, NN, 48, 32, b2, 1);
    k_bnstats<<<256, 256, 0, stream>>>(Hc3, 96, 5, stats2);
    k_bnapply<<<782, 256, 0, stream>>>(Hc3, 96, 5, stats2, g2, be2);

    // ---- Layer 3 (32->64)
    k_prop<<<1563, 256, 0, stream>>>(cnt, pslots, Hc3, 96, 0, Hc3, 96, 32, 3, 1.0f,
                                     nullptr, 0, 0, 0.0f, nullptr, 0, 0, nullptr, 0);
    k_prop<<<1563, 256, 0, stream>>>(cnt, pslots, Hc3, 96, 32, Hc3, 96, 64, 3, 2.0f,
                                     Hc3, 96, 0, -1.0f, nullptr, 0, 0, nullptr, 0);
    k_gemm_mfma_bf<<<dim3(1, 391), 256, 0, stream>>>(Hc3, 96, bt3h, bt3l, Hc4, 192, NN, 96, 64, b3, 1);
    k_bnstats<<<256, 256, 0, stream>>>(Hc4, 192, 6, stats3);
    k_bnapply<<<1563, 256, 0, stream>>>(Hc4, 192, 6, stats3, g3, be3);

    // ---- Layer 4 (64->128): props on k_prop16 (unsliced — 64B sub-slices
    // would share cache lines; slicing verified-harmful by line-granularity
    // arithmetic)
    k_prop16<<<3125, 256, 0, stream>>>(cnt, pslots, Hc4, 192, 0, Hc4, 192, 64, 4, 1.0f,
                                       nullptr, 0, 0, 0.0f);
    k_prop16<<<3125, 256, 0, stream>>>(cnt, pslots, Hc4, 192, 64, Hc4, 192, 128, 4, 2.0f,
                                       Hc4, 192, 0, -1.0f);
    k_gemm_mfma_bf<<<dim3(1, 391), 256, 0, stream>>>(Hc4, 192, bt4h, bt4l, Hc5, 384, NN, 192, 128, b4, 1);
    k_bnstats<<<256, 256, 0, stream>>>(Hc5, 384, 7, stats4);
    k_bnapply<<<3125, 256, 0, stream>>>(Hc5, 384, 7, stats4, g4, be4);

    // ---- Layer 5 (128->256): props on k_prop16s (2-way XCD-sliced)
    k_prop16s<<<6256, 256, 0, stream>>>(cnt, pslots, Hc5, 384, 0, Hc5, 384, 128, 1.0f,
                                        nullptr, 0, 0, 0.0f);
    k_prop16s<<<6256, 256, 0, stream>>>(cnt, pslots, Hc5, 384, 128, Hc5, 384, 256, 2.0f,
                                        Hc5, 384, 0, -1.0f);
    k_gemm_mfma_bf<<<dim3(2, 391), 256, 0, stream>>>(Hc5, 384, bt5h, bt5l, h5, 256, NN, 384, 256, b5, 0);

    // ---- Pool + dense + log_softmax
    k_pool1<<<dim3(16, 64), 256, 0, stream>>>(h5, gb, partial);
    k_pool2d<<<64, 256, 0, stream>>>(partial, gb, Wd, bd, outp);
}

// Round 9
// 757.118 us; speedup vs baseline: 1.0201x; 1.0101x over previous
//
#include <hip/hip_runtime.h>
#include <hip/hip_fp16.h>
#include <cmath>

#define NN 50000
#define NE 1600000
#define NG 64
#define CAP 96    // slots per row; deg ~ Poisson(32), P(deg>=96) ~ e^-41 -> safe
// Build: two-pass bucketed, NO per-edge global atomics (r15 verified: -31us).
// Ledger: r9 +1.6M atomics=+74us; r12 line-padding=nil (per-op serializer
// ~21G ops/s, ~43B write-through/op); r13 co-residency=nil.
// LESSON: never per-element device-scope atomics on gfx950 — bucket + LDS-rank.
#define BSH 7
#define NBUCK ((NN + (1 << BSH) - 1) >> BSH)   // 391 buckets of 128 rows
#define MAXBUCK 6144                            // mean 4096, sigma ~64 -> safe
// Prop ladder (closed): r16 us8 = WORSE (MLP-bound, wider loads cut
// outstanding misses); r17 16-deep = flat (miss queue saturates <=8);
// r18 L5 2-way XCD feature-slice = CONFIRMED (FETCH 157->116MB, 59.2->55.8us)
// but VALUBusy 38->46% -> prop family now at its structural latency limit.
// r19: L5 GEMM XCD-pair swizzle — dim3(2,391) puts the two N-blocks of an
// M-tile on DIFFERENT XCDs (round-robin dispatch) so A (38.4MB) is HBM-fetched
// twice. 1D swizzled grid co-locates both N-halves on XCD y%8 (per-XCD A WS
// 4.8MB, read once).
// r11 LESSON (kept): workspace layout is perf-relevant state — all buffer
// addresses byte-identical to the 764us r15 run.

typedef __attribute__((ext_vector_type(8))) short short8_t;
typedef __attribute__((ext_vector_type(4))) float floatx4;
typedef __attribute__((ext_vector_type(4))) unsigned short us4;
typedef __attribute__((ext_vector_type(8))) unsigned short us8;

static __device__ __forceinline__ float softplusf(float x) {
    return fmaxf(x, 0.0f) + log1pf(expf(-fabsf(x)));
}

static __device__ __forceinline__ float bf2f(unsigned short u) {
    return __uint_as_float(((unsigned)u) << 16);
}
static __device__ __forceinline__ unsigned short f2bf(float x) {
    unsigned u = __float_as_uint(x);
    unsigned t = (u >> 16) & 1u;
    return (unsigned short)((u + 0x7FFFu + t) >> 16);  // RNE
}
static __device__ __forceinline__ float h2f(unsigned u) {
    __half_raw r; r.x = (unsigned short)(u & 0xFFFFu);
    return __half2float(__half(r));
}
static __device__ __forceinline__ unsigned short f2h(float x) {
    __half h = __float2half_rn(x);
    return static_cast<__half_raw>(h).x;
}

// exact split x = hi + lo (bf16 each, ~2^-16 relative residual)
static __device__ __forceinline__ void split_bf16(float x, unsigned short& hi, unsigned short& lo) {
    unsigned u = __float_as_uint(x);
    unsigned hb = u & 0xFFFF0000u;
    hi = (unsigned short)(hb >> 16);
    float r = x - __uint_as_float(hb);   // exact
    lo = f2bf(r);
}

static __device__ __forceinline__ int lower_bound_dev(const int* __restrict__ b, int val) {
    int lo = 0, hi = NN;
    while (lo < hi) {
        int mid = (lo + hi) >> 1;
        if (b[mid] < val) lo = mid + 1; else hi = mid;
    }
    return lo;
}

// ---- One-shot prep: all weight splits (layer-1 wcat computed on the fly,
// bit-identical to the old k_wcat1->k_wsplit path) + graph bounds.
__global__ __launch_bounds__(256) void k_prep(
    const float* __restrict__ W1, const float* __restrict__ W3,
    const float* __restrict__ W4, const float* __restrict__ W5,
    const int* __restrict__ batch,
    unsigned short* __restrict__ bt1h, unsigned short* __restrict__ bt1l,
    unsigned short* __restrict__ bt3h, unsigned short* __restrict__ bt3l,
    unsigned short* __restrict__ bt4h, unsigned short* __restrict__ bt4l,
    unsigned short* __restrict__ bt5h, unsigned short* __restrict__ bt5l,
    int* __restrict__ gb)
{
    const int bx = blockIdx.x;
    const int tid = threadIdx.x;
    if (bx < 24) {                       // layer 1: K=128, N=48, wcat on the fly
        int idx = bx * 256 + tid;
        if (idx < 128 * 48) {
            int k = idx / 48, j = idx - k * 48;
            float v;
            if (j < 16)      v = W1[k * 16 + j] - W1[2 * 2048 + k * 16 + j];
            else if (j < 32) v = W1[2048 + k * 16 + (j - 16)];
            else             v = W1[2 * 2048 + k * 16 + (j - 32)];
            unsigned short h, l;
            split_bf16(v, h, l);
            bt1h[(size_t)j * 128 + k] = h;
            bt1l[(size_t)j * 128 + k] = l;
        }
    } else if (bx < 48) {                // layer 3: K=96, N=64
        int idx = (bx - 24) * 256 + tid;
        if (idx < 96 * 64) {
            int k = idx / 64, n = idx - k * 64;
            unsigned short h, l;
            split_bf16(W3[idx], h, l);
            bt3h[(size_t)n * 96 + k] = h;
            bt3l[(size_t)n * 96 + k] = l;
        }
    } else if (bx < 144) {               // layer 4: K=192, N=128
        int idx = (bx - 48) * 256 + tid;
        if (idx < 192 * 128) {
            int k = idx / 128, n = idx - k * 128;
            unsigned short h, l;
            split_bf16(W4[idx], h, l);
            bt4h[(size_t)n * 192 + k] = h;
            bt4l[(size_t)n * 192 + k] = l;
        }
    } else if (bx < 528) {               // layer 5: K=384, N=256
        int idx = (bx - 144) * 256 + tid;
        if (idx < 384 * 256) {
            int k = idx / 256, n = idx - k * 256;
            unsigned short h, l;
            split_bf16(W5[idx], h, l);
            bt5h[(size_t)n * 384 + k] = h;
            bt5l[(size_t)n * 384 + k] = l;
        }
    } else {                             // graph bounds
        int g = tid;
        if (g <= NG) gb[g] = (g == NG) ? NN : lower_bound_dev(batch, g);
    }
}

// ---- Build pass 1: bin edges into NBUCK row-buckets. Per-block LDS
// histogram; ONE global atomic per (block,touched bucket) ~ 100K total.
// ebuf[b*MAXBUCK + i] = (row<<32) | (col<<16) | fp16(w).
__global__ __launch_bounds__(256) void k_bin(const int* __restrict__ row,
                                             const int* __restrict__ col,
                                             const float* __restrict__ w,
                                             int* __restrict__ bbase,
                                             unsigned long long* __restrict__ ebuf) {
    __shared__ int hist[NBUCK];
    __shared__ int base[NBUCK];
    const int t = threadIdx.x;
    const int per = (NE + gridDim.x - 1) / gridDim.x;
    const int e0 = blockIdx.x * per;
    const int e1 = min(e0 + per, NE);
    for (int i = t; i < NBUCK; i += 256) hist[i] = 0;
    __syncthreads();
    for (int e = e0 + t; e < e1; e += 256) atomicAdd(&hist[row[e] >> BSH], 1);
    __syncthreads();
    for (int i = t; i < NBUCK; i += 256) {
        int h = hist[i];
        base[i] = h ? atomicAdd(&bbase[i], h) : 0;
    }
    __syncthreads();
    for (int i = t; i < NBUCK; i += 256) hist[i] = 0;
    __syncthreads();
    for (int e = e0 + t; e < e1; e += 256) {
        int r = row[e];
        int b = r >> BSH;
        int k = atomicAdd(&hist[b], 1);        // LDS: local rank
        int idx = base[b] + k;
        if (idx < MAXBUCK) {                   // defensive (impossible stat.)
            unsigned pay = ((unsigned)col[e] << 16) | (unsigned)f2h(w[e]);
            ebuf[(size_t)b * MAXBUCK + idx] =
                ((unsigned long long)(unsigned)r << 32) | pay;
        }
    }
}

// ---- Build pass 2: one block per bucket; slot ranks via LDS atomics only.
// pslot writes for a bucket land in a 48KB region -> L2-merged full lines.
// Also writes cnt (no global memset needed).
__global__ __launch_bounds__(256) void k_place(const int* __restrict__ bbase,
                                               const unsigned long long* __restrict__ ebuf,
                                               int* __restrict__ cnt,
                                               unsigned* __restrict__ pslots) {
    __shared__ int cl[1 << BSH];
    const int t = threadIdx.x;
    const int b = blockIdx.x;
    if (t < (1 << BSH)) cl[t] = 0;
    __syncthreads();
    const int n = min(bbase[b], MAXBUCK);
    const unsigned long long* eb = ebuf + (size_t)b * MAXBUCK;
    for (int i = t; i < n; i += 256) {
        unsigned long long pk = eb[i];
        int r = (int)(pk >> 32);
        int k = atomicAdd(&cl[r & ((1 << BSH) - 1)], 1);
        k = min(k, CAP - 1);                   // defensive
        pslots[(size_t)r * CAP + k] = (unsigned)pk;
    }
    __syncthreads();
    int r = (b << BSH) + t;
    if (t < (1 << BSH) && r < NN) cnt[r] = min(cl[t], CAP);
}

#define ASTR 40  // padded LDS row stride in ushorts (32 + 8)

// ---------------- MFMA GEMM, fp32 A (3-term split), bf16 C. Layer 1 only.
__global__ __launch_bounds__(256, 2) void k_gemm_mfma_f32A(
    const float* __restrict__ A, int lda,
    const unsigned short* __restrict__ BhiT,
    const unsigned short* __restrict__ BloT,
    unsigned short* __restrict__ C, int ldc,
    int M, int K, int Ncol)
{
    __shared__ unsigned short Ah[128 * ASTR];
    __shared__ unsigned short Al[128 * ASTR];
    __shared__ unsigned short Bh[128 * ASTR];
    __shared__ unsigned short Bl[128 * ASTR];

    const int tid = threadIdx.x;
    const int lane = tid & 63;
    const int wave = tid >> 6;
    const int wm = wave >> 1, wn = wave & 1;
    const int quad = lane >> 4, l16 = lane & 15;
    const int bm = blockIdx.y * 128, bn = blockIdx.x * 128;
    const int srow = tid >> 1;
    const int skq  = (tid & 1) * 16;

    floatx4 acc[4][4];
#pragma unroll
    for (int i = 0; i < 4; ++i)
#pragma unroll
        for (int j = 0; j < 4; ++j) acc[i][j] = (floatx4){0.f, 0.f, 0.f, 0.f};

    for (int k0 = 0; k0 < K; k0 += 32) {
        float4 a0 = make_float4(0, 0, 0, 0), a1 = a0, a2 = a0, a3 = a0;
        const int ga = bm + srow;
        if (ga < M) {
            const float* Ap = A + (size_t)ga * lda + k0 + skq;
            a0 = *(const float4*)(Ap + 0);
            a1 = *(const float4*)(Ap + 4);
            a2 = *(const float4*)(Ap + 8);
            a3 = *(const float4*)(Ap + 12);
        }
        uint4 bh0 = make_uint4(0, 0, 0, 0), bh1 = bh0, bl0 = bh0, bl1 = bh0;
        const int gb2 = bn + srow;
        if (gb2 < Ncol) {
            const unsigned short* ph = BhiT + (size_t)gb2 * K + k0 + skq;
            const unsigned short* pl = BloT + (size_t)gb2 * K + k0 + skq;
            bh0 = *(const uint4*)(ph);
            bh1 = *(const uint4*)(ph + 8);
            bl0 = *(const uint4*)(pl);
            bl1 = *(const uint4*)(pl + 8);
        }
        __attribute__((aligned(16))) unsigned short ah[16], al[16];
        const float av[16] = {a0.x, a0.y, a0.z, a0.w, a1.x, a1.y, a1.z, a1.w,
                              a2.x, a2.y, a2.z, a2.w, a3.x, a3.y, a3.z, a3.w};
#pragma unroll
        for (int i = 0; i < 16; ++i) split_bf16(av[i], ah[i], al[i]);

        __syncthreads();
        *(uint4*)&Ah[srow * ASTR + skq]     = *(const uint4*)&ah[0];
        *(uint4*)&Ah[srow * ASTR + skq + 8] = *(const uint4*)&ah[8];
        *(uint4*)&Al[srow * ASTR + skq]     = *(const uint4*)&al[0];
        *(uint4*)&Al[srow * ASTR + skq + 8] = *(const uint4*)&al[8];
        *(uint4*)&Bh[srow * ASTR + skq]     = bh0;
        *(uint4*)&Bh[srow * ASTR + skq + 8] = bh1;
        *(uint4*)&Bl[srow * ASTR + skq]     = bl0;
        *(uint4*)&Bl[srow * ASTR + skq + 8] = bl1;
        __syncthreads();

        short8_t afh[4], afl[4], bfh[4], bfl[4];
#pragma unroll
        for (int t = 0; t < 4; ++t) {
            const int m = wm * 64 + t * 16 + l16;
            afh[t] = *(const short8_t*)&Ah[m * ASTR + quad * 8];
            afl[t] = *(const short8_t*)&Al[m * ASTR + quad * 8];
            const int n = wn * 64 + t * 16 + l16;
            bfh[t] = *(const short8_t*)&Bh[n * ASTR + quad * 8];
            bfl[t] = *(const short8_t*)&Bl[n * ASTR + quad * 8];
        }
#pragma unroll
        for (int i = 0; i < 4; ++i)
#pragma unroll
            for (int j = 0; j < 4; ++j) {
                acc[i][j] = __builtin_amdgcn_mfma_f32_16x16x32_bf16(afh[i], bfh[j], acc[i][j], 0, 0, 0);
                acc[i][j] = __builtin_amdgcn_mfma_f32_16x16x32_bf16(afh[i], bfl[j], acc[i][j], 0, 0, 0);
                acc[i][j] = __builtin_amdgcn_mfma_f32_16x16x32_bf16(afl[i], bfh[j], acc[i][j], 0, 0, 0);
            }
    }

#pragma unroll
    for (int j = 0; j < 4; ++j) {
        const int colc = bn + wn * 64 + j * 16 + l16;
        if (colc >= Ncol) continue;
#pragma unroll
        for (int i = 0; i < 4; ++i) {
#pragma unroll
            for (int r = 0; r < 4; ++r) {
                const int rowc = bm + wm * 64 + i * 16 + quad * 4 + r;
                if (rowc >= M) continue;
                C[(size_t)rowc * ldc + colc] = f2bf(acc[i][j][r]);
            }
        }
    }
}

// dinv[r] = rsqrt(sum of raw w over row r), 0 if deg<=0 (atomic-free)
__global__ __launch_bounds__(256) void k_degsum(const int* __restrict__ cnt,
                                                const unsigned* __restrict__ pslots,
                                                float* __restrict__ dinv) {
    int tid = threadIdx.x;
    int lane = tid & 15;
    int node = blockIdx.x * 16 + (tid >> 4);
    if (node >= NN) return;
    int e = cnt[node];
    const unsigned* base = pslots + (size_t)node * CAP;
    float s = 0.0f;
    for (int k = lane; k < e; k += 16) s += h2f(base[k]);
#pragma unroll
    for (int m = 8; m >= 1; m >>= 1) s += __shfl_xor(s, m);
    if (lane == 0) dinv[node] = (s > 0.0f) ? rsqrtf(s) : 0.0f;
}

// In-place: weight half of pslot <- fp16(-w * dinv[r] * dinv[col])
__global__ __launch_bounds__(256) void k_repack(const int* __restrict__ cnt,
                                                unsigned* __restrict__ pslots,
                                                const float* __restrict__ dinv) {
    int tid = threadIdx.x;
    int lane = tid & 15;
    int node = blockIdx.x * 16 + (tid >> 4);
    if (node >= NN) return;
    int e = cnt[node];
    float dr = dinv[node];
    unsigned* pb = pslots + (size_t)node * CAP;
    for (int k = lane; k < e; k += 16) {
        unsigned s = pb[k];
        float wv = -h2f(s) * dr * dinv[s >> 16];
        pb[k] = (s & 0xFFFF0000u) | (unsigned)f2h(wv);
    }
}

// ---------------- MFMA GEMM, bf16 A direct (2-term W split). Layers 3/4/5.
// swz=1 (L5 only): 1D grid, XCD-pair swizzle — both N-halves of M-tile y land
// on XCD y%8 so the A-panel is HBM-fetched once (r19).
__global__ __launch_bounds__(256, 2) void k_gemm_mfma_bf(
    const unsigned short* __restrict__ A, int lda,
    const unsigned short* __restrict__ BhiT,
    const unsigned short* __restrict__ BloT,
    unsigned short* __restrict__ C, int ldc,
    int M, int K, int Ncol,
    const float* __restrict__ bias, int act, int swz)
{
    __shared__ unsigned short Ah[128 * ASTR];
    __shared__ unsigned short Bh[128 * ASTR];
    __shared__ unsigned short Bl[128 * ASTR];

    const int tid = threadIdx.x;
    const int lane = tid & 63;
    const int wave = tid >> 6;
    const int wm = wave >> 1, wn = wave & 1;
    const int quad = lane >> 4, l16 = lane & 15;
    int bm, bn;
    if (swz) {
        const int s = blockIdx.x;
        const int xcd = s & 7;
        const int k = s >> 3;
        bn = (k & 1) * 128;
        const int y = xcd + 8 * (k >> 1);
        bm = y * 128;
        if (bm >= M) return;               // uniform per block (before barriers)
    } else {
        bm = blockIdx.y * 128;
        bn = blockIdx.x * 128;
    }
    const int srow = tid >> 1;
    const int skq  = (tid & 1) * 16;

    floatx4 acc[4][4];
#pragma unroll
    for (int i = 0; i < 4; ++i)
#pragma unroll
        for (int j = 0; j < 4; ++j) acc[i][j] = (floatx4){0.f, 0.f, 0.f, 0.f};

    for (int k0 = 0; k0 < K; k0 += 32) {
        uint4 a0 = make_uint4(0, 0, 0, 0), a1 = a0;
        const int ga = bm + srow;
        if (ga < M) {
            const unsigned short* Ap = A + (size_t)ga * lda + k0 + skq;
            a0 = *(const uint4*)(Ap);
            a1 = *(const uint4*)(Ap + 8);
        }
        uint4 bh0 = make_uint4(0, 0, 0, 0), bh1 = bh0, bl0 = bh0, bl1 = bh0;
        const int gb = bn + srow;
        if (gb < Ncol) {
            const unsigned short* ph = BhiT + (size_t)gb * K + k0 + skq;
            const unsigned short* pl = BloT + (size_t)gb * K + k0 + skq;
            bh0 = *(const uint4*)(ph);
            bh1 = *(const uint4*)(ph + 8);
            bl0 = *(const uint4*)(pl);
            bl1 = *(const uint4*)(pl + 8);
        }
        __syncthreads();
        *(uint4*)&Ah[srow * ASTR + skq]     = a0;
        *(uint4*)&Ah[srow * ASTR + skq + 8] = a1;
        *(uint4*)&Bh[srow * ASTR + skq]     = bh0;
        *(uint4*)&Bh[srow * ASTR + skq + 8] = bh1;
        *(uint4*)&Bl[srow * ASTR + skq]     = bl0;
        *(uint4*)&Bl[srow * ASTR + skq + 8] = bl1;
        __syncthreads();

        short8_t afh[4], bfh[4], bfl[4];
#pragma unroll
        for (int t = 0; t < 4; ++t) {
            const int m = wm * 64 + t * 16 + l16;
            afh[t] = *(const short8_t*)&Ah[m * ASTR + quad * 8];
            const int n = wn * 64 + t * 16 + l16;
            bfh[t] = *(const short8_t*)&Bh[n * ASTR + quad * 8];
            bfl[t] = *(const short8_t*)&Bl[n * ASTR + quad * 8];
        }
#pragma unroll
        for (int i = 0; i < 4; ++i)
#pragma unroll
            for (int j = 0; j < 4; ++j) {
                acc[i][j] = __builtin_amdgcn_mfma_f32_16x16x32_bf16(afh[i], bfh[j], acc[i][j], 0, 0, 0);
                acc[i][j] = __builtin_amdgcn_mfma_f32_16x16x32_bf16(afh[i], bfl[j], acc[i][j], 0, 0, 0);
            }
    }

#pragma unroll
    for (int j = 0; j < 4; ++j) {
        const int col = bn + wn * 64 + j * 16 + l16;
        if (col >= Ncol) continue;
        const float bv = bias ? bias[col] : 0.0f;
#pragma unroll
        for (int i = 0; i < 4; ++i) {
#pragma unroll
            for (int r = 0; r < 4; ++r) {
                const int row = bm + wm * 64 + i * 16 + quad * 4 + r;
                if (row >= M) continue;
                float v = acc[i][j][r] + bv;
                if (act) v = softplusf(v);
                C[(size_t)row * ldc + col] = f2bf(v);
            }
        }
    }
}

// fp32-weight vector GEMM with bf16 A and bf16 C (layer 2 only, K=48)
__global__ __launch_bounds__(256) void k_gemm(
    const unsigned short* __restrict__ A, int lda,
    const float* __restrict__ B, int ldb,
    unsigned short* __restrict__ C, int ldc,
    int M, int K, int Ncol,
    const float* __restrict__ bias, int act)
{
    __shared__ float As[16][128];
    __shared__ float Bs[16][128];
    const int tid = threadIdx.x;
    const int tx = tid & 15;
    const int ty = tid >> 4;
    const int bm = blockIdx.y * 128;
    const int bn = blockIdx.x * 128;
    const int arow = tid >> 1;
    const int akq = (tid & 1) * 8;
    const int bkr = tid >> 4;
    const int bcq = (tid & 15) * 8;

    float acc[8][8];
#pragma unroll
    for (int i = 0; i < 8; ++i)
#pragma unroll
        for (int j = 0; j < 8; ++j) acc[i][j] = 0.0f;

    for (int k0 = 0; k0 < K; k0 += 16) {
        uint4 ald = make_uint4(0, 0, 0, 0);
        int gr = bm + arow;
        if (gr < M) ald = *(const uint4*)(A + (size_t)gr * lda + k0 + akq);
        float4 b0 = make_float4(0, 0, 0, 0), b1 = make_float4(0, 0, 0, 0);
        int cb = bn + bcq;
        const float* Bp = B + (k0 + bkr) * ldb;
        if (cb < Ncol)     b0 = *(const float4*)(Bp + cb);
        if (cb + 4 < Ncol) b1 = *(const float4*)(Bp + cb + 4);
        __syncthreads();
        const unsigned short* au = (const unsigned short*)&ald;
#pragma unroll
        for (int i = 0; i < 8; ++i) As[akq + i][arow] = bf2f(au[i]);
        *(float4*)&Bs[bkr][bcq] = b0;
        *(float4*)&Bs[bkr][bcq + 4] = b1;
        __syncthreads();
#pragma unroll
        for (int kk = 0; kk < 16; ++kk) {
            float a[8], b[8];
            float4 t;
            t = *(const float4*)&As[kk][ty * 4];      a[0] = t.x; a[1] = t.y; a[2] = t.z; a[3] = t.w;
            t = *(const float4*)&As[kk][64 + ty * 4]; a[4] = t.x; a[5] = t.y; a[6] = t.z; a[7] = t.w;
            t = *(const float4*)&Bs[kk][tx * 4];      b[0] = t.x; b[1] = t.y; b[2] = t.z; b[3] = t.w;
            t = *(const float4*)&Bs[kk][64 + tx * 4]; b[4] = t.x; b[5] = t.y; b[6] = t.z; b[7] = t.w;
#pragma unroll
            for (int i = 0; i < 8; ++i)
#pragma unroll
                for (int j = 0; j < 8; ++j)
                    acc[i][j] = fmaf(a[i], b[j], acc[i][j]);
        }
    }
#pragma unroll
    for (int i = 0; i < 8; ++i) {
        int r = bm + ((i < 4) ? (ty * 4 + i) : (64 + ty * 4 + i - 4));
        if (r >= M) continue;
#pragma unroll
        for (int j = 0; j < 8; ++j) {
            int cl = bn + ((j < 4) ? (tx * 4 + j) : (64 + tx * 4 + j - 4));
            if (cl >= Ncol) continue;
            float v = acc[i][j];
            if (bias) v += bias[cl];
            if (act) v = softplusf(v);
            C[(size_t)r * ldc + cl] = f2bf(v);
        }
    }
}

// Slotted propagation, 4 bf16 feats/lane (us4 8B gathers), 8 edges in flight.
// Layers 1-3 (proven r8 structure).
__global__ __launch_bounds__(256) void k_prop(
    const int* __restrict__ cnt, const unsigned* __restrict__ pslots,
    const unsigned short* __restrict__ z, int zld, int zoff,
    unsigned short* __restrict__ out, int outld, int ooff,
    int ltw, float alpha,
    const unsigned short* __restrict__ add1, int a1ld, int a1off, float c1,
    const unsigned short* __restrict__ add2, int a2ld, int a2off,
    const float* __restrict__ bias, int act)
{
    const int T = 1 << ltw;
    const int lane = threadIdx.x & (T - 1);
    const int node = blockIdx.x * (256 >> ltw) + (threadIdx.x >> ltw);
    if (node >= NN) return;
    const int f4 = lane * 4;
    const int e = cnt[node];
    const unsigned* base = pslots + (size_t)node * CAP;
    float accA[4] = {0, 0, 0, 0};
    float accB[4] = {0, 0, 0, 0};
    const unsigned short* zp = z + zoff + f4;
    int p = 0;
    for (; p + 8 <= e; p += 8) {
        unsigned s0 = base[p + 0], s1 = base[p + 1], s2 = base[p + 2], s3 = base[p + 3];
        unsigned s4 = base[p + 4], s5 = base[p + 5], s6 = base[p + 6], s7 = base[p + 7];
        const us4 z0 = *(const us4*)(zp + (size_t)(s0 >> 16) * zld);
        const us4 z1 = *(const us4*)(zp + (size_t)(s1 >> 16) * zld);
        const us4 z2 = *(const us4*)(zp + (size_t)(s2 >> 16) * zld);
        const us4 z3 = *(const us4*)(zp + (size_t)(s3 >> 16) * zld);
        const us4 z4 = *(const us4*)(zp + (size_t)(s4 >> 16) * zld);
        const us4 z5 = *(const us4*)(zp + (size_t)(s5 >> 16) * zld);
        const us4 z6 = *(const us4*)(zp + (size_t)(s6 >> 16) * zld);
        const us4 z7 = *(const us4*)(zp + (size_t)(s7 >> 16) * zld);
        float w0 = h2f(s0), w1 = h2f(s1), w2 = h2f(s2), w3 = h2f(s3);
        float w4 = h2f(s4), w5 = h2f(s5), w6 = h2f(s6), w7 = h2f(s7);
#pragma unroll
        for (int i = 0; i < 4; ++i) {
            accA[i] = fmaf(w0, bf2f(z0[i]), accA[i]);
            accB[i] = fmaf(w1, bf2f(z1[i]), accB[i]);
            accA[i] = fmaf(w2, bf2f(z2[i]), accA[i]);
            accB[i] = fmaf(w3, bf2f(z3[i]), accB[i]);
            accA[i] = fmaf(w4, bf2f(z4[i]), accA[i]);
            accB[i] = fmaf(w5, bf2f(z5[i]), accB[i]);
            accA[i] = fmaf(w6, bf2f(z6[i]), accA[i]);
            accB[i] = fmaf(w7, bf2f(z7[i]), accB[i]);
        }
    }
    for (; p + 4 <= e; p += 4) {
        unsigned s0 = base[p + 0], s1 = base[p + 1], s2 = base[p + 2], s3 = base[p + 3];
        const us4 z0 = *(const us4*)(zp + (size_t)(s0 >> 16) * zld);
        const us4 z1 = *(const us4*)(zp + (size_t)(s1 >> 16) * zld);
        const us4 z2 = *(const us4*)(zp + (size_t)(s2 >> 16) * zld);
        const us4 z3 = *(const us4*)(zp + (size_t)(s3 >> 16) * zld);
        float w0 = h2f(s0), w1 = h2f(s1), w2 = h2f(s2), w3 = h2f(s3);
#pragma unroll
        for (int i = 0; i < 4; ++i) {
            accA[i] = fmaf(w0, bf2f(z0[i]), accA[i]);
            accB[i] = fmaf(w1, bf2f(z1[i]), accB[i]);
            accA[i] = fmaf(w2, bf2f(z2[i]), accA[i]);
            accB[i] = fmaf(w3, bf2f(z3[i]), accB[i]);
        }
    }
    for (; p < e; ++p) {
        unsigned s = base[p];
        float wv = h2f(s);
        const us4 zv = *(const us4*)(zp + (size_t)(s >> 16) * zld);
#pragma unroll
        for (int i = 0; i < 4; ++i) accA[i] = fmaf(wv, bf2f(zv[i]), accA[i]);
    }
#pragma unroll
    for (int i = 0; i < 4; ++i) accA[i] = alpha * (accA[i] + accB[i]);
    if (add1) {
        const us4 t = *(const us4*)(add1 + (size_t)node * a1ld + a1off + f4);
#pragma unroll
        for (int i = 0; i < 4; ++i) accA[i] = fmaf(c1, bf2f(t[i]), accA[i]);
    }
    if (add2) {
        const us4 t = *(const us4*)(add2 + (size_t)node * a2ld + a2off + f4);
#pragma unroll
        for (int i = 0; i < 4; ++i) accA[i] += bf2f(t[i]);
    }
    if (bias) {
        const float4 t = *(const float4*)(bias + f4);
        accA[0] += t.x; accA[1] += t.y; accA[2] += t.z; accA[3] += t.w;
    }
    if (act) {
#pragma unroll
        for (int i = 0; i < 4; ++i) accA[i] = softplusf(accA[i]);
    }
    us4 o;
#pragma unroll
    for (int i = 0; i < 4; ++i) o[i] = f2bf(accA[i]);
    *(us4*)(out + (size_t)node * outld + ooff + f4) = o;
}

// r17 structure, 16 edges in flight (fully unrolled, compile-time indices).
// Layer 4 call sites.
__global__ __launch_bounds__(256) void k_prop16(
    const int* __restrict__ cnt, const unsigned* __restrict__ pslots,
    const unsigned short* __restrict__ z, int zld, int zoff,
    unsigned short* __restrict__ out, int outld, int ooff,
    int ltw, float alpha,
    const unsigned short* __restrict__ add1, int a1ld, int a1off, float c1)
{
    const int T = 1 << ltw;
    const int lane = threadIdx.x & (T - 1);
    const int node = blockIdx.x * (256 >> ltw) + (threadIdx.x >> ltw);
    if (node >= NN) return;
    const int f4 = lane * 4;
    const int e = cnt[node];
    const unsigned* base = pslots + (size_t)node * CAP;
    float accA[4] = {0, 0, 0, 0};
    float accB[4] = {0, 0, 0, 0};
    const unsigned short* zp = z + zoff + f4;
    int p = 0;
    for (; p + 16 <= e; p += 16) {
        unsigned s[16];
#pragma unroll
        for (int q = 0; q < 16; ++q) s[q] = base[p + q];
        us4 zv[16];
#pragma unroll
        for (int q = 0; q < 16; ++q)
            zv[q] = *(const us4*)(zp + (size_t)(s[q] >> 16) * zld);
#pragma unroll
        for (int q = 0; q < 16; q += 2) {
            float wa = h2f(s[q]), wb = h2f(s[q + 1]);
#pragma unroll
            for (int i = 0; i < 4; ++i) {
                accA[i] = fmaf(wa, bf2f(zv[q][i]), accA[i]);
                accB[i] = fmaf(wb, bf2f(zv[q + 1][i]), accB[i]);
            }
        }
    }
    for (; p + 8 <= e; p += 8) {
        unsigned s0 = base[p + 0], s1 = base[p + 1], s2 = base[p + 2], s3 = base[p + 3];
        unsigned s4 = base[p + 4], s5 = base[p + 5], s6 = base[p + 6], s7 = base[p + 7];
        const us4 z0 = *(const us4*)(zp + (size_t)(s0 >> 16) * zld);
        const us4 z1 = *(const us4*)(zp + (size_t)(s1 >> 16) * zld);
        const us4 z2 = *(const us4*)(zp + (size_t)(s2 >> 16) * zld);
        const us4 z3 = *(const us4*)(zp + (size_t)(s3 >> 16) * zld);
        const us4 z4 = *(const us4*)(zp + (size_t)(s4 >> 16) * zld);
        const us4 z5 = *(const us4*)(zp + (size_t)(s5 >> 16) * zld);
        const us4 z6 = *(const us4*)(zp + (size_t)(s6 >> 16) * zld);
        const us4 z7 = *(const us4*)(zp + (size_t)(s7 >> 16) * zld);
        float w0 = h2f(s0), w1 = h2f(s1), w2 = h2f(s2), w3 = h2f(s3);
        float w4 = h2f(s4), w5 = h2f(s5), w6 = h2f(s6), w7 = h2f(s7);
#pragma unroll
        for (int i = 0; i < 4; ++i) {
            accA[i] = fmaf(w0, bf2f(z0[i]), accA[i]);
            accB[i] = fmaf(w1, bf2f(z1[i]), accB[i]);
            accA[i] = fmaf(w2, bf2f(z2[i]), accA[i]);
            accB[i] = fmaf(w3, bf2f(z3[i]), accB[i]);
            accA[i] = fmaf(w4, bf2f(z4[i]), accA[i]);
            accB[i] = fmaf(w5, bf2f(z5[i]), accB[i]);
            accA[i] = fmaf(w6, bf2f(z6[i]), accA[i]);
            accB[i] = fmaf(w7, bf2f(z7[i]), accB[i]);
        }
    }
    for (; p + 4 <= e; p += 4) {
        unsigned s0 = base[p + 0], s1 = base[p + 1], s2 = base[p + 2], s3 = base[p + 3];
        const us4 z0 = *(const us4*)(zp + (size_t)(s0 >> 16) * zld);
        const us4 z1 = *(const us4*)(zp + (size_t)(s1 >> 16) * zld);
        const us4 z2 = *(const us4*)(zp + (size_t)(s2 >> 16) * zld);
        const us4 z3 = *(const us4*)(zp + (size_t)(s3 >> 16) * zld);
        float w0 = h2f(s0), w1 = h2f(s1), w2 = h2f(s2), w3 = h2f(s3);
#pragma unroll
        for (int i = 0; i < 4; ++i) {
            accA[i] = fmaf(w0, bf2f(z0[i]), accA[i]);
            accB[i] = fmaf(w1, bf2f(z1[i]), accB[i]);
            accA[i] = fmaf(w2, bf2f(z2[i]), accA[i]);
            accB[i] = fmaf(w3, bf2f(z3[i]), accB[i]);
        }
    }
    for (; p < e; ++p) {
        unsigned s = base[p];
        float wv = h2f(s);
        const us4 zv = *(const us4*)(zp + (size_t)(s >> 16) * zld);
#pragma unroll
        for (int i = 0; i < 4; ++i) accA[i] = fmaf(wv, bf2f(zv[i]), accA[i]);
    }
#pragma unroll
    for (int i = 0; i < 4; ++i) accA[i] = alpha * (accA[i] + accB[i]);
    if (add1) {
        const us4 t = *(const us4*)(add1 + (size_t)node * a1ld + a1off + f4);
#pragma unroll
        for (int i = 0; i < 4; ++i) accA[i] = fmaf(c1, bf2f(t[i]), accA[i]);
    }
    us4 o;
#pragma unroll
    for (int i = 0; i < 4; ++i) o[i] = f2bf(accA[i]);
    *(us4*)(out + (size_t)node * outld + ooff + f4) = o;
}

// r18: L5-only 2-way feature-sliced prop with XCD-aware block mapping.
// (verified r8->r18: FETCH 157->116MB, 59.2->55.8us)
__global__ __launch_bounds__(256) void k_prop16s(
    const int* __restrict__ cnt, const unsigned* __restrict__ pslots,
    const unsigned short* __restrict__ z, int zld, int zoff,
    unsigned short* __restrict__ out, int outld, int ooff,
    float alpha,
    const unsigned short* __restrict__ add1, int a1ld, int a1off, float c1)
{
    const int o8 = blockIdx.x & 7;
    const int g8 = blockIdx.x >> 3;
    const int slice = o8 >> 2;                  // 0 for XCDs 0-3, 1 for 4-7
    const int nb = g8 * 4 + (o8 & 3);           // node-block within slice
    if (nb >= 3125) return;
    const int lane = threadIdx.x & 15;
    const int node = nb * 16 + (threadIdx.x >> 4);
    const int f4 = slice * 64 + lane * 4;       // feature offset (ushorts)
    const int e = cnt[node];
    const unsigned* base = pslots + (size_t)node * CAP;
    float accA[4] = {0, 0, 0, 0};
    float accB[4] = {0, 0, 0, 0};
    const unsigned short* zp = z + zoff + f4;
    int p = 0;
    for (; p + 16 <= e; p += 16) {
        unsigned s[16];
#pragma unroll
        for (int q = 0; q < 16; ++q) s[q] = base[p + q];
        us4 zv[16];
#pragma unroll
        for (int q = 0; q < 16; ++q)
            zv[q] = *(const us4*)(zp + (size_t)(s[q] >> 16) * zld);
#pragma unroll
        for (int q = 0; q < 16; q += 2) {
            float wa = h2f(s[q]), wb = h2f(s[q + 1]);
#pragma unroll
            for (int i = 0; i < 4; ++i) {
                accA[i] = fmaf(wa, bf2f(zv[q][i]), accA[i]);
                accB[i] = fmaf(wb, bf2f(zv[q + 1][i]), accB[i]);
            }
        }
    }
    for (; p + 8 <= e; p += 8) {
        unsigned s0 = base[p + 0], s1 = base[p + 1], s2 = base[p + 2], s3 = base[p + 3];
        unsigned s4 = base[p + 4], s5 = base[p + 5], s6 = base[p + 6], s7 = base[p + 7];
        const us4 z0 = *(const us4*)(zp + (size_t)(s0 >> 16) * zld);
        const us4 z1 = *(const us4*)(zp + (size_t)(s1 >> 16) * zld);
        const us4 z2 = *(const us4*)(zp + (size_t)(s2 >> 16) * zld);
        const us4 z3 = *(const us4*)(zp + (size_t)(s3 >> 16) * zld);
        const us4 z4 = *(const us4*)(zp + (size_t)(s4 >> 16) * zld);
        const us4 z5 = *(const us4*)(zp + (size_t)(s5 >> 16) * zld);
        const us4 z6 = *(const us4*)(zp + (size_t)(s6 >> 16) * zld);
        const us4 z7 = *(const us4*)(zp + (size_t)(s7 >> 16) * zld);
        float w0 = h2f(s0), w1 = h2f(s1), w2 = h2f(s2), w3 = h2f(s3);
        float w4 = h2f(s4), w5 = h2f(s5), w6 = h2f(s6), w7 = h2f(s7);
#pragma unroll
        for (int i = 0; i < 4; ++i) {
            accA[i] = fmaf(w0, bf2f(z0[i]), accA[i]);
            accB[i] = fmaf(w1, bf2f(z1[i]), accB[i]);
            accA[i] = fmaf(w2, bf2f(z2[i]), accA[i]);
            accB[i] = fmaf(w3, bf2f(z3[i]), accB[i]);
            accA[i] = fmaf(w4, bf2f(z4[i]), accA[i]);
            accB[i] = fmaf(w5, bf2f(z5[i]), accB[i]);
            accA[i] = fmaf(w6, bf2f(z6[i]), accA[i]);
            accB[i] = fmaf(w7, bf2f(z7[i]), accB[i]);
        }
    }
    for (; p + 4 <= e; p += 4) {
        unsigned s0 = base[p + 0], s1 = base[p + 1], s2 = base[p + 2], s3 = base[p + 3];
        const us4 z0 = *(const us4*)(zp + (size_t)(s0 >> 16) * zld);
        const us4 z1 = *(const us4*)(zp + (size_t)(s1 >> 16) * zld);
        const us4 z2 = *(const us4*)(zp + (size_t)(s2 >> 16) * zld);
        const us4 z3 = *(const us4*)(zp + (size_t)(s3 >> 16) * zld);
        float w0 = h2f(s0), w1 = h2f(s1), w2 = h2f(s2), w3 = h2f(s3);
#pragma unroll
        for (int i = 0; i < 4; ++i) {
            accA[i] = fmaf(w0, bf2f(z0[i]), accA[i]);
            accB[i] = fmaf(w1, bf2f(z1[i]), accB[i]);
            accA[i] = fmaf(w2, bf2f(z2[i]), accA[i]);
            accB[i] = fmaf(w3, bf2f(z3[i]), accB[i]);
        }
    }
    for (; p < e; ++p) {
        unsigned s = base[p];
        float wv = h2f(s);
        const us4 zv = *(const us4*)(zp + (size_t)(s >> 16) * zld);
#pragma unroll
        for (int i = 0; i < 4; ++i) accA[i] = fmaf(wv, bf2f(zv[i]), accA[i]);
    }
#pragma unroll
    for (int i = 0; i < 4; ++i) accA[i] = alpha * (accA[i] + accB[i]);
    if (add1) {
        const us4 t = *(const us4*)(add1 + (size_t)node * a1ld + a1off + f4);
#pragma unroll
        for (int i = 0; i < 4; ++i) accA[i] = fmaf(c1, bf2f(t[i]), accA[i]);
    }
    us4 o;
#pragma unroll
    for (int i = 0; i < 4; ++i) o[i] = f2bf(accA[i]);
    *(us4*)(out + (size_t)node * outld + ooff + f4) = o;
}

__global__ __launch_bounds__(256) void k_bnstats(const unsigned short* __restrict__ h, int ld, int lc,
                                                 float* __restrict__ stats) {
    const int C = 1 << lc;
    const int tid = threadIdx.x;
    const int c = tid & (C - 1);
    const int rpb = 256 >> lc;
    int r = blockIdx.x * rpb + (tid >> lc);
    const int stride = gridDim.x * rpb;
    float s = 0.0f, q = 0.0f;
    for (; r < NN; r += stride) {
        float v = bf2f(h[(size_t)r * ld + c]);
        s += v;
        q = fmaf(v, v, q);
    }
    __shared__ float shs[256], shq[256];
    shs[tid] = s; shq[tid] = q;
    __syncthreads();
    for (int o = 128; o >= C; o >>= 1) {
        if (tid < o) { shs[tid] += shs[tid + o]; shq[tid] += shq[tid + o]; }
        __syncthreads();
    }
    if (tid < C) {
        atomicAdd(&stats[c], shs[tid]);
        atomicAdd(&stats[128 + c], shq[tid]);
    }
}

// Vectorized BN apply: 8 elems/thread.
__global__ void k_bnapply(unsigned short* __restrict__ h, int ld, int lc,
                          const float* __restrict__ stats,
                          const float* __restrict__ g, const float* __restrict__ be) {
    int idx = blockIdx.x * 256 + threadIdx.x;        // in units of 8 elems
    const int C8 = 1 << (lc - 3);
    if (idx >= NN * C8) return;
    int r = idx >> (lc - 3);
    int c0 = (idx & (C8 - 1)) << 3;
    const float invN = 1.0f / (float)NN;
    unsigned short* hp = h + (size_t)r * ld + c0;
    us8 v = *(const us8*)hp;
    us8 o;
#pragma unroll
    for (int i = 0; i < 8; ++i) {
        int c = c0 + i;
        float m = stats[c] * invN;
        float var = fmaf(stats[128 + c], invN, -m * m);
        var = fmaxf(var, 0.0f);
        float inv = rsqrtf(var + 1e-5f);
        o[i] = f2bf(fmaf(g[c] * inv, bf2f(v[i]) - m, be[c]));
    }
    *(us8*)hp = o;
}

// Pool stage 1 over bf16 h5.
__global__ __launch_bounds__(256) void k_pool1(const unsigned short* __restrict__ h,
                                               const int* __restrict__ gb,
                                               float* __restrict__ partial) {
    int g = blockIdx.y;
    int j = blockIdx.x;
    int start = gb[g], end = gb[g + 1];
    int len = end - start;
    int chunk = (len + 15) >> 4;
    int s = start + j * chunk;
    int e = min(s + chunk, end);
    int c = threadIdx.x;
    float mx = -INFINITY, sum = 0.0f;
    for (int r = s; r < e; ++r) {
        float v = bf2f(h[(size_t)r * 256 + c]);
        mx = fmaxf(mx, v);
        sum += v;
    }
    size_t base = ((size_t)(g * 16 + j)) * 512;
    partial[base + c] = mx;
    partial[base + 256 + c] = sum;
}

// Fused pool stage 2 + dense + log_softmax: 64 blocks.
__global__ __launch_bounds__(256) void k_pool2d(const float* __restrict__ partial,
                                                const int* __restrict__ gb,
                                                const float* __restrict__ Wd,
                                                const float* __restrict__ bd,
                                                float* __restrict__ out) {
    __shared__ float pl[512];
    __shared__ float red[4][256];
    int g = blockIdx.x;
    int c = threadIdx.x;
    float mx = -INFINITY, sum = 0.0f;
#pragma unroll
    for (int j = 0; j < 16; ++j) {
        size_t base = ((size_t)(g * 16 + j)) * 512;
        mx = fmaxf(mx, partial[base + c]);
        sum += partial[base + 256 + c];
    }
    int len = gb[g + 1] - gb[g];
    pl[c] = (len > 0) ? mx : 0.0f;
    pl[256 + c] = sum / fmaxf((float)len, 1.0f);
    __syncthreads();
    float p[4] = {0, 0, 0, 0};
    for (int k = c; k < 512; k += 256) {
        float pv = pl[k];
#pragma unroll
        for (int cc = 0; cc < 4; ++cc) p[cc] = fmaf(pv, Wd[k * 4 + cc], p[cc]);
    }
#pragma unroll
    for (int cc = 0; cc < 4; ++cc) red[cc][c] = p[cc];
    __syncthreads();
    for (int o = 128; o >= 1; o >>= 1) {
        if (c < o) {
#pragma unroll
            for (int cc = 0; cc < 4; ++cc) red[cc][c] += red[cc][c + o];
        }
        __syncthreads();
    }
    if (c == 0) {
        float l0 = red[0][0] + bd[0], l1 = red[1][0] + bd[1];
        float l2 = red[2][0] + bd[2], l3 = red[3][0] + bd[3];
        float m = fmaxf(fmaxf(l0, l1), fmaxf(l2, l3));
        float ls = m + logf(expf(l0 - m) + expf(l1 - m) + expf(l2 - m) + expf(l3 - m));
        out[g * 4 + 0] = l0 - ls;
        out[g * 4 + 1] = l1 - ls;
        out[g * 4 + 2] = l2 - ls;
        out[g * 4 + 3] = l3 - ls;
    }
}

extern "C" void kernel_launch(void* const* d_in, const int* in_sizes, int n_in,
                              void* d_out, int out_size, void* d_ws, size_t ws_size,
                              hipStream_t stream)
{
    const float* x    = (const float*)d_in[0];
    const float* ew   = (const float*)d_in[1];
    const int*   row  = (const int*)d_in[2];
    const int*   colp = row + NE;
    const int*   batch = (const int*)d_in[3];
    const float* W1 = (const float*)d_in[4];
    const float* b1 = (const float*)d_in[5];
    const float* g1 = (const float*)d_in[6];
    const float* be1 = (const float*)d_in[7];
    const float* W2 = (const float*)d_in[8];
    const float* b2 = (const float*)d_in[9];
    const float* g2 = (const float*)d_in[10];
    const float* be2 = (const float*)d_in[11];
    const float* W3 = (const float*)d_in[12];
    const float* b3 = (const float*)d_in[13];
    const float* g3 = (const float*)d_in[14];
    const float* be3 = (const float*)d_in[15];
    const float* W4 = (const float*)d_in[16];
    const float* b4 = (const float*)d_in[17];
    const float* g4 = (const float*)d_in[18];
    const float* be4 = (const float*)d_in[19];
    const float* W5 = (const float*)d_in[20];
    const float* b5 = (const float*)d_in[21];
    const float* Wd = (const float*)d_in[22];
    const float* bd = (const float*)d_in[23];
    float* outp = (float*)d_out;
    (void)in_sizes; (void)n_in; (void)out_size; (void)ws_size; (void)ew;

    char* wsb = (char*)d_ws;
    size_t off = 0;
    auto take = [&](size_t bytes) -> void* {
        void* p = wsb + off;
        off = (off + bytes + 255) & ~(size_t)255;
        return p;
    };
    // Layout byte-identical to the 764us r15 run (r11 lesson).
    int*   cnt    = (int*)take((size_t)NN * sizeof(int));
    float* dinv   = (float*)take((size_t)NN * sizeof(float));
    int*   gb     = (int*)take((NG + 1) * sizeof(int));
    unsigned* pslots = (unsigned*)take((size_t)NN * CAP * sizeof(unsigned));
    float* statsA = (float*)take(4 * 256 * sizeof(float));
    float* wcat   = (float*)take(6144 * sizeof(float));  // placeholder, unused
    unsigned short* bt1h = (unsigned short*)take(48 * 128 * 2);
    unsigned short* bt1l = (unsigned short*)take(48 * 128 * 2);
    unsigned short* bt3h = (unsigned short*)take(64 * 96 * 2);
    unsigned short* bt3l = (unsigned short*)take(64 * 96 * 2);
    unsigned short* bt4h = (unsigned short*)take(128 * 192 * 2);
    unsigned short* bt4l = (unsigned short*)take(128 * 192 * 2);
    unsigned short* bt5h = (unsigned short*)take(256 * 384 * 2);
    unsigned short* bt5l = (unsigned short*)take(256 * 384 * 2);
    float* partial= (float*)take((size_t)NG * 16 * 512 * sizeof(float));
    unsigned short* P   = (unsigned short*)take((size_t)NN * 48 * 2);
    unsigned short* uv  = (unsigned short*)take((size_t)NN * 32 * 2);
    unsigned short* Hc2 = (unsigned short*)take((size_t)NN * 48 * 2);
    unsigned short* Hc3 = (unsigned short*)take((size_t)NN * 96 * 2);
    unsigned short* Hc4 = (unsigned short*)take((size_t)NN * 192 * 2);
    unsigned short* Hc5 = (unsigned short*)take((size_t)NN * 384 * 2);
    unsigned short* h5  = (unsigned short*)take((size_t)NN * 256 * 2);
    int*   bbase  = (int*)take(NBUCK * sizeof(int));
    (void)wcat;
    // ebuf aliases Hc5: needs NBUCK*MAXBUCK*8 = 19.2MB < Hc5's 38.4MB; dead
    // before k_gemm_mfma_bf(layer 4) first writes Hc5.
    unsigned long long* ebuf = (unsigned long long*)Hc5;

    float* stats1 = statsA;
    float* stats2 = statsA + 256;
    float* stats3 = statsA + 512;
    float* stats4 = statsA + 768;

    hipMemsetAsync(bbase, 0, NBUCK * sizeof(int), stream);
    hipMemsetAsync(statsA, 0, 4 * 256 * sizeof(float), stream);

    // ---- weight prep + graph bounds (single launch)
    k_prep<<<529, 256, 0, stream>>>(W1, W3, W4, W5, batch,
                                    bt1h, bt1l, bt3h, bt3l, bt4h, bt4l,
                                    bt5h, bt5l, gb);

    // ---- adjacency build: bucket-bin (pass 1) + LDS-ranked place (pass 2)
    k_bin<<<256, 256, 0, stream>>>(row, colp, ew, bbase, ebuf);
    k_place<<<NBUCK, 256, 0, stream>>>(bbase, ebuf, cnt, pslots);

    // ---- Layer 1 GEMM (128->48): P = x @ [W0-W2 | W1 | W2]
    k_gemm_mfma_f32A<<<dim3(1, 391), 256, 0, stream>>>(x, 128, bt1h, bt1l, P, 48, NN, 128, 48);

    k_degsum<<<3125, 256, 0, stream>>>(cnt, pslots, dinv);
    k_repack<<<3125, 256, 0, stream>>>(cnt, pslots, dinv);

    // ---- Layer 1 (128->16): h1 = P0 + prop(P1) + 2*prop(prop(P2)) + b
    k_prop<<<1563, 256, 0, stream>>>(cnt, pslots, P, 48, 16, uv, 32, 0, 3, 1.0f,
                                     nullptr, 0, 0, 0.0f, nullptr, 0, 0, nullptr, 0);
    k_prop<<<782, 256, 0, stream>>>(cnt, pslots, uv, 32, 16, Hc2, 48, 0, 2, 2.0f,
                                    P, 48, 0, 1.0f, uv, 32, 0, b1, 1);
    k_bnstats<<<256, 256, 0, stream>>>(Hc2, 48, 4, stats1);
    k_bnapply<<<391, 256, 0, stream>>>(Hc2, 48, 4, stats1, g1, be1);

    // ---- Layer 2 (16->32)
    k_prop<<<782, 256, 0, stream>>>(cnt, pslots, Hc2, 48, 0, Hc2, 48, 16, 2, 1.0f,
                                    nullptr, 0, 0, 0.0f, nullptr, 0, 0, nullptr, 0);
    k_prop<<<782, 256, 0, stream>>>(cnt, pslots, Hc2, 48, 16, Hc2, 48, 32, 2, 2.0f,
                                    Hc2, 48, 0, -1.0f, nullptr, 0, 0, nullptr, 0);
    k_gemm<<<dim3(1, 391), 256, 0, stream>>>(Hc2, 48, W2, 32, Hc3, 96, NN, 48, 32, b2, 1);
    k_bnstats<<<256, 256, 0, stream>>>(Hc3, 96, 5, stats2);
    k_bnapply<<<782, 256, 0, stream>>>(Hc3, 96, 5, stats2, g2, be2);

    // ---- Layer 3 (32->64)
    k_prop<<<1563, 256, 0, stream>>>(cnt, pslots, Hc3, 96, 0, Hc3, 96, 32, 3, 1.0f,
                                     nullptr, 0, 0, 0.0f, nullptr, 0, 0, nullptr, 0);
    k_prop<<<1563, 256, 0, stream>>>(cnt, pslots, Hc3, 96, 32, Hc3, 96, 64, 3, 2.0f,
                                     Hc3, 96, 0, -1.0f, nullptr, 0, 0, nullptr, 0);
    k_gemm_mfma_bf<<<dim3(1, 391), 256, 0, stream>>>(Hc3, 96, bt3h, bt3l, Hc4, 192, NN, 96, 64, b3, 1, 0);
    k_bnstats<<<256, 256, 0, stream>>>(Hc4, 192, 6, stats3);
    k_bnapply<<<1563, 256, 0, stream>>>(Hc4, 192, 6, stats3, g3, be3);

    // ---- Layer 4 (64->128): props on k_prop16 (unsliced — 64B sub-slices
    // would share cache lines)
    k_prop16<<<3125, 256, 0, stream>>>(cnt, pslots, Hc4, 192, 0, Hc4, 192, 64, 4, 1.0f,
                                       nullptr, 0, 0, 0.0f);
    k_prop16<<<3125, 256, 0, stream>>>(cnt, pslots, Hc4, 192, 64, Hc4, 192, 128, 4, 2.0f,
                                       Hc4, 192, 0, -1.0f);
    k_gemm_mfma_bf<<<dim3(1, 391), 256, 0, stream>>>(Hc4, 192, bt4h, bt4l, Hc5, 384, NN, 192, 128, b4, 1, 0);
    k_bnstats<<<256, 256, 0, stream>>>(Hc5, 384, 7, stats4);
    k_bnapply<<<3125, 256, 0, stream>>>(Hc5, 384, 7, stats4, g4, be4);

    // ---- Layer 5 (128->256): props on k_prop16s (2-way XCD-sliced)
    k_prop16s<<<6256, 256, 0, stream>>>(cnt, pslots, Hc5, 384, 0, Hc5, 384, 128, 1.0f,
                                        nullptr, 0, 0, 0.0f);
    k_prop16s<<<6256, 256, 0, stream>>>(cnt, pslots, Hc5, 384, 128, Hc5, 384, 256, 2.0f,
                                        Hc5, 384, 0, -1.0f);
    // L5 GEMM: XCD-pair swizzled 1D grid (784 = 8 xcd * 98; both N-halves of
    // M-tile y on XCD y%8 -> A read once per XCD)
    k_gemm_mfma_bf<<<784, 256, 0, stream>>>(Hc5, 384, bt5h, bt5l, h5, 256, NN, 384, 256, b5, 0, 1);

    // ---- Pool + dense + log_softmax
    k_pool1<<<dim3(16, 64), 256, 0, stream>>>(h5, gb, partial);
    k_pool2d<<<64, 256, 0, stream>>>(partial, gb, Wd, bd, outp);
}